// Round 1
// baseline (5239.986 us; speedup 1.0000x reference)
//
#include <hip/hip_runtime.h>
#include <math.h>

#define N_NODES 100000
#define N_EDGES 3200000
#define N_GRAPHS 64

// ---- monotone float<->unsigned key for atomicMax-based segment max ----
// key(x) preserves order; all finite floats map to key > 0, so zero-init works.
__device__ __forceinline__ unsigned fkey(float x) {
    unsigned u = __float_as_uint(x);
    return (u & 0x80000000u) ? ~u : (u | 0x80000000u);
}
__device__ __forceinline__ float fdec(unsigned k) {
    return (k & 0x80000000u) ? __uint_as_float(k ^ 0x80000000u)
                             : __uint_as_float(~k);
}

__device__ __forceinline__ void atomAddF(float* p, float v) {
#if defined(__HIP_PLATFORM_AMD__)
    unsafeAtomicAdd(p, v);   // native global_atomic_add_f32 on CDNA
#else
    atomicAdd(p, v);
#endif
}

// ---- K1: q1,k1,v1 = x @ W + b  (3 -> 64), 64 threads per node ----
__global__ void k1_node_qkv(const float* __restrict__ x,
                            const float* __restrict__ Wq, const float* __restrict__ bq,
                            const float* __restrict__ Wk, const float* __restrict__ bk,
                            const float* __restrict__ Wv, const float* __restrict__ bv,
                            float* __restrict__ q1, float* __restrict__ k1,
                            float* __restrict__ v1) {
    __shared__ float sW[3 * 192 + 3 * 64];
    float* sWq = sW;        float* sWk = sW + 192;  float* sWv = sW + 384;
    float* sbq = sW + 576;  float* sbk = sW + 640;  float* sbv = sW + 704;
    for (int i = threadIdx.x; i < 192; i += blockDim.x) {
        sWq[i] = Wq[i]; sWk[i] = Wk[i]; sWv[i] = Wv[i];
    }
    for (int i = threadIdx.x; i < 64; i += blockDim.x) {
        sbq[i] = bq[i]; sbk[i] = bk[i]; sbv[i] = bv[i];
    }
    __syncthreads();
    int j = threadIdx.x & 63;
    int n = blockIdx.x * 4 + (threadIdx.x >> 6);
    if (n >= N_NODES) return;
    float x0 = x[n * 3], x1 = x[n * 3 + 1], x2 = x[n * 3 + 2];
    size_t o = (size_t)n * 64 + j;
    q1[o] = sbq[j] + x0 * sWq[j] + x1 * sWq[64 + j] + x2 * sWq[128 + j];
    k1[o] = sbk[j] + x0 * sWk[j] + x1 * sWk[64 + j] + x2 * sWk[128 + j];
    v1[o] = sbv[j] + x0 * sWv[j] + x1 * sWv[64 + j] + x2 * sWv[128 + j];
}

// ---- K2: layer-1 edge logits (16 threads/edge; 4 threads per head) ----
__global__ void k2_edge_logits(const int* __restrict__ ei,
                               const float* __restrict__ q1, const float* __restrict__ k1,
                               float* __restrict__ logits, unsigned* __restrict__ mkey) {
    int tid = blockIdx.x * blockDim.x + threadIdx.x;
    int e = tid >> 4;
    if (e >= N_EDGES) return;
    int t = tid & 15;
    int src = ei[e], dst = ei[N_EDGES + e];
    float4 qv = *reinterpret_cast<const float4*>(q1 + (size_t)dst * 64 + t * 4);
    float4 kv = *reinterpret_cast<const float4*>(k1 + (size_t)src * 64 + t * 4);
    float s = qv.x * kv.x + qv.y * kv.y + qv.z * kv.z + qv.w * kv.w;
    s += __shfl_xor(s, 1);
    s += __shfl_xor(s, 2);
    if ((t & 3) == 0) {
        int h = t >> 2;
        float logit = s * 0.25f;  // 1/sqrt(16)
        logits[(size_t)e * 4 + h] = logit;
        atomicMax(mkey + (size_t)dst * 4 + h, fkey(logit));
    }
}

// ---- K3: layer-1 exp + unnormalized scatter (16 threads/edge) ----
__global__ void k3_edge_scatter(const int* __restrict__ ei,
                                const float* __restrict__ v1,
                                const float* __restrict__ logits,
                                const unsigned* __restrict__ mkey,
                                float* __restrict__ denom, float* __restrict__ acc) {
    int tid = blockIdx.x * blockDim.x + threadIdx.x;
    int e = tid >> 4;
    if (e >= N_EDGES) return;
    int t = tid & 15;
    int h = t >> 2;
    int src = ei[e], dst = ei[N_EDGES + e];
    float logit = logits[(size_t)e * 4 + h];
    float m = fdec(mkey[(size_t)dst * 4 + h]);
    float a = __expf(logit - m);
    if ((t & 3) == 0) atomAddF(denom + (size_t)dst * 4 + h, a);
    float4 vv = *reinterpret_cast<const float4*>(v1 + (size_t)src * 64 + t * 4);
    float* accp = acc + (size_t)dst * 64 + t * 4;
    atomAddF(accp + 0, a * vv.x);
    atomAddF(accp + 1, a * vv.y);
    atomAddF(accp + 2, a * vv.z);
    atomAddF(accp + 3, a * vv.w);
}

// ---- K4: layer-1 epilogue: h1 = relu(acc/denom + x@Ws1 + bs1), in place ----
__global__ void k4_epilogue1(const float* __restrict__ x,
                             const float* __restrict__ Ws, const float* __restrict__ bs,
                             const float* __restrict__ denom,
                             float* __restrict__ acc) {
    __shared__ float sW[192], sb[64];
    for (int i = threadIdx.x; i < 192; i += blockDim.x) sW[i] = Ws[i];
    for (int i = threadIdx.x; i < 64; i += blockDim.x) sb[i] = bs[i];
    __syncthreads();
    int j = threadIdx.x & 63;
    int n = blockIdx.x * 4 + (threadIdx.x >> 6);
    if (n >= N_NODES) return;
    float x0 = x[n * 3], x1 = x[n * 3 + 1], x2 = x[n * 3 + 2];
    float skip = sb[j] + x0 * sW[j] + x1 * sW[64 + j] + x2 * sW[128 + j];
    int h = j >> 4;
    size_t o = (size_t)n * 64 + j;
    float val = acc[o] / (denom[(size_t)n * 4 + h] + 1e-16f) + skip;
    acc[o] = fmaxf(val, 0.0f);
}

// ---- K5: q2,k2,v2 = h1 @ W + b (64 -> 6), one thread per node ----
__global__ void k5_node_qkv2(const float* __restrict__ h1,
                             const float* __restrict__ Wq, const float* __restrict__ bq,
                             const float* __restrict__ Wk, const float* __restrict__ bk,
                             const float* __restrict__ Wv, const float* __restrict__ bv,
                             float* __restrict__ q2, float* __restrict__ k2,
                             float* __restrict__ v2) {
    __shared__ float sWq[384], sWk[384], sWv[384], sbq[6], sbk[6], sbv[6];
    for (int i = threadIdx.x; i < 384; i += blockDim.x) {
        sWq[i] = Wq[i]; sWk[i] = Wk[i]; sWv[i] = Wv[i];
    }
    if (threadIdx.x < 6) {
        sbq[threadIdx.x] = bq[threadIdx.x];
        sbk[threadIdx.x] = bk[threadIdx.x];
        sbv[threadIdx.x] = bv[threadIdx.x];
    }
    __syncthreads();
    int n = blockIdx.x * blockDim.x + threadIdx.x;
    if (n >= N_NODES) return;
    float qa[6], ka[6], va[6];
    for (int c = 0; c < 6; ++c) { qa[c] = sbq[c]; ka[c] = sbk[c]; va[c] = sbv[c]; }
    const float4* hp = reinterpret_cast<const float4*>(h1 + (size_t)n * 64);
    for (int i4 = 0; i4 < 16; ++i4) {
        float4 hv = hp[i4];
        float hvv[4] = {hv.x, hv.y, hv.z, hv.w};
        for (int u = 0; u < 4; ++u) {
            float hx = hvv[u];
            int i = i4 * 4 + u;
            for (int c = 0; c < 6; ++c) {
                qa[c] += hx * sWq[i * 6 + c];
                ka[c] += hx * sWk[i * 6 + c];
                va[c] += hx * sWv[i * 6 + c];
            }
        }
    }
    for (int c = 0; c < 6; ++c) {
        q2[(size_t)n * 6 + c] = qa[c];
        k2[(size_t)n * 6 + c] = ka[c];
        v2[(size_t)n * 6 + c] = va[c];
    }
}

// ---- K6: layer-2 edge logits (1 thread/edge) ----
__global__ void k6_edge2_logits(const int* __restrict__ ei,
                                const float* __restrict__ q2, const float* __restrict__ k2,
                                float* __restrict__ logits, unsigned* __restrict__ mkey) {
    int e = blockIdx.x * blockDim.x + threadIdx.x;
    if (e >= N_EDGES) return;
    int src = ei[e], dst = ei[N_EDGES + e];
    const float2* qp = reinterpret_cast<const float2*>(q2 + (size_t)dst * 6);
    const float2* kp = reinterpret_cast<const float2*>(k2 + (size_t)src * 6);
    float2 a0 = qp[0], a1 = qp[1], a2 = qp[2];
    float2 b0 = kp[0], b1 = kp[1], b2 = kp[2];
    float s = a0.x * b0.x + a0.y * b0.y + a1.x * b1.x + a1.y * b1.y
            + a2.x * b2.x + a2.y * b2.y;
    float logit = s * 0.4082482904638631f;  // 1/sqrt(6)
    logits[e] = logit;
    atomicMax(mkey + dst, fkey(logit));
}

// ---- K7: layer-2 exp + scatter (1 thread/edge) ----
__global__ void k7_edge2_scatter(const int* __restrict__ ei,
                                 const float* __restrict__ v2,
                                 const float* __restrict__ logits,
                                 const unsigned* __restrict__ mkey,
                                 float* __restrict__ denom, float* __restrict__ acc) {
    int e = blockIdx.x * blockDim.x + threadIdx.x;
    if (e >= N_EDGES) return;
    int src = ei[e], dst = ei[N_EDGES + e];
    float a = __expf(logits[e] - fdec(mkey[dst]));
    atomAddF(denom + dst, a);
    const float2* vp = reinterpret_cast<const float2*>(v2 + (size_t)src * 6);
    float2 v0 = vp[0], v1 = vp[1], v2v = vp[2];
    float* accp = acc + (size_t)dst * 6;
    atomAddF(accp + 0, a * v0.x);
    atomAddF(accp + 1, a * v0.y);
    atomAddF(accp + 2, a * v1.x);
    atomAddF(accp + 3, a * v1.y);
    atomAddF(accp + 4, a * v2v.x);
    atomAddF(accp + 5, a * v2v.y);
}

// ---- K8: layer-2 epilogue + graph pooling atomics ----
__global__ void k8_epilogue2_pool(const float* __restrict__ h1,
                                  const float* __restrict__ Ws, const float* __restrict__ bs,
                                  const int* __restrict__ batch,
                                  const float* __restrict__ denom,
                                  const float* __restrict__ acc,
                                  float* __restrict__ psum, float* __restrict__ pcnt) {
    __shared__ float sW[384], sb[6];
    for (int i = threadIdx.x; i < 384; i += blockDim.x) sW[i] = Ws[i];
    if (threadIdx.x < 6) sb[threadIdx.x] = bs[threadIdx.x];
    __syncthreads();
    int n = blockIdx.x * blockDim.x + threadIdx.x;
    if (n >= N_NODES) return;
    float o[6];
    for (int c = 0; c < 6; ++c) o[c] = sb[c];
    const float4* hp = reinterpret_cast<const float4*>(h1 + (size_t)n * 64);
    for (int i4 = 0; i4 < 16; ++i4) {
        float4 hv = hp[i4];
        float hvv[4] = {hv.x, hv.y, hv.z, hv.w};
        for (int u = 0; u < 4; ++u) {
            float hx = hvv[u];
            int i = i4 * 4 + u;
            for (int c = 0; c < 6; ++c) o[c] += hx * sW[i * 6 + c];
        }
    }
    float dn = denom[n] + 1e-16f;
    int g = batch[n];
    for (int c = 0; c < 6; ++c) {
        float val = acc[(size_t)n * 6 + c] / dn + o[c];
        atomAddF(psum + g * 6 + c, val);
    }
    atomAddF(pcnt + g, 1.0f);
}

// ---- K9: pooled mean + log_softmax, one thread per graph ----
__global__ void k9_final(const float* __restrict__ psum, const float* __restrict__ pcnt,
                         float* __restrict__ out) {
    int g = threadIdx.x;
    if (g >= N_GRAPHS) return;
    float cnt = fmaxf(pcnt[g], 1.0f);
    float z[6];
    float mx = -1e30f;
    for (int c = 0; c < 6; ++c) {
        z[c] = psum[g * 6 + c] / cnt;
        mx = fmaxf(mx, z[c]);
    }
    float se = 0.f;
    for (int c = 0; c < 6; ++c) se += __expf(z[c] - mx);
    float lse = mx + logf(se);
    for (int c = 0; c < 6; ++c) out[g * 6 + c] = z[c] - lse;
}

extern "C" void kernel_launch(void* const* d_in, const int* in_sizes, int n_in,
                              void* d_out, int out_size, void* d_ws, size_t ws_size,
                              hipStream_t stream) {
    const float* x   = (const float*)d_in[0];
    const int*   ei  = (const int*)d_in[1];
    const int*   bat = (const int*)d_in[2];
    const float* Wq1 = (const float*)d_in[3];  const float* bq1 = (const float*)d_in[4];
    const float* Wk1 = (const float*)d_in[5];  const float* bk1 = (const float*)d_in[6];
    const float* Wv1 = (const float*)d_in[7];  const float* bv1 = (const float*)d_in[8];
    const float* Ws1 = (const float*)d_in[9];  const float* bs1 = (const float*)d_in[10];
    const float* Wq2 = (const float*)d_in[11]; const float* bq2 = (const float*)d_in[12];
    const float* Wk2 = (const float*)d_in[13]; const float* bk2 = (const float*)d_in[14];
    const float* Wv2 = (const float*)d_in[15]; const float* bv2 = (const float*)d_in[16];
    const float* Ws2 = (const float*)d_in[17]; const float* bs2 = (const float*)d_in[18];
    float* out = (float*)d_out;

    char* ws = (char*)d_ws;
    size_t off = 0;
    auto alloc = [&](size_t bytes) -> char* {
        char* p = ws + off;
        off += (bytes + 255) & ~(size_t)255;
        return p;
    };

    // ---- zero-initialized region (one memset) ----
    float*    acc1   = (float*)   alloc((size_t)N_NODES * 64 * 4);  // later holds h1
    unsigned* m1     = (unsigned*)alloc((size_t)N_NODES * 4 * 4);
    float*    denom1 = (float*)   alloc((size_t)N_NODES * 4 * 4);
    unsigned* m2     = (unsigned*)alloc((size_t)N_NODES * 4);
    float*    denom2 = (float*)   alloc((size_t)N_NODES * 4);
    float*    acc2   = (float*)   alloc((size_t)N_NODES * 6 * 4);
    float*    psum   = (float*)   alloc((size_t)N_GRAPHS * 6 * 4);
    float*    pcnt   = (float*)   alloc((size_t)N_GRAPHS * 4);
    size_t zero_bytes = off;

    // ---- uninitialized scratch ----
    float* q1      = (float*)alloc((size_t)N_NODES * 64 * 4);
    float* k1      = (float*)alloc((size_t)N_NODES * 64 * 4);
    float* v1      = (float*)alloc((size_t)N_NODES * 64 * 4);
    float* logits1 = (float*)alloc((size_t)N_EDGES * 4 * 4);
    // layer-2 reuse
    float* q2      = q1;
    float* k2      = k1;
    float* v2      = v1;
    float* logits2 = logits1;

    hipMemsetAsync(d_ws, 0, zero_bytes, stream);

    dim3 blk(256);
    int grid_node4 = (N_NODES + 3) / 4;          // 64 threads/node, 4 nodes/block
    int grid_node1 = (N_NODES + 255) / 256;      // 1 thread/node
    int grid_e16   = (N_EDGES + 15) / 16;        // 16 threads/edge
    int grid_e1    = (N_EDGES + 255) / 256;      // 1 thread/edge

    k1_node_qkv<<<grid_node4, blk, 0, stream>>>(x, Wq1, bq1, Wk1, bk1, Wv1, bv1,
                                                q1, k1, v1);
    k2_edge_logits<<<grid_e16, blk, 0, stream>>>(ei, q1, k1, logits1, m1);
    k3_edge_scatter<<<grid_e16, blk, 0, stream>>>(ei, v1, logits1, m1, denom1, acc1);
    k4_epilogue1<<<grid_node4, blk, 0, stream>>>(x, Ws1, bs1, denom1, acc1);
    // acc1 now holds h1
    k5_node_qkv2<<<grid_node1, blk, 0, stream>>>(acc1, Wq2, bq2, Wk2, bk2, Wv2, bv2,
                                                 q2, k2, v2);
    k6_edge2_logits<<<grid_e1, blk, 0, stream>>>(ei, q2, k2, logits2, m2);
    k7_edge2_scatter<<<grid_e1, blk, 0, stream>>>(ei, v2, logits2, m2, denom2, acc2);
    k8_epilogue2_pool<<<grid_node1, blk, 0, stream>>>(acc1, Ws2, bs2, bat,
                                                      denom2, acc2, psum, pcnt);
    k9_final<<<1, 64, 0, stream>>>(psum, pcnt, out);
}

// Round 2
// 873.946 us; speedup vs baseline: 5.9958x; 5.9958x over previous
//
#include <hip/hip_runtime.h>
#include <math.h>

#define N_NODES 100000
#define N_EDGES 3200000
#define N_GRAPHS 64
#define NEG_INF -1e30f

__device__ __forceinline__ void atomAddF(float* p, float v) {
#if defined(__HIP_PLATFORM_AMD__)
    unsafeAtomicAdd(p, v);   // native global_atomic_add_f32 on CDNA
#else
    atomicAdd(p, v);
#endif
}

// ---- C1: histogram of in-degree (by dst) ----
__global__ void c1_hist(const int* __restrict__ ei, int* __restrict__ deg) {
    int e = blockIdx.x * blockDim.x + threadIdx.x;
    if (e >= N_EDGES) return;
    atomicAdd(deg + ei[N_EDGES + e], 1);
}

// ---- C2: exclusive scan of deg -> rowstart[N+1], plus cursor copy ----
#define SCAN_T 1024
__global__ void c2_scan(const int* __restrict__ deg,
                        int* __restrict__ rowstart, int* __restrict__ cursor) {
    __shared__ int part[SCAN_T];
    const int per = (N_NODES + SCAN_T - 1) / SCAN_T;  // 98
    int tid = threadIdx.x;
    int base = tid * per;
    int s = 0;
    for (int i = 0; i < per; ++i) {
        int idx = base + i;
        if (idx < N_NODES) s += deg[idx];
    }
    part[tid] = s;
    __syncthreads();
    for (int off = 1; off < SCAN_T; off <<= 1) {
        int v = (tid >= off) ? part[tid - off] : 0;
        __syncthreads();
        part[tid] += v;
        __syncthreads();
    }
    int run = (tid == 0) ? 0 : part[tid - 1];
    for (int i = 0; i < per; ++i) {
        int idx = base + i;
        if (idx < N_NODES) {
            rowstart[idx] = run;
            cursor[idx] = run;
            run += deg[idx];
        }
    }
    if (tid == SCAN_T - 1) rowstart[N_NODES] = part[SCAN_T - 1];
}

// ---- C3: scatter src into CSR slots ----
__global__ void c3_scatter(const int* __restrict__ ei,
                           int* __restrict__ cursor, int* __restrict__ csr_src) {
    int e = blockIdx.x * blockDim.x + threadIdx.x;
    if (e >= N_EDGES) return;
    int src = ei[e], dst = ei[N_EDGES + e];
    int slot = atomicAdd(cursor + dst, 1);
    csr_src[slot] = src;
}

// ---- G1: fused layer-1. One wave per node; 4 edge slots x 16 lanes.
// q/k/v computed on the fly from x (3->64). Online softmax, fused
// skip (x@Ws1+bs1) + ReLU epilogue. Writes h1 [N,64].
__global__ void g1_layer1(const float* __restrict__ x,
                          const float* __restrict__ Wq, const float* __restrict__ bq,
                          const float* __restrict__ Wk, const float* __restrict__ bk,
                          const float* __restrict__ Wv, const float* __restrict__ bv,
                          const float* __restrict__ Ws, const float* __restrict__ bs,
                          const int* __restrict__ rowstart,
                          const int* __restrict__ csr_src,
                          float* __restrict__ h1) {
    __shared__ float sWq[192], sWk[192], sWv[192], sWs[192];
    __shared__ float sbq[64], sbk[64], sbv[64], sbs[64];
    for (int i = threadIdx.x; i < 192; i += 256) {
        sWq[i] = Wq[i]; sWk[i] = Wk[i]; sWv[i] = Wv[i]; sWs[i] = Ws[i];
    }
    for (int i = threadIdx.x; i < 64; i += 256) {
        sbq[i] = bq[i]; sbk[i] = bk[i]; sbv[i] = bv[i]; sbs[i] = bs[i];
    }
    __syncthreads();

    int wave = threadIdx.x >> 6;
    int lane = threadIdx.x & 63;
    int n = blockIdx.x * 4 + wave;          // grid exact: 25000*4 = 100000
    int t = lane & 15;                      // 16 lanes per edge (4 dims each)
    int slot = lane >> 4;                   // 4 edges in flight
    int j0 = t * 4;

    float x0 = x[n * 3], x1 = x[n * 3 + 1], x2 = x[n * 3 + 2];
    float q[4];
#pragma unroll
    for (int i = 0; i < 4; ++i)
        q[i] = sbq[j0 + i] + x0 * sWq[j0 + i] + x1 * sWq[64 + j0 + i] + x2 * sWq[128 + j0 + i];

    int row = rowstart[n];
    int deg = rowstart[n + 1] - row;

    float m = NEG_INF, dsum = 0.f;
    float acc[4] = {0.f, 0.f, 0.f, 0.f};

    for (int base = 0; base < deg; base += 4) {
        int e = base + slot;
        bool valid = e < deg;
        int src = valid ? csr_src[row + e] : 0;
        float sx0 = x[src * 3], sx1 = x[src * 3 + 1], sx2 = x[src * 3 + 2];
        float kf[4], vf[4];
#pragma unroll
        for (int i = 0; i < 4; ++i) {
            kf[i] = sbk[j0 + i] + sx0 * sWk[j0 + i] + sx1 * sWk[64 + j0 + i] + sx2 * sWk[128 + j0 + i];
            vf[i] = sbv[j0 + i] + sx0 * sWv[j0 + i] + sx1 * sWv[64 + j0 + i] + sx2 * sWv[128 + j0 + i];
        }
        float dot = q[0] * kf[0] + q[1] * kf[1] + q[2] * kf[2] + q[3] * kf[3];
        dot += __shfl_xor(dot, 1);
        dot += __shfl_xor(dot, 2);          // now per-head dot across 4 lanes
        float logit = valid ? dot * 0.25f : NEG_INF;   // 1/sqrt(16)
        float mnew = fmaxf(m, logit);
        float scale = __expf(m - mnew);     // 0 if m was NEG_INF and logit finite
        float a = valid ? __expf(logit - mnew) : 0.f;
        dsum = dsum * scale + a;
#pragma unroll
        for (int i = 0; i < 4; ++i) acc[i] = acc[i] * scale + a * vf[i];
        m = mnew;
    }

    // merge the 4 edge slots (lanes xor 16, 32)
#pragma unroll
    for (int off = 16; off <= 32; off <<= 1) {
        float m2 = __shfl_xor(m, off);
        float d2 = __shfl_xor(dsum, off);
        float a2[4];
#pragma unroll
        for (int i = 0; i < 4; ++i) a2[i] = __shfl_xor(acc[i], off);
        float mn = fmaxf(m, m2);
        float s1 = __expf(m - mn), s2 = __expf(m2 - mn);
        dsum = dsum * s1 + d2 * s2;
#pragma unroll
        for (int i = 0; i < 4; ++i) acc[i] = acc[i] * s1 + a2[i] * s2;
        m = mn;
    }

    if (slot == 0) {
        float inv = 1.f / (dsum + 1e-16f);
        float4 o;
        float* op = &o.x;
#pragma unroll
        for (int i = 0; i < 4; ++i) {
            float skip = sbs[j0 + i] + x0 * sWs[j0 + i] + x1 * sWs[64 + j0 + i] + x2 * sWs[128 + j0 + i];
            op[i] = fmaxf(acc[i] * inv + skip, 0.f);
        }
        *reinterpret_cast<float4*>(h1 + (size_t)n * 64 + j0) = o;
    }
}

// ---- K5: q2,k2,v2,s2 = h1 @ W + b (64 -> 6), one thread per node ----
__global__ void k5_node2(const float* __restrict__ h1,
                         const float* __restrict__ Wq, const float* __restrict__ bq,
                         const float* __restrict__ Wk, const float* __restrict__ bk,
                         const float* __restrict__ Wv, const float* __restrict__ bv,
                         const float* __restrict__ Ws, const float* __restrict__ bs,
                         float* __restrict__ q2, float* __restrict__ k2,
                         float* __restrict__ v2, float* __restrict__ s2) {
    __shared__ float sWq[384], sWk[384], sWv[384], sWs[384];
    __shared__ float sbq[6], sbk[6], sbv[6], sbs[6];
    for (int i = threadIdx.x; i < 384; i += blockDim.x) {
        sWq[i] = Wq[i]; sWk[i] = Wk[i]; sWv[i] = Wv[i]; sWs[i] = Ws[i];
    }
    if (threadIdx.x < 6) {
        sbq[threadIdx.x] = bq[threadIdx.x];
        sbk[threadIdx.x] = bk[threadIdx.x];
        sbv[threadIdx.x] = bv[threadIdx.x];
        sbs[threadIdx.x] = bs[threadIdx.x];
    }
    __syncthreads();
    int n = blockIdx.x * blockDim.x + threadIdx.x;
    if (n >= N_NODES) return;
    float qa[6], ka[6], va[6], sa[6];
#pragma unroll
    for (int c = 0; c < 6; ++c) { qa[c] = sbq[c]; ka[c] = sbk[c]; va[c] = sbv[c]; sa[c] = sbs[c]; }
    const float4* hp = reinterpret_cast<const float4*>(h1 + (size_t)n * 64);
#pragma unroll
    for (int i4 = 0; i4 < 16; ++i4) {
        float4 hv = hp[i4];
        float hvv[4] = {hv.x, hv.y, hv.z, hv.w};
#pragma unroll
        for (int u = 0; u < 4; ++u) {
            float hx = hvv[u];
            int i = i4 * 4 + u;
#pragma unroll
            for (int c = 0; c < 6; ++c) {
                qa[c] += hx * sWq[i * 6 + c];
                ka[c] += hx * sWk[i * 6 + c];
                va[c] += hx * sWv[i * 6 + c];
                sa[c] += hx * sWs[i * 6 + c];
            }
        }
    }
#pragma unroll
    for (int c = 0; c < 6; ++c) {
        q2[(size_t)n * 6 + c] = qa[c];
        k2[(size_t)n * 6 + c] = ka[c];
        v2[(size_t)n * 6 + c] = va[c];
        s2[(size_t)n * 6 + c] = sa[c];
    }
}

// ---- G2: fused layer-2 gather + epilogue + LDS-pre-reduced pooling.
// 16 lanes per node, 16 nodes per 256-thread block. Grid exact: 6250*16=100000.
__global__ void g2_layer2(const int* __restrict__ rowstart,
                          const int* __restrict__ csr_src,
                          const float* __restrict__ q2, const float* __restrict__ k2,
                          const float* __restrict__ v2, const float* __restrict__ s2,
                          const int* __restrict__ batch,
                          float* __restrict__ psum, float* __restrict__ pcnt) {
    __shared__ float bsum[N_GRAPHS * 6];
    __shared__ float bcnt[N_GRAPHS];
    for (int i = threadIdx.x; i < N_GRAPHS * 6; i += 256) bsum[i] = 0.f;
    for (int i = threadIdx.x; i < N_GRAPHS; i += 256) bcnt[i] = 0.f;
    __syncthreads();

    int node = blockIdx.x * 16 + (threadIdx.x >> 4);
    int lane16 = threadIdx.x & 15;

    float q[6];
#pragma unroll
    for (int c = 0; c < 6; ++c) q[c] = q2[(size_t)node * 6 + c];
    int row = rowstart[node];
    int deg = rowstart[node + 1] - row;

    float m = NEG_INF, d = 0.f;
    float acc[6] = {0.f, 0.f, 0.f, 0.f, 0.f, 0.f};
    for (int e = lane16; e < deg; e += 16) {
        int src = csr_src[row + e];
        const float* kp = k2 + (size_t)src * 6;
        float dot = q[0] * kp[0] + q[1] * kp[1] + q[2] * kp[2]
                  + q[3] * kp[3] + q[4] * kp[4] + q[5] * kp[5];
        float logit = dot * 0.4082482904638631f;  // 1/sqrt(6)
        float mn = fmaxf(m, logit);
        float sc = __expf(m - mn);
        float a = __expf(logit - mn);
        d = d * sc + a;
        const float* vp = v2 + (size_t)src * 6;
#pragma unroll
        for (int c = 0; c < 6; ++c) acc[c] = acc[c] * sc + a * vp[c];
        m = mn;
    }
    // merge 16 lanes
#pragma unroll
    for (int off = 1; off <= 8; off <<= 1) {
        float m2 = __shfl_xor(m, off);
        float d2 = __shfl_xor(d, off);
        float a2[6];
#pragma unroll
        for (int c = 0; c < 6; ++c) a2[c] = __shfl_xor(acc[c], off);
        float mn = fmaxf(m, m2);
        float s1 = __expf(m - mn), sc2 = __expf(m2 - mn);
        d = d * s1 + d2 * sc2;
#pragma unroll
        for (int c = 0; c < 6; ++c) acc[c] = acc[c] * s1 + a2[c] * sc2;
        m = mn;
    }

    if (lane16 == 0) {
        float inv = 1.f / (d + 1e-16f);
        int g = batch[node];
#pragma unroll
        for (int c = 0; c < 6; ++c) {
            float val = acc[c] * inv + s2[(size_t)node * 6 + c];
            atomicAdd(&bsum[g * 6 + c], val);
        }
        atomicAdd(&bcnt[g], 1.f);
    }
    __syncthreads();
    for (int i = threadIdx.x; i < N_GRAPHS * 6; i += 256) {
        float v = bsum[i];
        if (v != 0.f) atomAddF(psum + i, v);
    }
    for (int i = threadIdx.x; i < N_GRAPHS; i += 256) {
        float v = bcnt[i];
        if (v != 0.f) atomAddF(pcnt + i, v);
    }
}

// ---- K9: pooled mean + log_softmax, one thread per graph ----
__global__ void k9_final(const float* __restrict__ psum, const float* __restrict__ pcnt,
                         float* __restrict__ out) {
    int g = threadIdx.x;
    if (g >= N_GRAPHS) return;
    float cnt = fmaxf(pcnt[g], 1.0f);
    float z[6];
    float mx = -1e30f;
#pragma unroll
    for (int c = 0; c < 6; ++c) {
        z[c] = psum[g * 6 + c] / cnt;
        mx = fmaxf(mx, z[c]);
    }
    float se = 0.f;
#pragma unroll
    for (int c = 0; c < 6; ++c) se += __expf(z[c] - mx);
    float lse = mx + logf(se);
#pragma unroll
    for (int c = 0; c < 6; ++c) out[g * 6 + c] = z[c] - lse;
}

extern "C" void kernel_launch(void* const* d_in, const int* in_sizes, int n_in,
                              void* d_out, int out_size, void* d_ws, size_t ws_size,
                              hipStream_t stream) {
    const float* x   = (const float*)d_in[0];
    const int*   ei  = (const int*)d_in[1];
    const int*   bat = (const int*)d_in[2];
    const float* Wq1 = (const float*)d_in[3];  const float* bq1 = (const float*)d_in[4];
    const float* Wk1 = (const float*)d_in[5];  const float* bk1 = (const float*)d_in[6];
    const float* Wv1 = (const float*)d_in[7];  const float* bv1 = (const float*)d_in[8];
    const float* Ws1 = (const float*)d_in[9];  const float* bs1 = (const float*)d_in[10];
    const float* Wq2 = (const float*)d_in[11]; const float* bq2 = (const float*)d_in[12];
    const float* Wk2 = (const float*)d_in[13]; const float* bk2 = (const float*)d_in[14];
    const float* Wv2 = (const float*)d_in[15]; const float* bv2 = (const float*)d_in[16];
    const float* Ws2 = (const float*)d_in[17]; const float* bs2 = (const float*)d_in[18];
    float* out = (float*)d_out;

    char* ws = (char*)d_ws;
    size_t off = 0;
    auto alloc = [&](size_t bytes) -> char* {
        char* p = ws + off;
        off += (bytes + 255) & ~(size_t)255;
        return p;
    };

    // ---- zero-initialized region (one memset) ----
    int*   deg  = (int*)  alloc((size_t)N_NODES * 4);
    float* psum = (float*)alloc((size_t)N_GRAPHS * 6 * 4);
    float* pcnt = (float*)alloc((size_t)N_GRAPHS * 4);
    size_t zero_bytes = off;

    // ---- uninitialized scratch ----
    int*   rowstart = (int*)  alloc((size_t)(N_NODES + 1) * 4);
    int*   cursor   = (int*)  alloc((size_t)N_NODES * 4);
    int*   csr_src  = (int*)  alloc((size_t)N_EDGES * 4);
    float* h1       = (float*)alloc((size_t)N_NODES * 64 * 4);
    float* q2       = (float*)alloc((size_t)N_NODES * 6 * 4);
    float* k2       = (float*)alloc((size_t)N_NODES * 6 * 4);
    float* v2       = (float*)alloc((size_t)N_NODES * 6 * 4);
    float* s2       = (float*)alloc((size_t)N_NODES * 6 * 4);

    hipMemsetAsync(d_ws, 0, zero_bytes, stream);

    int grid_e = (N_EDGES + 255) / 256;
    c1_hist<<<grid_e, 256, 0, stream>>>(ei, deg);
    c2_scan<<<1, SCAN_T, 0, stream>>>(deg, rowstart, cursor);
    c3_scatter<<<grid_e, 256, 0, stream>>>(ei, cursor, csr_src);

    g1_layer1<<<N_NODES / 4, 256, 0, stream>>>(x, Wq1, bq1, Wk1, bk1, Wv1, bv1,
                                               Ws1, bs1, rowstart, csr_src, h1);
    k5_node2<<<(N_NODES + 255) / 256, 256, 0, stream>>>(h1, Wq2, bq2, Wk2, bk2,
                                                        Wv2, bv2, Ws2, bs2,
                                                        q2, k2, v2, s2);
    g2_layer2<<<N_NODES / 16, 256, 0, stream>>>(rowstart, csr_src, q2, k2, v2, s2,
                                                bat, psum, pcnt);
    k9_final<<<1, 64, 0, stream>>>(psum, pcnt, out);
}

// Round 3
// 315.134 us; speedup vs baseline: 16.6278x; 2.7733x over previous
//
#include <hip/hip_runtime.h>
#include <math.h>

#define N_NODES 100000
#define N_EDGES 3200000
#define N_GRAPHS 64
#define NEG_INF -1e30f

// bucket sort geometry: bucket = dst >> 10  (1024 nodes per bucket)
#define NB 98          // ceil(100000/1024)
#define NBLK 512       // partition blocks
#define CHUNK 6250     // 512 * 6250 = 3.2M exactly

__device__ __forceinline__ void atomAddF(float* p, float v) {
#if defined(__HIP_PLATFORM_AMD__)
    unsafeAtomicAdd(p, v);
#else
    atomicAdd(p, v);
#endif
}

// ---- P1: per-block bucket histogram ----
__global__ void p1_count(const int* __restrict__ ei, int* __restrict__ counts) {
    __shared__ int cnt[NB];
    for (int i = threadIdx.x; i < NB; i += 256) cnt[i] = 0;
    __syncthreads();
    int base = blockIdx.x * CHUNK;
    for (int i = threadIdx.x; i < CHUNK; i += 256) {
        int dst = ei[N_EDGES + base + i];
        atomicAdd(&cnt[dst >> 10], 1);
    }
    __syncthreads();
    for (int i = threadIdx.x; i < NB; i += 256)
        counts[i * NBLK + blockIdx.x] = cnt[i];
}

// ---- P2: single-block exclusive scan of counts[NB*NBLK] in place ----
__global__ void p2_scan(int* __restrict__ counts) {
    __shared__ int part[1024];
    const int per = (NB * NBLK) / 1024;  // 50176/1024 = 49 exactly
    int tid = threadIdx.x;
    int b0 = tid * per;
    int s = 0;
    for (int i = 0; i < per; ++i) s += counts[b0 + i];
    part[tid] = s;
    __syncthreads();
    for (int off = 1; off < 1024; off <<= 1) {
        int v = (tid >= off) ? part[tid - off] : 0;
        __syncthreads();
        part[tid] += v;
        __syncthreads();
    }
    int run = (tid == 0) ? 0 : part[tid - 1];
    for (int i = 0; i < per; ++i) {
        int c = counts[b0 + i];
        counts[b0 + i] = run;
        run += c;
    }
}

// ---- P3: partition (src,dst) pairs into bucket regions ----
__global__ void p3_partition(const int* __restrict__ ei,
                             const int* __restrict__ offsets,
                             int2* __restrict__ pairs) {
    __shared__ int cur[NB];
    for (int i = threadIdx.x; i < NB; i += 256)
        cur[i] = offsets[i * NBLK + blockIdx.x];
    __syncthreads();
    int base = blockIdx.x * CHUNK;
    for (int i = threadIdx.x; i < CHUNK; i += 256) {
        int src = ei[base + i];
        int dst = ei[N_EDGES + base + i];
        int pos = atomicAdd(&cur[dst >> 10], 1);
        pairs[pos] = make_int2(src, dst);
    }
}

// ---- P4: per-bucket exact CSR build (one block per bucket) ----
// Produces rowstart[N+1] and csr_src. All scatter writes confined to the
// bucket's ~130 KB csr slice -> L2-resident.
__global__ void p4_build(const int2* __restrict__ pairs,
                         const int* __restrict__ offsets,
                         int* __restrict__ rowstart, int* __restrict__ csr_src) {
    __shared__ int cnt[1024];
    __shared__ int sc[1024];
    __shared__ int cur[1024];
    int b = blockIdx.x;
    int tid = threadIdx.x;  // blockDim = 1024
    int ebase = offsets[b * NBLK];
    int eend = (b == NB - 1) ? N_EDGES : offsets[(b + 1) * NBLK];
    int ne = eend - ebase;

    cnt[tid] = 0;
    __syncthreads();
    for (int i = tid; i < ne; i += 1024) {
        int dst = pairs[ebase + i].y;
        atomicAdd(&cnt[dst & 1023], 1);
    }
    __syncthreads();
    sc[tid] = cnt[tid];
    __syncthreads();
    for (int off = 1; off < 1024; off <<= 1) {
        int v = (tid >= off) ? sc[tid - off] : 0;
        __syncthreads();
        sc[tid] += v;
        __syncthreads();
    }
    int excl = sc[tid] - cnt[tid];
    cur[tid] = excl;
    int node = (b << 10) + tid;
    if (node < N_NODES) rowstart[node] = ebase + excl;
    if (b == NB - 1 && tid == 0) rowstart[N_NODES] = N_EDGES;
    __syncthreads();
    for (int i = tid; i < ne; i += 1024) {
        int2 p = pairs[ebase + i];
        int pos = ebase + atomicAdd(&cur[p.y & 1023], 1);
        csr_src[pos] = p.x;
    }
}

// ---- G1: fused layer-1. One wave per node; 4 edge slots x 16 lanes. ----
__global__ void g1_layer1(const float* __restrict__ x,
                          const float* __restrict__ Wq, const float* __restrict__ bq,
                          const float* __restrict__ Wk, const float* __restrict__ bk,
                          const float* __restrict__ Wv, const float* __restrict__ bv,
                          const float* __restrict__ Ws, const float* __restrict__ bs,
                          const int* __restrict__ rowstart,
                          const int* __restrict__ csr_src,
                          float* __restrict__ h1) {
    __shared__ float sWq[192], sWk[192], sWv[192], sWs[192];
    __shared__ float sbq[64], sbk[64], sbv[64], sbs[64];
    for (int i = threadIdx.x; i < 192; i += 256) {
        sWq[i] = Wq[i]; sWk[i] = Wk[i]; sWv[i] = Wv[i]; sWs[i] = Ws[i];
    }
    for (int i = threadIdx.x; i < 64; i += 256) {
        sbq[i] = bq[i]; sbk[i] = bk[i]; sbv[i] = bv[i]; sbs[i] = bs[i];
    }
    __syncthreads();

    int wave = threadIdx.x >> 6;
    int lane = threadIdx.x & 63;
    int n = blockIdx.x * 4 + wave;
    int t = lane & 15;
    int slot = lane >> 4;
    int j0 = t * 4;

    float x0 = x[n * 3], x1 = x[n * 3 + 1], x2 = x[n * 3 + 2];
    float q[4];
#pragma unroll
    for (int i = 0; i < 4; ++i)
        q[i] = sbq[j0 + i] + x0 * sWq[j0 + i] + x1 * sWq[64 + j0 + i] + x2 * sWq[128 + j0 + i];

    int row = rowstart[n];
    int deg = rowstart[n + 1] - row;

    float m = NEG_INF, dsum = 0.f;
    float acc[4] = {0.f, 0.f, 0.f, 0.f};

    for (int base = 0; base < deg; base += 4) {
        int e = base + slot;
        bool valid = e < deg;
        int src = valid ? csr_src[row + e] : 0;
        float sx0 = x[src * 3], sx1 = x[src * 3 + 1], sx2 = x[src * 3 + 2];
        float kf[4], vf[4];
#pragma unroll
        for (int i = 0; i < 4; ++i) {
            kf[i] = sbk[j0 + i] + sx0 * sWk[j0 + i] + sx1 * sWk[64 + j0 + i] + sx2 * sWk[128 + j0 + i];
            vf[i] = sbv[j0 + i] + sx0 * sWv[j0 + i] + sx1 * sWv[64 + j0 + i] + sx2 * sWv[128 + j0 + i];
        }
        float dot = q[0] * kf[0] + q[1] * kf[1] + q[2] * kf[2] + q[3] * kf[3];
        dot += __shfl_xor(dot, 1);
        dot += __shfl_xor(dot, 2);
        float logit = valid ? dot * 0.25f : NEG_INF;
        float mnew = fmaxf(m, logit);
        float scale = __expf(m - mnew);
        float a = valid ? __expf(logit - mnew) : 0.f;
        dsum = dsum * scale + a;
#pragma unroll
        for (int i = 0; i < 4; ++i) acc[i] = acc[i] * scale + a * vf[i];
        m = mnew;
    }

#pragma unroll
    for (int off = 16; off <= 32; off <<= 1) {
        float m2 = __shfl_xor(m, off);
        float d2 = __shfl_xor(dsum, off);
        float a2[4];
#pragma unroll
        for (int i = 0; i < 4; ++i) a2[i] = __shfl_xor(acc[i], off);
        float mn = fmaxf(m, m2);
        float s1 = __expf(m - mn), s2 = __expf(m2 - mn);
        dsum = dsum * s1 + d2 * s2;
#pragma unroll
        for (int i = 0; i < 4; ++i) acc[i] = acc[i] * s1 + a2[i] * s2;
        m = mn;
    }

    if (slot == 0) {
        float inv = 1.f / (dsum + 1e-16f);
        float4 o;
        float* op = &o.x;
#pragma unroll
        for (int i = 0; i < 4; ++i) {
            float skip = sbs[j0 + i] + x0 * sWs[j0 + i] + x1 * sWs[64 + j0 + i] + x2 * sWs[128 + j0 + i];
            op[i] = fmaxf(acc[i] * inv + skip, 0.f);
        }
        *reinterpret_cast<float4*>(h1 + (size_t)n * 64 + j0) = o;
    }
}

// ---- K5: q2,k2,v2,s2 = h1 @ W + b (64 -> 6) ----
__global__ void k5_node2(const float* __restrict__ h1,
                         const float* __restrict__ Wq, const float* __restrict__ bq,
                         const float* __restrict__ Wk, const float* __restrict__ bk,
                         const float* __restrict__ Wv, const float* __restrict__ bv,
                         const float* __restrict__ Ws, const float* __restrict__ bs,
                         float* __restrict__ q2, float* __restrict__ k2,
                         float* __restrict__ v2, float* __restrict__ s2) {
    __shared__ float sWq[384], sWk[384], sWv[384], sWs[384];
    __shared__ float sbq[6], sbk[6], sbv[6], sbs[6];
    for (int i = threadIdx.x; i < 384; i += blockDim.x) {
        sWq[i] = Wq[i]; sWk[i] = Wk[i]; sWv[i] = Wv[i]; sWs[i] = Ws[i];
    }
    if (threadIdx.x < 6) {
        sbq[threadIdx.x] = bq[threadIdx.x];
        sbk[threadIdx.x] = bk[threadIdx.x];
        sbv[threadIdx.x] = bv[threadIdx.x];
        sbs[threadIdx.x] = bs[threadIdx.x];
    }
    __syncthreads();
    int n = blockIdx.x * blockDim.x + threadIdx.x;
    if (n >= N_NODES) return;
    float qa[6], ka[6], va[6], sa[6];
#pragma unroll
    for (int c = 0; c < 6; ++c) { qa[c] = sbq[c]; ka[c] = sbk[c]; va[c] = sbv[c]; sa[c] = sbs[c]; }
    const float4* hp = reinterpret_cast<const float4*>(h1 + (size_t)n * 64);
#pragma unroll
    for (int i4 = 0; i4 < 16; ++i4) {
        float4 hv = hp[i4];
        float hvv[4] = {hv.x, hv.y, hv.z, hv.w};
#pragma unroll
        for (int u = 0; u < 4; ++u) {
            float hx = hvv[u];
            int i = i4 * 4 + u;
#pragma unroll
            for (int c = 0; c < 6; ++c) {
                qa[c] += hx * sWq[i * 6 + c];
                ka[c] += hx * sWk[i * 6 + c];
                va[c] += hx * sWv[i * 6 + c];
                sa[c] += hx * sWs[i * 6 + c];
            }
        }
    }
#pragma unroll
    for (int c = 0; c < 6; ++c) {
        q2[(size_t)n * 6 + c] = qa[c];
        k2[(size_t)n * 6 + c] = ka[c];
        v2[(size_t)n * 6 + c] = va[c];
        s2[(size_t)n * 6 + c] = sa[c];
    }
}

// ---- G2: fused layer-2 gather + epilogue + LDS-pre-reduced pooling ----
__global__ void g2_layer2(const int* __restrict__ rowstart,
                          const int* __restrict__ csr_src,
                          const float* __restrict__ q2, const float* __restrict__ k2,
                          const float* __restrict__ v2, const float* __restrict__ s2,
                          const int* __restrict__ batch,
                          float* __restrict__ psum, float* __restrict__ pcnt) {
    __shared__ float bsum[N_GRAPHS * 6];
    __shared__ float bcnt[N_GRAPHS];
    for (int i = threadIdx.x; i < N_GRAPHS * 6; i += 256) bsum[i] = 0.f;
    for (int i = threadIdx.x; i < N_GRAPHS; i += 256) bcnt[i] = 0.f;
    __syncthreads();

    int node = blockIdx.x * 16 + (threadIdx.x >> 4);
    int lane16 = threadIdx.x & 15;

    float q[6];
#pragma unroll
    for (int c = 0; c < 6; ++c) q[c] = q2[(size_t)node * 6 + c];
    int row = rowstart[node];
    int deg = rowstart[node + 1] - row;

    float m = NEG_INF, d = 0.f;
    float acc[6] = {0.f, 0.f, 0.f, 0.f, 0.f, 0.f};
    for (int e = lane16; e < deg; e += 16) {
        int src = csr_src[row + e];
        const float* kp = k2 + (size_t)src * 6;
        float dot = q[0] * kp[0] + q[1] * kp[1] + q[2] * kp[2]
                  + q[3] * kp[3] + q[4] * kp[4] + q[5] * kp[5];
        float logit = dot * 0.4082482904638631f;
        float mn = fmaxf(m, logit);
        float sc = __expf(m - mn);
        float a = __expf(logit - mn);
        d = d * sc + a;
        const float* vp = v2 + (size_t)src * 6;
#pragma unroll
        for (int c = 0; c < 6; ++c) acc[c] = acc[c] * sc + a * vp[c];
        m = mn;
    }
#pragma unroll
    for (int off = 1; off <= 8; off <<= 1) {
        float m2 = __shfl_xor(m, off);
        float d2 = __shfl_xor(d, off);
        float a2[6];
#pragma unroll
        for (int c = 0; c < 6; ++c) a2[c] = __shfl_xor(acc[c], off);
        float mn = fmaxf(m, m2);
        float s1 = __expf(m - mn), sc2 = __expf(m2 - mn);
        d = d * s1 + d2 * sc2;
#pragma unroll
        for (int c = 0; c < 6; ++c) acc[c] = acc[c] * s1 + a2[c] * sc2;
        m = mn;
    }

    if (lane16 == 0) {
        float inv = 1.f / (d + 1e-16f);
        int g = batch[node];
#pragma unroll
        for (int c = 0; c < 6; ++c) {
            float val = acc[c] * inv + s2[(size_t)node * 6 + c];
            atomicAdd(&bsum[g * 6 + c], val);
        }
        atomicAdd(&bcnt[g], 1.f);
    }
    __syncthreads();
    for (int i = threadIdx.x; i < N_GRAPHS * 6; i += 256) {
        float v = bsum[i];
        if (v != 0.f) atomAddF(psum + i, v);
    }
    for (int i = threadIdx.x; i < N_GRAPHS; i += 256) {
        float v = bcnt[i];
        if (v != 0.f) atomAddF(pcnt + i, v);
    }
}

// ---- K9: pooled mean + log_softmax ----
__global__ void k9_final(const float* __restrict__ psum, const float* __restrict__ pcnt,
                         float* __restrict__ out) {
    int g = threadIdx.x;
    if (g >= N_GRAPHS) return;
    float cnt = fmaxf(pcnt[g], 1.0f);
    float z[6];
    float mx = -1e30f;
#pragma unroll
    for (int c = 0; c < 6; ++c) {
        z[c] = psum[g * 6 + c] / cnt;
        mx = fmaxf(mx, z[c]);
    }
    float se = 0.f;
#pragma unroll
    for (int c = 0; c < 6; ++c) se += __expf(z[c] - mx);
    float lse = mx + logf(se);
#pragma unroll
    for (int c = 0; c < 6; ++c) out[g * 6 + c] = z[c] - lse;
}

extern "C" void kernel_launch(void* const* d_in, const int* in_sizes, int n_in,
                              void* d_out, int out_size, void* d_ws, size_t ws_size,
                              hipStream_t stream) {
    const float* x   = (const float*)d_in[0];
    const int*   ei  = (const int*)d_in[1];
    const int*   bat = (const int*)d_in[2];
    const float* Wq1 = (const float*)d_in[3];  const float* bq1 = (const float*)d_in[4];
    const float* Wk1 = (const float*)d_in[5];  const float* bk1 = (const float*)d_in[6];
    const float* Wv1 = (const float*)d_in[7];  const float* bv1 = (const float*)d_in[8];
    const float* Ws1 = (const float*)d_in[9];  const float* bs1 = (const float*)d_in[10];
    const float* Wq2 = (const float*)d_in[11]; const float* bq2 = (const float*)d_in[12];
    const float* Wk2 = (const float*)d_in[13]; const float* bk2 = (const float*)d_in[14];
    const float* Wv2 = (const float*)d_in[15]; const float* bv2 = (const float*)d_in[16];
    const float* Ws2 = (const float*)d_in[17]; const float* bs2 = (const float*)d_in[18];
    float* out = (float*)d_out;

    char* ws = (char*)d_ws;
    size_t off = 0;
    auto alloc = [&](size_t bytes) -> char* {
        char* p = ws + off;
        off += (bytes + 255) & ~(size_t)255;
        return p;
    };

    // ---- zero-initialized region (one small memset) ----
    float* psum = (float*)alloc((size_t)N_GRAPHS * 6 * 4);
    float* pcnt = (float*)alloc((size_t)N_GRAPHS * 4);
    size_t zero_bytes = off;

    // ---- uninitialized scratch ----
    int*  counts   = (int*) alloc((size_t)NB * NBLK * 4);
    int2* pairs    = (int2*)alloc((size_t)N_EDGES * 8);
    int*  rowstart = (int*) alloc((size_t)(N_NODES + 1) * 4);
    int*  csr_src  = (int*) alloc((size_t)N_EDGES * 4);
    float* h1      = (float*)alloc((size_t)N_NODES * 64 * 4);
    float* q2      = (float*)alloc((size_t)N_NODES * 6 * 4);
    float* k2      = (float*)alloc((size_t)N_NODES * 6 * 4);
    float* v2      = (float*)alloc((size_t)N_NODES * 6 * 4);
    float* s2      = (float*)alloc((size_t)N_NODES * 6 * 4);

    hipMemsetAsync(d_ws, 0, zero_bytes, stream);

    p1_count<<<NBLK, 256, 0, stream>>>(ei, counts);
    p2_scan<<<1, 1024, 0, stream>>>(counts);
    p3_partition<<<NBLK, 256, 0, stream>>>(ei, counts, pairs);
    p4_build<<<NB, 1024, 0, stream>>>(pairs, counts, rowstart, csr_src);

    g1_layer1<<<N_NODES / 4, 256, 0, stream>>>(x, Wq1, bq1, Wk1, bk1, Wv1, bv1,
                                               Ws1, bs1, rowstart, csr_src, h1);
    k5_node2<<<(N_NODES + 255) / 256, 256, 0, stream>>>(h1, Wq2, bq2, Wk2, bk2,
                                                        Wv2, bv2, Ws2, bs2,
                                                        q2, k2, v2, s2);
    g2_layer2<<<N_NODES / 16, 256, 0, stream>>>(rowstart, csr_src, q2, k2, v2, s2,
                                                bat, psum, pcnt);
    k9_final<<<1, 64, 0, stream>>>(psum, pcnt, out);
}

// Round 4
// 231.023 us; speedup vs baseline: 22.6816x; 1.3641x over previous
//
#include <hip/hip_runtime.h>
#include <math.h>

#define N_NODES 100000
#define N_EDGES 3200000
#define N_GRAPHS 64
#define NEG_INF -1e30f

// bucket sort geometry: bucket = dst >> 10  (1024 nodes per bucket)
#define NB 98          // ceil(100000/1024)
#define NBLK 512       // partition blocks
#define CHUNK 6250     // 512 * 6250 = 3.2M exactly

__device__ __forceinline__ void atomAddF(float* p, float v) {
#if defined(__HIP_PLATFORM_AMD__)
    unsafeAtomicAdd(p, v);
#else
    atomicAdd(p, v);
#endif
}

// ---- P1: per-block bucket histogram ----
__global__ void p1_count(const int* __restrict__ ei, int* __restrict__ counts) {
    __shared__ int cnt[NB];
    for (int i = threadIdx.x; i < NB; i += 256) cnt[i] = 0;
    __syncthreads();
    int base = blockIdx.x * CHUNK;
    for (int i = threadIdx.x; i < CHUNK; i += 256) {
        int dst = ei[N_EDGES + base + i];
        atomicAdd(&cnt[dst >> 10], 1);
    }
    __syncthreads();
    for (int i = threadIdx.x; i < NB; i += 256)
        counts[i * NBLK + blockIdx.x] = cnt[i];
}

// ---- P2: single-block exclusive scan of counts[NB*NBLK] in place ----
__global__ void p2_scan(int* __restrict__ counts) {
    __shared__ int part[1024];
    const int per = (NB * NBLK) / 1024;  // 49
    int tid = threadIdx.x;
    int b0 = tid * per;
    int s = 0;
    for (int i = 0; i < per; ++i) s += counts[b0 + i];
    part[tid] = s;
    __syncthreads();
    for (int off = 1; off < 1024; off <<= 1) {
        int v = (tid >= off) ? part[tid - off] : 0;
        __syncthreads();
        part[tid] += v;
        __syncthreads();
    }
    int run = (tid == 0) ? 0 : part[tid - 1];
    for (int i = 0; i < per; ++i) {
        int c = counts[b0 + i];
        counts[b0 + i] = run;
        run += c;
    }
}

// ---- P3: partition (src,dst) pairs into bucket regions ----
__global__ void p3_partition(const int* __restrict__ ei,
                             const int* __restrict__ offsets,
                             int2* __restrict__ pairs) {
    __shared__ int cur[NB];
    for (int i = threadIdx.x; i < NB; i += 256)
        cur[i] = offsets[i * NBLK + blockIdx.x];
    __syncthreads();
    int base = blockIdx.x * CHUNK;
    for (int i = threadIdx.x; i < CHUNK; i += 256) {
        int src = ei[base + i];
        int dst = ei[N_EDGES + base + i];
        int pos = atomicAdd(&cur[dst >> 10], 1);
        pairs[pos] = make_int2(src, dst);
    }
}

// ---- P4: per-bucket exact CSR build (one block per bucket) ----
__global__ void p4_build(const int2* __restrict__ pairs,
                         const int* __restrict__ offsets,
                         int* __restrict__ rowstart, int* __restrict__ csr_src) {
    __shared__ int cnt[1024];
    __shared__ int sc[1024];
    __shared__ int cur[1024];
    int b = blockIdx.x;
    int tid = threadIdx.x;  // blockDim = 1024
    int ebase = offsets[b * NBLK];
    int eend = (b == NB - 1) ? N_EDGES : offsets[(b + 1) * NBLK];
    int ne = eend - ebase;

    cnt[tid] = 0;
    __syncthreads();
    for (int i = tid; i < ne; i += 1024) {
        int dst = pairs[ebase + i].y;
        atomicAdd(&cnt[dst & 1023], 1);
    }
    __syncthreads();
    sc[tid] = cnt[tid];
    __syncthreads();
    for (int off = 1; off < 1024; off <<= 1) {
        int v = (tid >= off) ? sc[tid - off] : 0;
        __syncthreads();
        sc[tid] += v;
        __syncthreads();
    }
    int excl = sc[tid] - cnt[tid];
    cur[tid] = excl;
    int node = (b << 10) + tid;
    if (node < N_NODES) rowstart[node] = ebase + excl;
    if (b == NB - 1 && tid == 0) rowstart[N_NODES] = N_EDGES;
    __syncthreads();
    for (int i = tid; i < ne; i += 1024) {
        int2 p = pairs[ebase + i];
        int pos = ebase + atomicAdd(&cur[p.y & 1023], 1);
        csr_src[pos] = p.x;
    }
}

// ---- G1: fused layer-1 with rank-3 factorization.
// 16 lanes per node (4 edge slots x 4 heads), 4 nodes per wave, 16 per block.
// logit_h = tb_h + sx . t_h  (t precomputed per node);
// V-accumulator is (d, s0,s1,s2) per head; Wv matmul deferred to epilogue.
__global__ void g1_layer1(const float* __restrict__ x,
                          const float* __restrict__ Wq, const float* __restrict__ bq,
                          const float* __restrict__ Wk, const float* __restrict__ bk,
                          const float* __restrict__ Wv, const float* __restrict__ bv,
                          const float* __restrict__ Ws, const float* __restrict__ bs,
                          const int* __restrict__ rowstart,
                          const int* __restrict__ csr_src,
                          float* __restrict__ h1) {
    __shared__ float sWq[192], sWk[192], sWv[192], sWs[192];
    __shared__ float sbq[64], sbk[64], sbv[64], sbs[64];
    for (int i = threadIdx.x; i < 192; i += 256) {
        sWq[i] = Wq[i]; sWk[i] = Wk[i]; sWv[i] = Wv[i]; sWs[i] = Ws[i];
    }
    for (int i = threadIdx.x; i < 64; i += 256) {
        sbq[i] = bq[i]; sbk[i] = bk[i]; sbv[i] = bv[i]; sbs[i] = bs[i];
    }
    __syncthreads();

    int lane = threadIdx.x & 63;
    int u = lane & 15;              // index within node-group
    int slot = u >> 2;              // 4 edge slots
    int j0 = u * 4;                 // this lane's 4 output dims
    int n = blockIdx.x * 16 + (threadIdx.x >> 6) * 4 + (lane >> 4);

    float x0 = x[n * 3], x1 = x[n * 3 + 1], x2 = x[n * 3 + 2];

    // q for dims j0..j0+3, pre-scaled by 1/sqrt(16)
    float q[4];
#pragma unroll
    for (int i = 0; i < 4; ++i)
        q[i] = 0.25f * (sbq[j0 + i] + x0 * sWq[j0 + i] + x1 * sWq[64 + j0 + i]
                        + x2 * sWq[128 + j0 + i]);
    // partial t for head (u>>2)
    float t0 = 0.f, t1 = 0.f, t2 = 0.f, tb = 0.f;
#pragma unroll
    for (int i = 0; i < 4; ++i) {
        float qi = q[i];
        t0 += qi * sWk[j0 + i];
        t1 += qi * sWk[64 + j0 + i];
        t2 += qi * sWk[128 + j0 + i];
        tb += qi * sbk[j0 + i];
    }
#pragma unroll
    for (int off = 1; off <= 2; off <<= 1) {
        t0 += __shfl_xor(t0, off);
        t1 += __shfl_xor(t1, off);
        t2 += __shfl_xor(t2, off);
        tb += __shfl_xor(tb, off);
    }
    // transpose: edge loop wants head = u&3 (currently lane holds head u>>2)
    int tsrc = (lane & 48) | ((lane & 3) << 2) | ((lane >> 2) & 3);
    t0 = __shfl(t0, tsrc, 64);
    t1 = __shfl(t1, tsrc, 64);
    t2 = __shfl(t2, tsrc, 64);
    tb = __shfl(tb, tsrc, 64);

    int row = rowstart[n];
    int deg = rowstart[n + 1] - row;

    float m = NEG_INF, d = 0.f, s0 = 0.f, s1 = 0.f, s2 = 0.f;
    for (int base = 0; base < deg; base += 4) {
        int e = base + slot;
        bool valid = e < deg;
        int src = valid ? csr_src[row + e] : 0;
        float sx0 = x[src * 3], sx1 = x[src * 3 + 1], sx2 = x[src * 3 + 2];
        float logit = valid ? (tb + sx0 * t0 + sx1 * t1 + sx2 * t2) : NEG_INF;
        float mn = fmaxf(m, logit);
        float sc = __expf(m - mn);
        float a = valid ? __expf(logit - mn) : 0.f;
        d = d * sc + a;
        s0 = s0 * sc + a * sx0;
        s1 = s1 * sc + a * sx1;
        s2 = s2 * sc + a * sx2;
        m = mn;
    }

    // merge 4 slots (lane bits 2-3)
#pragma unroll
    for (int off = 4; off <= 8; off <<= 1) {
        float m2 = __shfl_xor(m, off);
        float d2 = __shfl_xor(d, off);
        float s02 = __shfl_xor(s0, off);
        float s12 = __shfl_xor(s1, off);
        float s22 = __shfl_xor(s2, off);
        float mn = fmaxf(m, m2);
        float e1 = __expf(m - mn), e2 = __expf(m2 - mn);
        d = d * e1 + d2 * e2;
        s0 = s0 * e1 + s02 * e2;
        s1 = s1 * e1 + s12 * e2;
        s2 = s2 * e1 + s22 * e2;
        m = mn;
    }

    // epilogue: lane u needs head u>>2's state (held by lane with u&3 == u>>2)
    int esrc = (lane & 48) | ((lane >> 2) & 3);
    float dH = __shfl(d, esrc, 64);
    float s0H = __shfl(s0, esrc, 64);
    float s1H = __shfl(s1, esrc, 64);
    float s2H = __shfl(s2, esrc, 64);
    float inv = 1.f / (dH + 1e-16f);
    float f = dH * inv, r0 = s0H * inv, r1 = s1H * inv, r2 = s2H * inv;

    float4 o;
    float* op = &o.x;
#pragma unroll
    for (int i = 0; i < 4; ++i) {
        int j = j0 + i;
        float val = f * sbv[j] + r0 * sWv[j] + r1 * sWv[64 + j] + r2 * sWv[128 + j]
                  + sbs[j] + x0 * sWs[j] + x1 * sWs[64 + j] + x2 * sWs[128 + j];
        op[i] = fmaxf(val, 0.f);
    }
    *reinterpret_cast<float4*>(h1 + (size_t)n * 64 + j0) = o;
}

// ---- K5: q2,k2,v2,s2 = h1 @ W + b (64 -> 6) ----
__global__ void k5_node2(const float* __restrict__ h1,
                         const float* __restrict__ Wq, const float* __restrict__ bq,
                         const float* __restrict__ Wk, const float* __restrict__ bk,
                         const float* __restrict__ Wv, const float* __restrict__ bv,
                         const float* __restrict__ Ws, const float* __restrict__ bs,
                         float* __restrict__ q2, float* __restrict__ k2,
                         float* __restrict__ v2, float* __restrict__ s2) {
    __shared__ float sWq[384], sWk[384], sWv[384], sWs[384];
    __shared__ float sbq[6], sbk[6], sbv[6], sbs[6];
    for (int i = threadIdx.x; i < 384; i += blockDim.x) {
        sWq[i] = Wq[i]; sWk[i] = Wk[i]; sWv[i] = Wv[i]; sWs[i] = Ws[i];
    }
    if (threadIdx.x < 6) {
        sbq[threadIdx.x] = bq[threadIdx.x];
        sbk[threadIdx.x] = bk[threadIdx.x];
        sbv[threadIdx.x] = bv[threadIdx.x];
        sbs[threadIdx.x] = bs[threadIdx.x];
    }
    __syncthreads();
    int n = blockIdx.x * blockDim.x + threadIdx.x;
    if (n >= N_NODES) return;
    float qa[6], ka[6], va[6], sa[6];
#pragma unroll
    for (int c = 0; c < 6; ++c) { qa[c] = sbq[c]; ka[c] = sbk[c]; va[c] = sbv[c]; sa[c] = sbs[c]; }
    const float4* hp = reinterpret_cast<const float4*>(h1 + (size_t)n * 64);
#pragma unroll
    for (int i4 = 0; i4 < 16; ++i4) {
        float4 hv = hp[i4];
        float hvv[4] = {hv.x, hv.y, hv.z, hv.w};
#pragma unroll
        for (int u = 0; u < 4; ++u) {
            float hx = hvv[u];
            int i = i4 * 4 + u;
#pragma unroll
            for (int c = 0; c < 6; ++c) {
                qa[c] += hx * sWq[i * 6 + c];
                ka[c] += hx * sWk[i * 6 + c];
                va[c] += hx * sWv[i * 6 + c];
                sa[c] += hx * sWs[i * 6 + c];
            }
        }
    }
#pragma unroll
    for (int c = 0; c < 6; ++c) {
        q2[(size_t)n * 6 + c] = qa[c];
        k2[(size_t)n * 6 + c] = ka[c];
        v2[(size_t)n * 6 + c] = va[c];
        s2[(size_t)n * 6 + c] = sa[c];
    }
}

// ---- G2: fused layer-2 gather + epilogue + LDS-pre-reduced pooling ----
__global__ void g2_layer2(const int* __restrict__ rowstart,
                          const int* __restrict__ csr_src,
                          const float* __restrict__ q2, const float* __restrict__ k2,
                          const float* __restrict__ v2, const float* __restrict__ s2,
                          const int* __restrict__ batch,
                          float* __restrict__ psum, float* __restrict__ pcnt) {
    __shared__ float bsum[N_GRAPHS * 6];
    __shared__ float bcnt[N_GRAPHS];
    for (int i = threadIdx.x; i < N_GRAPHS * 6; i += 256) bsum[i] = 0.f;
    for (int i = threadIdx.x; i < N_GRAPHS; i += 256) bcnt[i] = 0.f;
    __syncthreads();

    int node = blockIdx.x * 16 + (threadIdx.x >> 4);
    int lane16 = threadIdx.x & 15;

    float q[6];
#pragma unroll
    for (int c = 0; c < 6; ++c) q[c] = q2[(size_t)node * 6 + c];
    int row = rowstart[node];
    int deg = rowstart[node + 1] - row;

    float m = NEG_INF, d = 0.f;
    float acc[6] = {0.f, 0.f, 0.f, 0.f, 0.f, 0.f};
    for (int e = lane16; e < deg; e += 16) {
        int src = csr_src[row + e];
        const float* kp = k2 + (size_t)src * 6;
        float dot = q[0] * kp[0] + q[1] * kp[1] + q[2] * kp[2]
                  + q[3] * kp[3] + q[4] * kp[4] + q[5] * kp[5];
        float logit = dot * 0.4082482904638631f;
        float mn = fmaxf(m, logit);
        float sc = __expf(m - mn);
        float a = __expf(logit - mn);
        d = d * sc + a;
        const float* vp = v2 + (size_t)src * 6;
#pragma unroll
        for (int c = 0; c < 6; ++c) acc[c] = acc[c] * sc + a * vp[c];
        m = mn;
    }
#pragma unroll
    for (int off = 1; off <= 8; off <<= 1) {
        float m2 = __shfl_xor(m, off);
        float d2 = __shfl_xor(d, off);
        float a2[6];
#pragma unroll
        for (int c = 0; c < 6; ++c) a2[c] = __shfl_xor(acc[c], off);
        float mn = fmaxf(m, m2);
        float e1 = __expf(m - mn), e2 = __expf(m2 - mn);
        d = d * e1 + d2 * e2;
#pragma unroll
        for (int c = 0; c < 6; ++c) acc[c] = acc[c] * e1 + a2[c] * e2;
        m = mn;
    }

    if (lane16 == 0) {
        float inv = 1.f / (d + 1e-16f);
        int g = batch[node];
#pragma unroll
        for (int c = 0; c < 6; ++c) {
            float val = acc[c] * inv + s2[(size_t)node * 6 + c];
            atomicAdd(&bsum[g * 6 + c], val);
        }
        atomicAdd(&bcnt[g], 1.f);
    }
    __syncthreads();
    for (int i = threadIdx.x; i < N_GRAPHS * 6; i += 256) {
        float v = bsum[i];
        if (v != 0.f) atomAddF(psum + i, v);
    }
    for (int i = threadIdx.x; i < N_GRAPHS; i += 256) {
        float v = bcnt[i];
        if (v != 0.f) atomAddF(pcnt + i, v);
    }
}

// ---- K9: pooled mean + log_softmax ----
__global__ void k9_final(const float* __restrict__ psum, const float* __restrict__ pcnt,
                         float* __restrict__ out) {
    int g = threadIdx.x;
    if (g >= N_GRAPHS) return;
    float cnt = fmaxf(pcnt[g], 1.0f);
    float z[6];
    float mx = -1e30f;
#pragma unroll
    for (int c = 0; c < 6; ++c) {
        z[c] = psum[g * 6 + c] / cnt;
        mx = fmaxf(mx, z[c]);
    }
    float se = 0.f;
#pragma unroll
    for (int c = 0; c < 6; ++c) se += __expf(z[c] - mx);
    float lse = mx + logf(se);
#pragma unroll
    for (int c = 0; c < 6; ++c) out[g * 6 + c] = z[c] - lse;
}

extern "C" void kernel_launch(void* const* d_in, const int* in_sizes, int n_in,
                              void* d_out, int out_size, void* d_ws, size_t ws_size,
                              hipStream_t stream) {
    const float* x   = (const float*)d_in[0];
    const int*   ei  = (const int*)d_in[1];
    const int*   bat = (const int*)d_in[2];
    const float* Wq1 = (const float*)d_in[3];  const float* bq1 = (const float*)d_in[4];
    const float* Wk1 = (const float*)d_in[5];  const float* bk1 = (const float*)d_in[6];
    const float* Wv1 = (const float*)d_in[7];  const float* bv1 = (const float*)d_in[8];
    const float* Ws1 = (const float*)d_in[9];  const float* bs1 = (const float*)d_in[10];
    const float* Wq2 = (const float*)d_in[11]; const float* bq2 = (const float*)d_in[12];
    const float* Wk2 = (const float*)d_in[13]; const float* bk2 = (const float*)d_in[14];
    const float* Wv2 = (const float*)d_in[15]; const float* bv2 = (const float*)d_in[16];
    const float* Ws2 = (const float*)d_in[17]; const float* bs2 = (const float*)d_in[18];
    float* out = (float*)d_out;

    char* ws = (char*)d_ws;
    size_t off = 0;
    auto alloc = [&](size_t bytes) -> char* {
        char* p = ws + off;
        off += (bytes + 255) & ~(size_t)255;
        return p;
    };

    float* psum = (float*)alloc((size_t)N_GRAPHS * 6 * 4);
    float* pcnt = (float*)alloc((size_t)N_GRAPHS * 4);
    size_t zero_bytes = off;

    int*  counts   = (int*) alloc((size_t)NB * NBLK * 4);
    int2* pairs    = (int2*)alloc((size_t)N_EDGES * 8);
    int*  rowstart = (int*) alloc((size_t)(N_NODES + 1) * 4);
    int*  csr_src  = (int*) alloc((size_t)N_EDGES * 4);
    float* h1      = (float*)alloc((size_t)N_NODES * 64 * 4);
    float* q2      = (float*)alloc((size_t)N_NODES * 6 * 4);
    float* k2      = (float*)alloc((size_t)N_NODES * 6 * 4);
    float* v2      = (float*)alloc((size_t)N_NODES * 6 * 4);
    float* s2      = (float*)alloc((size_t)N_NODES * 6 * 4);

    hipMemsetAsync(d_ws, 0, zero_bytes, stream);

    p1_count<<<NBLK, 256, 0, stream>>>(ei, counts);
    p2_scan<<<1, 1024, 0, stream>>>(counts);
    p3_partition<<<NBLK, 256, 0, stream>>>(ei, counts, pairs);
    p4_build<<<NB, 1024, 0, stream>>>(pairs, counts, rowstart, csr_src);

    g1_layer1<<<N_NODES / 16, 256, 0, stream>>>(x, Wq1, bq1, Wk1, bk1, Wv1, bv1,
                                                Ws1, bs1, rowstart, csr_src, h1);
    k5_node2<<<(N_NODES + 255) / 256, 256, 0, stream>>>(h1, Wq2, bq2, Wk2, bk2,
                                                        Wv2, bv2, Ws2, bs2,
                                                        q2, k2, v2, s2);
    g2_layer2<<<N_NODES / 16, 256, 0, stream>>>(rowstart, csr_src, q2, k2, v2, s2,
                                                bat, psum, pcnt);
    k9_final<<<1, 64, 0, stream>>>(psum, pcnt, out);
}

// Round 5
// 213.128 us; speedup vs baseline: 24.5860x; 1.0840x over previous
//
#include <hip/hip_runtime.h>
#include <hip/hip_fp16.h>
#include <math.h>

#define N_NODES 100000
#define N_EDGES 3200000
#define N_GRAPHS 64
#define NEG_INF -1e30f

// bucket sort geometry: bucket = dst >> 10  (1024 nodes per bucket)
#define NB 98          // ceil(100000/1024)
#define NBLK 512       // partition blocks
#define CHUNK 6250     // 512 * 6250 = 3.2M exactly

__device__ __forceinline__ void atomAddF(float* p, float v) {
#if defined(__HIP_PLATFORM_AMD__)
    unsafeAtomicAdd(p, v);
#else
    atomicAdd(p, v);
#endif
}

// ---- K0: pack x into 16B-aligned float4 rows (one cache line per gather) ----
__global__ void k0_packx(const float* __restrict__ x, float4* __restrict__ xp) {
    int n = blockIdx.x * 256 + threadIdx.x;
    if (n >= N_NODES) return;
    xp[n] = make_float4(x[3 * n], x[3 * n + 1], x[3 * n + 2], 0.f);
}

// ---- P1: per-block bucket histogram ----
__global__ void p1_count(const int* __restrict__ ei, int* __restrict__ counts) {
    __shared__ int cnt[NB];
    for (int i = threadIdx.x; i < NB; i += 256) cnt[i] = 0;
    __syncthreads();
    int base = blockIdx.x * CHUNK;
    for (int i = threadIdx.x; i < CHUNK; i += 256) {
        int dst = ei[N_EDGES + base + i];
        atomicAdd(&cnt[dst >> 10], 1);
    }
    __syncthreads();
    for (int i = threadIdx.x; i < NB; i += 256)
        counts[i * NBLK + blockIdx.x] = cnt[i];
}

// ---- P2: single-block exclusive scan of counts[NB*NBLK] in place ----
__global__ void p2_scan(int* __restrict__ counts) {
    __shared__ int part[1024];
    const int per = (NB * NBLK) / 1024;  // 49
    int tid = threadIdx.x;
    int b0 = tid * per;
    int s = 0;
    for (int i = 0; i < per; ++i) s += counts[b0 + i];
    part[tid] = s;
    __syncthreads();
    for (int off = 1; off < 1024; off <<= 1) {
        int v = (tid >= off) ? part[tid - off] : 0;
        __syncthreads();
        part[tid] += v;
        __syncthreads();
    }
    int run = (tid == 0) ? 0 : part[tid - 1];
    for (int i = 0; i < per; ++i) {
        int c = counts[b0 + i];
        counts[b0 + i] = run;
        run += c;
    }
}

// ---- P3: partition (src,dst) pairs into bucket regions ----
__global__ void p3_partition(const int* __restrict__ ei,
                             const int* __restrict__ offsets,
                             int2* __restrict__ pairs) {
    __shared__ int cur[NB];
    for (int i = threadIdx.x; i < NB; i += 256)
        cur[i] = offsets[i * NBLK + blockIdx.x];
    __syncthreads();
    int base = blockIdx.x * CHUNK;
    for (int i = threadIdx.x; i < CHUNK; i += 256) {
        int src = ei[base + i];
        int dst = ei[N_EDGES + base + i];
        int pos = atomicAdd(&cur[dst >> 10], 1);
        pairs[pos] = make_int2(src, dst);
    }
}

// ---- P4: per-bucket exact CSR build (one block per bucket) ----
__global__ void p4_build(const int2* __restrict__ pairs,
                         const int* __restrict__ offsets,
                         int* __restrict__ rowstart, int* __restrict__ csr_src) {
    __shared__ int cnt[1024];
    __shared__ int sc[1024];
    __shared__ int cur[1024];
    int b = blockIdx.x;
    int tid = threadIdx.x;  // blockDim = 1024
    int ebase = offsets[b * NBLK];
    int eend = (b == NB - 1) ? N_EDGES : offsets[(b + 1) * NBLK];
    int ne = eend - ebase;

    cnt[tid] = 0;
    __syncthreads();
    for (int i = tid; i < ne; i += 1024) {
        int dst = pairs[ebase + i].y;
        atomicAdd(&cnt[dst & 1023], 1);
    }
    __syncthreads();
    sc[tid] = cnt[tid];
    __syncthreads();
    for (int off = 1; off < 1024; off <<= 1) {
        int v = (tid >= off) ? sc[tid - off] : 0;
        __syncthreads();
        sc[tid] += v;
        __syncthreads();
    }
    int excl = sc[tid] - cnt[tid];
    cur[tid] = excl;
    int node = (b << 10) + tid;
    if (node < N_NODES) rowstart[node] = ebase + excl;
    if (b == NB - 1 && tid == 0) rowstart[N_NODES] = N_EDGES;
    __syncthreads();
    for (int i = tid; i < ne; i += 1024) {
        int2 p = pairs[ebase + i];
        int pos = ebase + atomicAdd(&cur[p.y & 1023], 1);
        csr_src[pos] = p.x;
    }
}

// ---- G1: fused layer-1 with rank-3 factorization (xp float4 gathers) ----
__global__ void g1_layer1(const float4* __restrict__ xp,
                          const float* __restrict__ Wq, const float* __restrict__ bq,
                          const float* __restrict__ Wk, const float* __restrict__ bk,
                          const float* __restrict__ Wv, const float* __restrict__ bv,
                          const float* __restrict__ Ws, const float* __restrict__ bs,
                          const int* __restrict__ rowstart,
                          const int* __restrict__ csr_src,
                          float* __restrict__ h1) {
    __shared__ float sWq[192], sWk[192], sWv[192], sWs[192];
    __shared__ float sbq[64], sbk[64], sbv[64], sbs[64];
    for (int i = threadIdx.x; i < 192; i += 256) {
        sWq[i] = Wq[i]; sWk[i] = Wk[i]; sWv[i] = Wv[i]; sWs[i] = Ws[i];
    }
    for (int i = threadIdx.x; i < 64; i += 256) {
        sbq[i] = bq[i]; sbk[i] = bk[i]; sbv[i] = bv[i]; sbs[i] = bs[i];
    }
    __syncthreads();

    int lane = threadIdx.x & 63;
    int u = lane & 15;              // index within node-group
    int slot = u >> 2;              // 4 edge slots
    int j0 = u * 4;                 // this lane's 4 output dims
    int n = blockIdx.x * 16 + (threadIdx.x >> 6) * 4 + (lane >> 4);

    float4 xc = xp[n];
    float x0 = xc.x, x1 = xc.y, x2 = xc.z;

    // q for dims j0..j0+3, pre-scaled by 1/sqrt(16)
    float q[4];
#pragma unroll
    for (int i = 0; i < 4; ++i)
        q[i] = 0.25f * (sbq[j0 + i] + x0 * sWq[j0 + i] + x1 * sWq[64 + j0 + i]
                        + x2 * sWq[128 + j0 + i]);
    // partial t for head (u>>2)
    float t0 = 0.f, t1 = 0.f, t2 = 0.f, tb = 0.f;
#pragma unroll
    for (int i = 0; i < 4; ++i) {
        float qi = q[i];
        t0 += qi * sWk[j0 + i];
        t1 += qi * sWk[64 + j0 + i];
        t2 += qi * sWk[128 + j0 + i];
        tb += qi * sbk[j0 + i];
    }
#pragma unroll
    for (int off = 1; off <= 2; off <<= 1) {
        t0 += __shfl_xor(t0, off);
        t1 += __shfl_xor(t1, off);
        t2 += __shfl_xor(t2, off);
        tb += __shfl_xor(tb, off);
    }
    // transpose: edge loop wants head = u&3 (currently lane holds head u>>2)
    int tsrc = (lane & 48) | ((lane & 3) << 2) | ((lane >> 2) & 3);
    t0 = __shfl(t0, tsrc, 64);
    t1 = __shfl(t1, tsrc, 64);
    t2 = __shfl(t2, tsrc, 64);
    tb = __shfl(tb, tsrc, 64);

    int row = rowstart[n];
    int deg = rowstart[n + 1] - row;

    float m = NEG_INF, d = 0.f, s0 = 0.f, s1 = 0.f, s2 = 0.f;
    for (int base = 0; base < deg; base += 4) {
        int e = base + slot;
        bool valid = e < deg;
        int src = valid ? csr_src[row + e] : 0;
        float4 sx = xp[src];
        float logit = valid ? (tb + sx.x * t0 + sx.y * t1 + sx.z * t2) : NEG_INF;
        float mn = fmaxf(m, logit);
        float sc = __expf(m - mn);
        float a = valid ? __expf(logit - mn) : 0.f;
        d = d * sc + a;
        s0 = s0 * sc + a * sx.x;
        s1 = s1 * sc + a * sx.y;
        s2 = s2 * sc + a * sx.z;
        m = mn;
    }

    // merge 4 slots (lane bits 2-3)
#pragma unroll
    for (int off = 4; off <= 8; off <<= 1) {
        float m2 = __shfl_xor(m, off);
        float d2 = __shfl_xor(d, off);
        float s02 = __shfl_xor(s0, off);
        float s12 = __shfl_xor(s1, off);
        float s22 = __shfl_xor(s2, off);
        float mn = fmaxf(m, m2);
        float e1 = __expf(m - mn), e2 = __expf(m2 - mn);
        d = d * e1 + d2 * e2;
        s0 = s0 * e1 + s02 * e2;
        s1 = s1 * e1 + s12 * e2;
        s2 = s2 * e1 + s22 * e2;
        m = mn;
    }

    // epilogue: lane u needs head u>>2's state (held by lane with u&3 == u>>2)
    int esrc = (lane & 48) | ((lane >> 2) & 3);
    float dH = __shfl(d, esrc, 64);
    float s0H = __shfl(s0, esrc, 64);
    float s1H = __shfl(s1, esrc, 64);
    float s2H = __shfl(s2, esrc, 64);
    float inv = 1.f / (dH + 1e-16f);
    float f = dH * inv, r0 = s0H * inv, r1 = s1H * inv, r2 = s2H * inv;

    float4 o;
    float* op = &o.x;
#pragma unroll
    for (int i = 0; i < 4; ++i) {
        int j = j0 + i;
        float val = f * sbv[j] + r0 * sWv[j] + r1 * sWv[64 + j] + r2 * sWv[128 + j]
                  + sbs[j] + x0 * sWs[j] + x1 * sWs[64 + j] + x2 * sWs[128 + j];
        op[i] = fmaxf(val, 0.f);
    }
    *reinterpret_cast<float4*>(h1 + (size_t)n * 64 + j0) = o;
}

// ---- K5: q2 (pre-scaled), s2 fp32; k2+v2 packed fp16 into 32B rows ----
__global__ void k5_node2(const float* __restrict__ h1,
                         const float* __restrict__ Wq, const float* __restrict__ bq,
                         const float* __restrict__ Wk, const float* __restrict__ bk,
                         const float* __restrict__ Wv, const float* __restrict__ bv,
                         const float* __restrict__ Ws, const float* __restrict__ bs,
                         float* __restrict__ q2, float* __restrict__ s2,
                         unsigned* __restrict__ kv2) {
    __shared__ float sWq[384], sWk[384], sWv[384], sWs[384];
    __shared__ float sbq[6], sbk[6], sbv[6], sbs[6];
    for (int i = threadIdx.x; i < 384; i += blockDim.x) {
        sWq[i] = Wq[i]; sWk[i] = Wk[i]; sWv[i] = Wv[i]; sWs[i] = Ws[i];
    }
    if (threadIdx.x < 6) {
        sbq[threadIdx.x] = bq[threadIdx.x];
        sbk[threadIdx.x] = bk[threadIdx.x];
        sbv[threadIdx.x] = bv[threadIdx.x];
        sbs[threadIdx.x] = bs[threadIdx.x];
    }
    __syncthreads();
    int n = blockIdx.x * blockDim.x + threadIdx.x;
    if (n >= N_NODES) return;
    float qa[6], ka[6], va[6], sa[6];
#pragma unroll
    for (int c = 0; c < 6; ++c) { qa[c] = sbq[c]; ka[c] = sbk[c]; va[c] = sbv[c]; sa[c] = sbs[c]; }
    const float4* hp = reinterpret_cast<const float4*>(h1 + (size_t)n * 64);
#pragma unroll
    for (int i4 = 0; i4 < 16; ++i4) {
        float4 hv = hp[i4];
        float hvv[4] = {hv.x, hv.y, hv.z, hv.w};
#pragma unroll
        for (int u = 0; u < 4; ++u) {
            float hx = hvv[u];
            int i = i4 * 4 + u;
#pragma unroll
            for (int c = 0; c < 6; ++c) {
                qa[c] += hx * sWq[i * 6 + c];
                ka[c] += hx * sWk[i * 6 + c];
                va[c] += hx * sWv[i * 6 + c];
                sa[c] += hx * sWs[i * 6 + c];
            }
        }
    }
    const float rsqrt6 = 0.4082482904638631f;
#pragma unroll
    for (int c = 0; c < 6; ++c) {
        q2[(size_t)n * 6 + c] = qa[c] * rsqrt6;   // pre-scale q
        s2[(size_t)n * 6 + c] = sa[c];
    }
    __half2 h01 = __floats2half2_rn(ka[0], ka[1]);
    __half2 h23 = __floats2half2_rn(ka[2], ka[3]);
    __half2 h45 = __floats2half2_rn(ka[4], ka[5]);
    __half2 g01 = __floats2half2_rn(va[0], va[1]);
    __half2 g23 = __floats2half2_rn(va[2], va[3]);
    __half2 g45 = __floats2half2_rn(va[4], va[5]);
    unsigned* kp = kv2 + ((size_t)n << 3);
    uint4 w;
    w.x = *(unsigned*)&h01; w.y = *(unsigned*)&h23;
    w.z = *(unsigned*)&h45; w.w = *(unsigned*)&g01;
    *(uint4*)kp = w;
    *(uint2*)(kp + 4) = make_uint2(*(unsigned*)&g23, *(unsigned*)&g45);
}

// ---- G2: fused layer-2 gather (fp16 packed kv) + epilogue + pooling ----
__global__ void g2_layer2(const int* __restrict__ rowstart,
                          const int* __restrict__ csr_src,
                          const float* __restrict__ q2,
                          const unsigned* __restrict__ kv2,
                          const float* __restrict__ s2,
                          const int* __restrict__ batch,
                          float* __restrict__ psum, float* __restrict__ pcnt) {
    __shared__ float bsum[N_GRAPHS * 6];
    __shared__ float bcnt[N_GRAPHS];
    for (int i = threadIdx.x; i < N_GRAPHS * 6; i += 256) bsum[i] = 0.f;
    for (int i = threadIdx.x; i < N_GRAPHS; i += 256) bcnt[i] = 0.f;
    __syncthreads();

    int node = blockIdx.x * 16 + (threadIdx.x >> 4);
    int lane16 = threadIdx.x & 15;

    float q[6];
#pragma unroll
    for (int c = 0; c < 6; ++c) q[c] = q2[(size_t)node * 6 + c];
    int row = rowstart[node];
    int deg = rowstart[node + 1] - row;

    float m = NEG_INF, d = 0.f;
    float acc[6] = {0.f, 0.f, 0.f, 0.f, 0.f, 0.f};
    for (int e = lane16; e < deg; e += 16) {
        int src = csr_src[row + e];
        const unsigned* kp = kv2 + ((size_t)src << 3);
        uint4 a = *(const uint4*)kp;
        uint2 b = *(const uint2*)(kp + 4);
        float2 k01 = __half22float2(*(const __half2*)&a.x);
        float2 k23 = __half22float2(*(const __half2*)&a.y);
        float2 k45 = __half22float2(*(const __half2*)&a.z);
        float2 v01 = __half22float2(*(const __half2*)&a.w);
        float2 v23 = __half22float2(*(const __half2*)&b.x);
        float2 v45 = __half22float2(*(const __half2*)&b.y);
        float logit = q[0] * k01.x + q[1] * k01.y + q[2] * k23.x
                    + q[3] * k23.y + q[4] * k45.x + q[5] * k45.y;
        float mn = fmaxf(m, logit);
        float sc = __expf(m - mn);
        float a_ = __expf(logit - mn);
        d = d * sc + a_;
        acc[0] = acc[0] * sc + a_ * v01.x;
        acc[1] = acc[1] * sc + a_ * v01.y;
        acc[2] = acc[2] * sc + a_ * v23.x;
        acc[3] = acc[3] * sc + a_ * v23.y;
        acc[4] = acc[4] * sc + a_ * v45.x;
        acc[5] = acc[5] * sc + a_ * v45.y;
        m = mn;
    }
#pragma unroll
    for (int off = 1; off <= 8; off <<= 1) {
        float m2 = __shfl_xor(m, off);
        float d2 = __shfl_xor(d, off);
        float a2[6];
#pragma unroll
        for (int c = 0; c < 6; ++c) a2[c] = __shfl_xor(acc[c], off);
        float mn = fmaxf(m, m2);
        float e1 = __expf(m - mn), e2 = __expf(m2 - mn);
        d = d * e1 + d2 * e2;
#pragma unroll
        for (int c = 0; c < 6; ++c) acc[c] = acc[c] * e1 + a2[c] * e2;
        m = mn;
    }

    if (lane16 == 0) {
        float inv = 1.f / (d + 1e-16f);
        int g = batch[node];
#pragma unroll
        for (int c = 0; c < 6; ++c) {
            float val = acc[c] * inv + s2[(size_t)node * 6 + c];
            atomicAdd(&bsum[g * 6 + c], val);
        }
        atomicAdd(&bcnt[g], 1.f);
    }
    __syncthreads();
    for (int i = threadIdx.x; i < N_GRAPHS * 6; i += 256) {
        float v = bsum[i];
        if (v != 0.f) atomAddF(psum + i, v);
    }
    for (int i = threadIdx.x; i < N_GRAPHS; i += 256) {
        float v = bcnt[i];
        if (v != 0.f) atomAddF(pcnt + i, v);
    }
}

// ---- K9: pooled mean + log_softmax ----
__global__ void k9_final(const float* __restrict__ psum, const float* __restrict__ pcnt,
                         float* __restrict__ out) {
    int g = threadIdx.x;
    if (g >= N_GRAPHS) return;
    float cnt = fmaxf(pcnt[g], 1.0f);
    float z[6];
    float mx = -1e30f;
#pragma unroll
    for (int c = 0; c < 6; ++c) {
        z[c] = psum[g * 6 + c] / cnt;
        mx = fmaxf(mx, z[c]);
    }
    float se = 0.f;
#pragma unroll
    for (int c = 0; c < 6; ++c) se += __expf(z[c] - mx);
    float lse = mx + logf(se);
#pragma unroll
    for (int c = 0; c < 6; ++c) out[g * 6 + c] = z[c] - lse;
}

extern "C" void kernel_launch(void* const* d_in, const int* in_sizes, int n_in,
                              void* d_out, int out_size, void* d_ws, size_t ws_size,
                              hipStream_t stream) {
    const float* x   = (const float*)d_in[0];
    const int*   ei  = (const int*)d_in[1];
    const int*   bat = (const int*)d_in[2];
    const float* Wq1 = (const float*)d_in[3];  const float* bq1 = (const float*)d_in[4];
    const float* Wk1 = (const float*)d_in[5];  const float* bk1 = (const float*)d_in[6];
    const float* Wv1 = (const float*)d_in[7];  const float* bv1 = (const float*)d_in[8];
    const float* Ws1 = (const float*)d_in[9];  const float* bs1 = (const float*)d_in[10];
    const float* Wq2 = (const float*)d_in[11]; const float* bq2 = (const float*)d_in[12];
    const float* Wk2 = (const float*)d_in[13]; const float* bk2 = (const float*)d_in[14];
    const float* Wv2 = (const float*)d_in[15]; const float* bv2 = (const float*)d_in[16];
    const float* Ws2 = (const float*)d_in[17]; const float* bs2 = (const float*)d_in[18];
    float* out = (float*)d_out;

    char* ws = (char*)d_ws;
    size_t off = 0;
    auto alloc = [&](size_t bytes) -> char* {
        char* p = ws + off;
        off += (bytes + 255) & ~(size_t)255;
        return p;
    };

    float* psum = (float*)alloc((size_t)N_GRAPHS * 6 * 4);
    float* pcnt = (float*)alloc((size_t)N_GRAPHS * 4);
    size_t zero_bytes = off;

    int*  counts   = (int*) alloc((size_t)NB * NBLK * 4);
    int2* pairs    = (int2*)alloc((size_t)N_EDGES * 8);
    int*  rowstart = (int*) alloc((size_t)(N_NODES + 1) * 4);
    int*  csr_src  = (int*) alloc((size_t)N_EDGES * 4);
    float4* xp     = (float4*)alloc((size_t)N_NODES * 16);
    float* h1      = (float*)alloc((size_t)N_NODES * 64 * 4);
    float* q2      = (float*)alloc((size_t)N_NODES * 6 * 4);
    float* s2      = (float*)alloc((size_t)N_NODES * 6 * 4);
    unsigned* kv2  = (unsigned*)alloc((size_t)N_NODES * 32);

    hipMemsetAsync(d_ws, 0, zero_bytes, stream);

    k0_packx<<<(N_NODES + 255) / 256, 256, 0, stream>>>(x, xp);
    p1_count<<<NBLK, 256, 0, stream>>>(ei, counts);
    p2_scan<<<1, 1024, 0, stream>>>(counts);
    p3_partition<<<NBLK, 256, 0, stream>>>(ei, counts, pairs);
    p4_build<<<NB, 1024, 0, stream>>>(pairs, counts, rowstart, csr_src);

    g1_layer1<<<N_NODES / 16, 256, 0, stream>>>(xp, Wq1, bq1, Wk1, bk1, Wv1, bv1,
                                                Ws1, bs1, rowstart, csr_src, h1);
    k5_node2<<<(N_NODES + 255) / 256, 256, 0, stream>>>(h1, Wq2, bq2, Wk2, bk2,
                                                        Wv2, bv2, Ws2, bs2,
                                                        q2, s2, kv2);
    g2_layer2<<<N_NODES / 16, 256, 0, stream>>>(rowstart, csr_src, q2, kv2, s2,
                                                bat, psum, pcnt);
    k9_final<<<1, 64, 0, stream>>>(psum, pcnt, out);
}

// Round 6
// 176.361 us; speedup vs baseline: 29.7117x; 1.2085x over previous
//
#include <hip/hip_runtime.h>
#include <hip/hip_fp16.h>
#include <math.h>

#define N_NODES 100000
#define N_EDGES 3200000
#define N_GRAPHS 64
#define NEG_INF -1e30f

// bucket sort geometry: bucket = dst >> 9  (512 nodes per bucket)
#define NB 196         // ceil(100000/512)
#define CAP 18432      // per-bucket capacity; mean 16384, sigma ~128 -> +16 sigma
#define NBLK 512       // partition blocks
#define CHUNK 6250     // 512 * 6250 = 3.2M exactly

__device__ __forceinline__ void atomAddF(float* p, float v) {
#if defined(__HIP_PLATFORM_AMD__)
    unsafeAtomicAdd(p, v);
#else
    atomicAdd(p, v);
#endif
}

// ---- K0: pack x into 16B-aligned float4 rows ----
__global__ void k0_packx(const float* __restrict__ x, float4* __restrict__ xp) {
    int n = blockIdx.x * 256 + threadIdx.x;
    if (n >= N_NODES) return;
    xp[n] = make_float4(x[3 * n], x[3 * n + 1], x[3 * n + 2], 0.f);
}

// ---- S1: fused count + reserve + partition into fixed-capacity buckets.
// pairs[pos] = (src<<9) | (dst & 511); regions reserved via one global
// atomicAdd per (block,bucket).
__global__ void s1_partition(const int* __restrict__ ei,
                             int* __restrict__ bucket_fill,
                             unsigned* __restrict__ pairs) {
    __shared__ int cnt[NB];
    __shared__ int cur[NB];
    __shared__ unsigned dstbuf[CHUNK];   // 25 KB: cache dst for pass 2
    for (int i = threadIdx.x; i < NB; i += 256) cnt[i] = 0;
    __syncthreads();
    int base = blockIdx.x * CHUNK;
    for (int i = threadIdx.x; i < CHUNK; i += 256) {
        unsigned dst = (unsigned)ei[N_EDGES + base + i];
        dstbuf[i] = dst;
        atomicAdd(&cnt[dst >> 9], 1);
    }
    __syncthreads();
    for (int b = threadIdx.x; b < NB; b += 256) {
        int c = cnt[b];
        int off = c > 0 ? atomicAdd(&bucket_fill[b], c) : 0;
        cur[b] = b * CAP + off;
    }
    __syncthreads();
    for (int i = threadIdx.x; i < CHUNK; i += 256) {
        unsigned dst = dstbuf[i];
        int src = ei[base + i];
        int pos = atomicAdd(&cur[dst >> 9], 1);
        pairs[pos] = ((unsigned)src << 9) | (dst & 511u);
    }
}

// ---- B4: per-bucket exact CSR build (one block of 512 per bucket).
// csr_src stays in the padded per-bucket layout; rs/re give row extents.
__global__ void b4_build(const unsigned* __restrict__ pairs,
                         const int* __restrict__ bucket_fill,
                         int* __restrict__ rs, int* __restrict__ re,
                         int* __restrict__ csr_src) {
    __shared__ int cnt[512];
    __shared__ int sc[512];
    __shared__ int cur[512];
    int b = blockIdx.x;
    int tid = threadIdx.x;   // blockDim = 512
    int rbase = b * CAP;
    int ne = bucket_fill[b];

    cnt[tid] = 0;
    __syncthreads();
    for (int i = tid; i < ne; i += 512)
        atomicAdd(&cnt[pairs[rbase + i] & 511u], 1);
    __syncthreads();
    sc[tid] = cnt[tid];
    __syncthreads();
    for (int off = 1; off < 512; off <<= 1) {
        int v = (tid >= off) ? sc[tid - off] : 0;
        __syncthreads();
        sc[tid] += v;
        __syncthreads();
    }
    int excl = sc[tid] - cnt[tid];
    cur[tid] = rbase + excl;
    int node = (b << 9) + tid;
    if (node < N_NODES) {
        rs[node] = rbase + excl;
        re[node] = rbase + sc[tid];
    }
    __syncthreads();
    for (int i = tid; i < ne; i += 512) {
        unsigned p = pairs[rbase + i];
        int pos = atomicAdd(&cur[p & 511u], 1);
        csr_src[pos] = (int)(p >> 9);
    }
}

// ---- G1: fused layer-1, rank-3 factorization, 2-state ILP.
// 16 lanes per node (4 edge slots x 4 heads), 4 nodes per wave.
__global__ void g1_layer1(const float4* __restrict__ xp,
                          const float* __restrict__ Wq, const float* __restrict__ bq,
                          const float* __restrict__ Wk, const float* __restrict__ bk,
                          const float* __restrict__ Wv, const float* __restrict__ bv,
                          const float* __restrict__ Ws, const float* __restrict__ bs,
                          const int* __restrict__ rs, const int* __restrict__ re,
                          const int* __restrict__ csr_src,
                          float* __restrict__ h1) {
    __shared__ float sWq[192], sWk[192], sWv[192], sWs[192];
    __shared__ float sbq[64], sbk[64], sbv[64], sbs[64];
    for (int i = threadIdx.x; i < 192; i += 256) {
        sWq[i] = Wq[i]; sWk[i] = Wk[i]; sWv[i] = Wv[i]; sWs[i] = Ws[i];
    }
    for (int i = threadIdx.x; i < 64; i += 256) {
        sbq[i] = bq[i]; sbk[i] = bk[i]; sbv[i] = bv[i]; sbs[i] = bs[i];
    }
    __syncthreads();

    int lane = threadIdx.x & 63;
    int u = lane & 15;
    int slot = u >> 2;
    int j0 = u * 4;
    int n = blockIdx.x * 16 + (threadIdx.x >> 6) * 4 + (lane >> 4);

    float4 xc = xp[n];
    float x0 = xc.x, x1 = xc.y, x2 = xc.z;

    float q[4];
#pragma unroll
    for (int i = 0; i < 4; ++i)
        q[i] = 0.25f * (sbq[j0 + i] + x0 * sWq[j0 + i] + x1 * sWq[64 + j0 + i]
                        + x2 * sWq[128 + j0 + i]);
    float t0 = 0.f, t1 = 0.f, t2 = 0.f, tb = 0.f;
#pragma unroll
    for (int i = 0; i < 4; ++i) {
        float qi = q[i];
        t0 += qi * sWk[j0 + i];
        t1 += qi * sWk[64 + j0 + i];
        t2 += qi * sWk[128 + j0 + i];
        tb += qi * sbk[j0 + i];
    }
#pragma unroll
    for (int off = 1; off <= 2; off <<= 1) {
        t0 += __shfl_xor(t0, off);
        t1 += __shfl_xor(t1, off);
        t2 += __shfl_xor(t2, off);
        tb += __shfl_xor(tb, off);
    }
    // transpose: edge loop wants head = u&3
    int tsrc = (lane & 48) | ((lane & 3) << 2) | ((lane >> 2) & 3);
    t0 = __shfl(t0, tsrc, 64);
    t1 = __shfl(t1, tsrc, 64);
    t2 = __shfl(t2, tsrc, 64);
    tb = __shfl(tb, tsrc, 64);

    int row = rs[n];
    int deg = re[n] - row;

    float mA = NEG_INF, dA = 0.f, s0A = 0.f, s1A = 0.f, s2A = 0.f;
    float mB = NEG_INF, dB = 0.f, s0B = 0.f, s1B = 0.f, s2B = 0.f;
    for (int base = 0; base < deg; base += 8) {
        int eA = base + slot, eB = base + 4 + slot;
        bool vA = eA < deg, vB = eB < deg;
        int srcA = vA ? csr_src[row + eA] : 0;
        int srcB = vB ? csr_src[row + eB] : 0;
        float4 xA = xp[srcA];
        float4 xB = xp[srcB];
        float lA = vA ? (tb + xA.x * t0 + xA.y * t1 + xA.z * t2) : NEG_INF;
        float lB = vB ? (tb + xB.x * t0 + xB.y * t1 + xB.z * t2) : NEG_INF;
        float mnA = fmaxf(mA, lA);
        float scA = __expf(mA - mnA);
        float aA = vA ? __expf(lA - mnA) : 0.f;
        dA = dA * scA + aA;
        s0A = s0A * scA + aA * xA.x;
        s1A = s1A * scA + aA * xA.y;
        s2A = s2A * scA + aA * xA.z;
        mA = mnA;
        float mnB = fmaxf(mB, lB);
        float scB = __expf(mB - mnB);
        float aB = vB ? __expf(lB - mnB) : 0.f;
        dB = dB * scB + aB;
        s0B = s0B * scB + aB * xB.x;
        s1B = s1B * scB + aB * xB.y;
        s2B = s2B * scB + aB * xB.z;
        mB = mnB;
    }
    // merge B into A (in-lane)
    float m = fmaxf(mA, mB);
    float fA = __expf(mA - m), fB = __expf(mB - m);
    float d = dA * fA + dB * fB;
    float s0 = s0A * fA + s0B * fB;
    float s1 = s1A * fA + s1B * fB;
    float s2 = s2A * fA + s2B * fB;

    // cross-slot merge: global max, single rescale, butterfly sums
    float gm = m;
    gm = fmaxf(gm, __shfl_xor(gm, 4));
    gm = fmaxf(gm, __shfl_xor(gm, 8));
    float f = __expf(m - gm);
    d *= f; s0 *= f; s1 *= f; s2 *= f;
#pragma unroll
    for (int off = 4; off <= 8; off <<= 1) {
        d += __shfl_xor(d, off);
        s0 += __shfl_xor(s0, off);
        s1 += __shfl_xor(s1, off);
        s2 += __shfl_xor(s2, off);
    }

    // epilogue: lane u needs head u>>2's state (held by lane with u&3 == u>>2)
    int esrc = (lane & 48) | ((lane >> 2) & 3);
    float dH = __shfl(d, esrc, 64);
    float s0H = __shfl(s0, esrc, 64);
    float s1H = __shfl(s1, esrc, 64);
    float s2H = __shfl(s2, esrc, 64);
    float inv = 1.f / (dH + 1e-16f);
    float fr = dH * inv, r0 = s0H * inv, r1 = s1H * inv, r2 = s2H * inv;

    float4 o;
    float* op = &o.x;
#pragma unroll
    for (int i = 0; i < 4; ++i) {
        int j = j0 + i;
        float val = fr * sbv[j] + r0 * sWv[j] + r1 * sWv[64 + j] + r2 * sWv[128 + j]
                  + sbs[j] + x0 * sWs[j] + x1 * sWs[64 + j] + x2 * sWs[128 + j];
        op[i] = fmaxf(val, 0.f);
    }
    *reinterpret_cast<float4*>(h1 + (size_t)n * 64 + j0) = o;
}

// ---- K5: q2 (pre-scaled), s2 fp32; k2+v2 packed fp16 into 32B rows ----
__global__ void k5_node2(const float* __restrict__ h1,
                         const float* __restrict__ Wq, const float* __restrict__ bq,
                         const float* __restrict__ Wk, const float* __restrict__ bk,
                         const float* __restrict__ Wv, const float* __restrict__ bv,
                         const float* __restrict__ Ws, const float* __restrict__ bs,
                         float* __restrict__ q2, float* __restrict__ s2,
                         unsigned* __restrict__ kv2) {
    __shared__ float sWq[384], sWk[384], sWv[384], sWs[384];
    __shared__ float sbq[6], sbk[6], sbv[6], sbs[6];
    for (int i = threadIdx.x; i < 384; i += blockDim.x) {
        sWq[i] = Wq[i]; sWk[i] = Wk[i]; sWv[i] = Wv[i]; sWs[i] = Ws[i];
    }
    if (threadIdx.x < 6) {
        sbq[threadIdx.x] = bq[threadIdx.x];
        sbk[threadIdx.x] = bk[threadIdx.x];
        sbv[threadIdx.x] = bv[threadIdx.x];
        sbs[threadIdx.x] = bs[threadIdx.x];
    }
    __syncthreads();
    int n = blockIdx.x * blockDim.x + threadIdx.x;
    if (n >= N_NODES) return;
    float qa[6], ka[6], va[6], sa[6];
#pragma unroll
    for (int c = 0; c < 6; ++c) { qa[c] = sbq[c]; ka[c] = sbk[c]; va[c] = sbv[c]; sa[c] = sbs[c]; }
    const float4* hp = reinterpret_cast<const float4*>(h1 + (size_t)n * 64);
#pragma unroll
    for (int i4 = 0; i4 < 16; ++i4) {
        float4 hv = hp[i4];
        float hvv[4] = {hv.x, hv.y, hv.z, hv.w};
#pragma unroll
        for (int u = 0; u < 4; ++u) {
            float hx = hvv[u];
            int i = i4 * 4 + u;
#pragma unroll
            for (int c = 0; c < 6; ++c) {
                qa[c] += hx * sWq[i * 6 + c];
                ka[c] += hx * sWk[i * 6 + c];
                va[c] += hx * sWv[i * 6 + c];
                sa[c] += hx * sWs[i * 6 + c];
            }
        }
    }
    const float rsqrt6 = 0.4082482904638631f;
#pragma unroll
    for (int c = 0; c < 6; ++c) {
        q2[(size_t)n * 6 + c] = qa[c] * rsqrt6;
        s2[(size_t)n * 6 + c] = sa[c];
    }
    __half2 h01 = __floats2half2_rn(ka[0], ka[1]);
    __half2 h23 = __floats2half2_rn(ka[2], ka[3]);
    __half2 h45 = __floats2half2_rn(ka[4], ka[5]);
    __half2 g01 = __floats2half2_rn(va[0], va[1]);
    __half2 g23 = __floats2half2_rn(va[2], va[3]);
    __half2 g45 = __floats2half2_rn(va[4], va[5]);
    unsigned* kp = kv2 + ((size_t)n << 3);
    uint4 w;
    w.x = *(unsigned*)&h01; w.y = *(unsigned*)&h23;
    w.z = *(unsigned*)&h45; w.w = *(unsigned*)&g01;
    *(uint4*)kp = w;
    *(uint2*)(kp + 4) = make_uint2(*(unsigned*)&g23, *(unsigned*)&g45);
}

// ---- G2: fused layer-2 gather, 2-state ILP + cheap merge + pooling ----
__global__ void g2_layer2(const int* __restrict__ rs, const int* __restrict__ re,
                          const int* __restrict__ csr_src,
                          const float* __restrict__ q2,
                          const unsigned* __restrict__ kv2,
                          const float* __restrict__ s2,
                          const int* __restrict__ batch,
                          float* __restrict__ psum, float* __restrict__ pcnt) {
    __shared__ float bsum[N_GRAPHS * 6];
    __shared__ float bcnt[N_GRAPHS];
    for (int i = threadIdx.x; i < N_GRAPHS * 6; i += 256) bsum[i] = 0.f;
    for (int i = threadIdx.x; i < N_GRAPHS; i += 256) bcnt[i] = 0.f;
    __syncthreads();

    int node = blockIdx.x * 16 + (threadIdx.x >> 4);
    int lane16 = threadIdx.x & 15;

    float q[6];
#pragma unroll
    for (int c = 0; c < 6; ++c) q[c] = q2[(size_t)node * 6 + c];
    int row = rs[node];
    int deg = re[node] - row;

    float mA = NEG_INF, dA = 0.f;
    float aA[6] = {0.f, 0.f, 0.f, 0.f, 0.f, 0.f};
    float mB = NEG_INF, dB = 0.f;
    float aB[6] = {0.f, 0.f, 0.f, 0.f, 0.f, 0.f};
    for (int e = lane16; e < deg; e += 32) {
        int e2 = e + 16;
        bool vB = e2 < deg;
        int srcA = csr_src[row + e];
        int srcB = vB ? csr_src[row + e2] : srcA;
        const unsigned* kpA = kv2 + ((size_t)srcA << 3);
        const unsigned* kpB = kv2 + ((size_t)srcB << 3);
        uint4 a4A = *(const uint4*)kpA;
        uint2 b2A = *(const uint2*)(kpA + 4);
        uint4 a4B = *(const uint4*)kpB;
        uint2 b2B = *(const uint2*)(kpB + 4);

        float2 k01 = __half22float2(*(const __half2*)&a4A.x);
        float2 k23 = __half22float2(*(const __half2*)&a4A.y);
        float2 k45 = __half22float2(*(const __half2*)&a4A.z);
        float2 v01 = __half22float2(*(const __half2*)&a4A.w);
        float2 v23 = __half22float2(*(const __half2*)&b2A.x);
        float2 v45 = __half22float2(*(const __half2*)&b2A.y);
        float lA = q[0] * k01.x + q[1] * k01.y + q[2] * k23.x
                 + q[3] * k23.y + q[4] * k45.x + q[5] * k45.y;
        float mnA = fmaxf(mA, lA);
        float scA = __expf(mA - mnA);
        float wA = __expf(lA - mnA);
        dA = dA * scA + wA;
        aA[0] = aA[0] * scA + wA * v01.x;
        aA[1] = aA[1] * scA + wA * v01.y;
        aA[2] = aA[2] * scA + wA * v23.x;
        aA[3] = aA[3] * scA + wA * v23.y;
        aA[4] = aA[4] * scA + wA * v45.x;
        aA[5] = aA[5] * scA + wA * v45.y;
        mA = mnA;

        k01 = __half22float2(*(const __half2*)&a4B.x);
        k23 = __half22float2(*(const __half2*)&a4B.y);
        k45 = __half22float2(*(const __half2*)&a4B.z);
        v01 = __half22float2(*(const __half2*)&a4B.w);
        v23 = __half22float2(*(const __half2*)&b2B.x);
        v45 = __half22float2(*(const __half2*)&b2B.y);
        float lB = vB ? (q[0] * k01.x + q[1] * k01.y + q[2] * k23.x
                       + q[3] * k23.y + q[4] * k45.x + q[5] * k45.y) : NEG_INF;
        float mnB = fmaxf(mB, lB);
        float scB = __expf(mB - mnB);
        float wB = vB ? __expf(lB - mnB) : 0.f;
        dB = dB * scB + wB;
        aB[0] = aB[0] * scB + wB * v01.x;
        aB[1] = aB[1] * scB + wB * v01.y;
        aB[2] = aB[2] * scB + wB * v23.x;
        aB[3] = aB[3] * scB + wB * v23.y;
        aB[4] = aB[4] * scB + wB * v45.x;
        aB[5] = aB[5] * scB + wB * v45.y;
        mB = mnB;
    }
    // merge B into A (in-lane)
    float m = fmaxf(mA, mB);
    float fA = __expf(mA - m), fB = __expf(mB - m);
    float d = dA * fA + dB * fB;
    float acc[6];
#pragma unroll
    for (int c = 0; c < 6; ++c) acc[c] = aA[c] * fA + aB[c] * fB;

    // cross-lane: global max, single rescale, butterfly sums
    float gm = m;
#pragma unroll
    for (int off = 1; off <= 8; off <<= 1) gm = fmaxf(gm, __shfl_xor(gm, off));
    float f = __expf(m - gm);
    d *= f;
#pragma unroll
    for (int c = 0; c < 6; ++c) acc[c] *= f;
#pragma unroll
    for (int off = 1; off <= 8; off <<= 1) {
        d += __shfl_xor(d, off);
#pragma unroll
        for (int c = 0; c < 6; ++c) acc[c] += __shfl_xor(acc[c], off);
    }

    if (lane16 == 0) {
        float inv = 1.f / (d + 1e-16f);
        int g = batch[node];
#pragma unroll
        for (int c = 0; c < 6; ++c) {
            float val = acc[c] * inv + s2[(size_t)node * 6 + c];
            atomicAdd(&bsum[g * 6 + c], val);
        }
        atomicAdd(&bcnt[g], 1.f);
    }
    __syncthreads();
    for (int i = threadIdx.x; i < N_GRAPHS * 6; i += 256) {
        float v = bsum[i];
        if (v != 0.f) atomAddF(psum + i, v);
    }
    for (int i = threadIdx.x; i < N_GRAPHS; i += 256) {
        float v = bcnt[i];
        if (v != 0.f) atomAddF(pcnt + i, v);
    }
}

// ---- K9: pooled mean + log_softmax ----
__global__ void k9_final(const float* __restrict__ psum, const float* __restrict__ pcnt,
                         float* __restrict__ out) {
    int g = threadIdx.x;
    if (g >= N_GRAPHS) return;
    float cnt = fmaxf(pcnt[g], 1.0f);
    float z[6];
    float mx = -1e30f;
#pragma unroll
    for (int c = 0; c < 6; ++c) {
        z[c] = psum[g * 6 + c] / cnt;
        mx = fmaxf(mx, z[c]);
    }
    float se = 0.f;
#pragma unroll
    for (int c = 0; c < 6; ++c) se += __expf(z[c] - mx);
    float lse = mx + logf(se);
#pragma unroll
    for (int c = 0; c < 6; ++c) out[g * 6 + c] = z[c] - lse;
}

extern "C" void kernel_launch(void* const* d_in, const int* in_sizes, int n_in,
                              void* d_out, int out_size, void* d_ws, size_t ws_size,
                              hipStream_t stream) {
    const float* x   = (const float*)d_in[0];
    const int*   ei  = (const int*)d_in[1];
    const int*   bat = (const int*)d_in[2];
    const float* Wq1 = (const float*)d_in[3];  const float* bq1 = (const float*)d_in[4];
    const float* Wk1 = (const float*)d_in[5];  const float* bk1 = (const float*)d_in[6];
    const float* Wv1 = (const float*)d_in[7];  const float* bv1 = (const float*)d_in[8];
    const float* Ws1 = (const float*)d_in[9];  const float* bs1 = (const float*)d_in[10];
    const float* Wq2 = (const float*)d_in[11]; const float* bq2 = (const float*)d_in[12];
    const float* Wk2 = (const float*)d_in[13]; const float* bk2 = (const float*)d_in[14];
    const float* Wv2 = (const float*)d_in[15]; const float* bv2 = (const float*)d_in[16];
    const float* Ws2 = (const float*)d_in[17]; const float* bs2 = (const float*)d_in[18];
    float* out = (float*)d_out;

    char* ws = (char*)d_ws;
    size_t off = 0;
    auto alloc = [&](size_t bytes) -> char* {
        char* p = ws + off;
        off += (bytes + 255) & ~(size_t)255;
        return p;
    };

    // ---- zero-initialized region (one small memset) ----
    float* psum = (float*)alloc((size_t)N_GRAPHS * 6 * 4);
    float* pcnt = (float*)alloc((size_t)N_GRAPHS * 4);
    int* bucket_fill = (int*)alloc((size_t)NB * 4);
    size_t zero_bytes = off;

    // ---- uninitialized scratch ----
    unsigned* pairs   = (unsigned*)alloc((size_t)NB * CAP * 4);
    int*      csr_src = (int*)     alloc((size_t)NB * CAP * 4);
    int*      rsv     = (int*)     alloc((size_t)N_NODES * 4);
    int*      rev     = (int*)     alloc((size_t)N_NODES * 4);
    float4*   xp      = (float4*)  alloc((size_t)N_NODES * 16);
    float*    h1      = (float*)   alloc((size_t)N_NODES * 64 * 4);
    float*    q2      = (float*)   alloc((size_t)N_NODES * 6 * 4);
    float*    s2      = (float*)   alloc((size_t)N_NODES * 6 * 4);
    unsigned* kv2     = (unsigned*)alloc((size_t)N_NODES * 32);

    hipMemsetAsync(d_ws, 0, zero_bytes, stream);

    k0_packx<<<(N_NODES + 255) / 256, 256, 0, stream>>>(x, xp);
    s1_partition<<<NBLK, 256, 0, stream>>>(ei, bucket_fill, pairs);
    b4_build<<<NB, 512, 0, stream>>>(pairs, bucket_fill, rsv, rev, csr_src);

    g1_layer1<<<N_NODES / 16, 256, 0, stream>>>(xp, Wq1, bq1, Wk1, bk1, Wv1, bv1,
                                                Ws1, bs1, rsv, rev, csr_src, h1);
    k5_node2<<<(N_NODES + 255) / 256, 256, 0, stream>>>(h1, Wq2, bq2, Wk2, bk2,
                                                        Wv2, bv2, Ws2, bs2,
                                                        q2, s2, kv2);
    g2_layer2<<<N_NODES / 16, 256, 0, stream>>>(rsv, rev, csr_src, q2, kv2, s2,
                                                bat, psum, pcnt);
    k9_final<<<1, 64, 0, stream>>>(psum, pcnt, out);
}

// Round 7
// 174.247 us; speedup vs baseline: 30.0722x; 1.0121x over previous
//
#include <hip/hip_runtime.h>
#include <hip/hip_fp16.h>
#include <math.h>

#define N_NODES 100000
#define N_EDGES 3200000
#define N_GRAPHS 64
#define NEG_INF -1e30f

// bucket sort geometry: bucket = dst >> 9  (512 nodes per bucket)
#define NB 196         // ceil(100000/512)
#define CAP 18432      // per-bucket capacity; mean 16384 + 16 sigma
#define NBLK 512       // partition blocks
#define CHUNK 6250     // 512 * 6250 = 3.2M exactly

__device__ __forceinline__ void atomAddF(float* p, float v) {
#if defined(__HIP_PLATFORM_AMD__)
    unsafeAtomicAdd(p, v);
#else
    atomicAdd(p, v);
#endif
}

__device__ __forceinline__ float b2f(unsigned w, int sh) {
    return (float)(signed char)(w >> sh);
}

// ---- K0: pack x into float4 (node-own, fp32) and half4 (gather, 8B) ----
__global__ void k0_packx(const float* __restrict__ x, float4* __restrict__ xp,
                         uint2* __restrict__ xh) {
    int n = blockIdx.x * 256 + threadIdx.x;
    if (n >= N_NODES) return;
    float x0 = x[3 * n], x1 = x[3 * n + 1], x2 = x[3 * n + 2];
    xp[n] = make_float4(x0, x1, x2, 0.f);
    __half2 h01 = __floats2half2_rn(x0, x1);
    __half2 h2p = __floats2half2_rn(x2, 0.f);
    xh[n] = make_uint2(*(unsigned*)&h01, *(unsigned*)&h2p);
}

// ---- S1: fused count + reserve + partition into fixed-capacity buckets ----
__global__ void s1_partition(const int* __restrict__ ei,
                             int* __restrict__ bucket_fill,
                             unsigned* __restrict__ pairs) {
    __shared__ int cnt[NB];
    __shared__ int cur[NB];
    __shared__ unsigned dstbuf[CHUNK];   // 25 KB: cache dst for pass 2
    for (int i = threadIdx.x; i < NB; i += 256) cnt[i] = 0;
    __syncthreads();
    int base = blockIdx.x * CHUNK;
    for (int i = threadIdx.x; i < CHUNK; i += 256) {
        unsigned dst = (unsigned)ei[N_EDGES + base + i];
        dstbuf[i] = dst;
        atomicAdd(&cnt[dst >> 9], 1);
    }
    __syncthreads();
    for (int b = threadIdx.x; b < NB; b += 256) {
        int c = cnt[b];
        int off = c > 0 ? atomicAdd(&bucket_fill[b], c) : 0;
        cur[b] = b * CAP + off;
    }
    __syncthreads();
    for (int i = threadIdx.x; i < CHUNK; i += 256) {
        unsigned dst = dstbuf[i];
        int src = ei[base + i];
        int pos = atomicAdd(&cur[dst >> 9], 1);
        pairs[pos] = ((unsigned)src << 9) | (dst & 511u);
    }
}

// ---- B4: per-bucket exact CSR build ----
__global__ void b4_build(const unsigned* __restrict__ pairs,
                         const int* __restrict__ bucket_fill,
                         int* __restrict__ rs, int* __restrict__ re,
                         int* __restrict__ csr_src) {
    __shared__ int cnt[512];
    __shared__ int sc[512];
    __shared__ int cur[512];
    int b = blockIdx.x;
    int tid = threadIdx.x;   // blockDim = 512
    int rbase = b * CAP;
    int ne = bucket_fill[b];

    cnt[tid] = 0;
    __syncthreads();
    for (int i = tid; i < ne; i += 512)
        atomicAdd(&cnt[pairs[rbase + i] & 511u], 1);
    __syncthreads();
    sc[tid] = cnt[tid];
    __syncthreads();
    for (int off = 1; off < 512; off <<= 1) {
        int v = (tid >= off) ? sc[tid - off] : 0;
        __syncthreads();
        sc[tid] += v;
        __syncthreads();
    }
    int excl = sc[tid] - cnt[tid];
    cur[tid] = rbase + excl;
    int node = (b << 9) + tid;
    if (node < N_NODES) {
        rs[node] = rbase + excl;
        re[node] = rbase + sc[tid];
    }
    __syncthreads();
    for (int i = tid; i < ne; i += 512) {
        unsigned p = pairs[rbase + i];
        int pos = atomicAdd(&cur[p & 511u], 1);
        csr_src[pos] = (int)(p >> 9);
    }
}

// ---- G1: fused layer-1, rank-3 factorization, fp16 x-gathers ----
__global__ void g1_layer1(const float4* __restrict__ xp,
                          const uint2* __restrict__ xh,
                          const float* __restrict__ Wq, const float* __restrict__ bq,
                          const float* __restrict__ Wk, const float* __restrict__ bk,
                          const float* __restrict__ Wv, const float* __restrict__ bv,
                          const float* __restrict__ Ws, const float* __restrict__ bs,
                          const int* __restrict__ rs, const int* __restrict__ re,
                          const int* __restrict__ csr_src,
                          float* __restrict__ h1) {
    __shared__ float sWq[192], sWk[192], sWv[192], sWs[192];
    __shared__ float sbq[64], sbk[64], sbv[64], sbs[64];
    for (int i = threadIdx.x; i < 192; i += 256) {
        sWq[i] = Wq[i]; sWk[i] = Wk[i]; sWv[i] = Wv[i]; sWs[i] = Ws[i];
    }
    for (int i = threadIdx.x; i < 64; i += 256) {
        sbq[i] = bq[i]; sbk[i] = bk[i]; sbv[i] = bv[i]; sbs[i] = bs[i];
    }
    __syncthreads();

    int lane = threadIdx.x & 63;
    int u = lane & 15;
    int slot = u >> 2;
    int j0 = u * 4;
    int n = blockIdx.x * 16 + (threadIdx.x >> 6) * 4 + (lane >> 4);

    float4 xc = xp[n];
    float x0 = xc.x, x1 = xc.y, x2 = xc.z;

    float q[4];
#pragma unroll
    for (int i = 0; i < 4; ++i)
        q[i] = 0.25f * (sbq[j0 + i] + x0 * sWq[j0 + i] + x1 * sWq[64 + j0 + i]
                        + x2 * sWq[128 + j0 + i]);
    float t0 = 0.f, t1 = 0.f, t2 = 0.f, tb = 0.f;
#pragma unroll
    for (int i = 0; i < 4; ++i) {
        float qi = q[i];
        t0 += qi * sWk[j0 + i];
        t1 += qi * sWk[64 + j0 + i];
        t2 += qi * sWk[128 + j0 + i];
        tb += qi * sbk[j0 + i];
    }
#pragma unroll
    for (int off = 1; off <= 2; off <<= 1) {
        t0 += __shfl_xor(t0, off);
        t1 += __shfl_xor(t1, off);
        t2 += __shfl_xor(t2, off);
        tb += __shfl_xor(tb, off);
    }
    // transpose: edge loop wants head = u&3
    int tsrc = (lane & 48) | ((lane & 3) << 2) | ((lane >> 2) & 3);
    t0 = __shfl(t0, tsrc, 64);
    t1 = __shfl(t1, tsrc, 64);
    t2 = __shfl(t2, tsrc, 64);
    tb = __shfl(tb, tsrc, 64);

    int row = rs[n];
    int deg = re[n] - row;

    float mA = NEG_INF, dA = 0.f, s0A = 0.f, s1A = 0.f, s2A = 0.f;
    float mB = NEG_INF, dB = 0.f, s0B = 0.f, s1B = 0.f, s2B = 0.f;
    for (int base = 0; base < deg; base += 8) {
        int eA = base + slot, eB = base + 4 + slot;
        bool vA = eA < deg, vB = eB < deg;
        int srcA = vA ? csr_src[row + eA] : 0;
        int srcB = vB ? csr_src[row + eB] : 0;
        uint2 wA = xh[srcA];
        uint2 wB = xh[srcB];
        float2 a01 = __half22float2(*(const __half2*)&wA.x);
        float a2 = __half22float2(*(const __half2*)&wA.y).x;
        float2 b01 = __half22float2(*(const __half2*)&wB.x);
        float b2 = __half22float2(*(const __half2*)&wB.y).x;
        float lA = vA ? (tb + a01.x * t0 + a01.y * t1 + a2 * t2) : NEG_INF;
        float lB = vB ? (tb + b01.x * t0 + b01.y * t1 + b2 * t2) : NEG_INF;
        float mnA = fmaxf(mA, lA);
        float scA = __expf(mA - mnA);
        float aA = vA ? __expf(lA - mnA) : 0.f;
        dA = dA * scA + aA;
        s0A = s0A * scA + aA * a01.x;
        s1A = s1A * scA + aA * a01.y;
        s2A = s2A * scA + aA * a2;
        mA = mnA;
        float mnB = fmaxf(mB, lB);
        float scB = __expf(mB - mnB);
        float aB = vB ? __expf(lB - mnB) : 0.f;
        dB = dB * scB + aB;
        s0B = s0B * scB + aB * b01.x;
        s1B = s1B * scB + aB * b01.y;
        s2B = s2B * scB + aB * b2;
        mB = mnB;
    }
    // merge B into A (in-lane)
    float m = fmaxf(mA, mB);
    float fA = __expf(mA - m), fB = __expf(mB - m);
    float d = dA * fA + dB * fB;
    float s0 = s0A * fA + s0B * fB;
    float s1 = s1A * fA + s1B * fB;
    float s2 = s2A * fA + s2B * fB;

    // cross-slot merge: global max, single rescale, butterfly sums
    float gm = m;
    gm = fmaxf(gm, __shfl_xor(gm, 4));
    gm = fmaxf(gm, __shfl_xor(gm, 8));
    float f = __expf(m - gm);
    d *= f; s0 *= f; s1 *= f; s2 *= f;
#pragma unroll
    for (int off = 4; off <= 8; off <<= 1) {
        d += __shfl_xor(d, off);
        s0 += __shfl_xor(s0, off);
        s1 += __shfl_xor(s1, off);
        s2 += __shfl_xor(s2, off);
    }

    // epilogue: lane u needs head u>>2's state
    int esrc = (lane & 48) | ((lane >> 2) & 3);
    float dH = __shfl(d, esrc, 64);
    float s0H = __shfl(s0, esrc, 64);
    float s1H = __shfl(s1, esrc, 64);
    float s2H = __shfl(s2, esrc, 64);
    float inv = 1.f / (dH + 1e-16f);
    float fr = dH * inv, r0 = s0H * inv, r1 = s1H * inv, r2 = s2H * inv;

    float4 o;
    float* op = &o.x;
#pragma unroll
    for (int i = 0; i < 4; ++i) {
        int j = j0 + i;
        float val = fr * sbv[j] + r0 * sWv[j] + r1 * sWv[64 + j] + r2 * sWv[128 + j]
                  + sbs[j] + x0 * sWs[j] + x1 * sWs[64 + j] + x2 * sWs[128 + j];
        op[i] = fmaxf(val, 0.f);
    }
    *reinterpret_cast<float4*>(h1 + (size_t)n * 64 + j0) = o;
}

// ---- K5: q2 (pre-scaled) + s2 fp32; k2/v2 int8-quantized into ONE 16B row ----
// kv2[n] = {k0..k5, v0..v5 int8, scale_k fp16, scale_v fp16}
__global__ void k5_node2(const float* __restrict__ h1,
                         const float* __restrict__ Wq, const float* __restrict__ bq,
                         const float* __restrict__ Wk, const float* __restrict__ bk,
                         const float* __restrict__ Wv, const float* __restrict__ bv,
                         const float* __restrict__ Ws, const float* __restrict__ bs,
                         float* __restrict__ q2, float* __restrict__ s2,
                         uint4* __restrict__ kv2) {
    __shared__ float sWq[384], sWk[384], sWv[384], sWs[384];
    __shared__ float sbq[6], sbk[6], sbv[6], sbs[6];
    for (int i = threadIdx.x; i < 384; i += blockDim.x) {
        sWq[i] = Wq[i]; sWk[i] = Wk[i]; sWv[i] = Wv[i]; sWs[i] = Ws[i];
    }
    if (threadIdx.x < 6) {
        sbq[threadIdx.x] = bq[threadIdx.x];
        sbk[threadIdx.x] = bk[threadIdx.x];
        sbv[threadIdx.x] = bv[threadIdx.x];
        sbs[threadIdx.x] = bs[threadIdx.x];
    }
    __syncthreads();
    int n = blockIdx.x * blockDim.x + threadIdx.x;
    if (n >= N_NODES) return;
    float qa[6], ka[6], va[6], sa[6];
#pragma unroll
    for (int c = 0; c < 6; ++c) { qa[c] = sbq[c]; ka[c] = sbk[c]; va[c] = sbv[c]; sa[c] = sbs[c]; }
    const float4* hp = reinterpret_cast<const float4*>(h1 + (size_t)n * 64);
#pragma unroll
    for (int i4 = 0; i4 < 16; ++i4) {
        float4 hv = hp[i4];
        float hvv[4] = {hv.x, hv.y, hv.z, hv.w};
#pragma unroll
        for (int u = 0; u < 4; ++u) {
            float hx = hvv[u];
            int i = i4 * 4 + u;
#pragma unroll
            for (int c = 0; c < 6; ++c) {
                qa[c] += hx * sWq[i * 6 + c];
                ka[c] += hx * sWk[i * 6 + c];
                va[c] += hx * sWv[i * 6 + c];
                sa[c] += hx * sWs[i * 6 + c];
            }
        }
    }
    const float rsqrt6 = 0.4082482904638631f;
#pragma unroll
    for (int c = 0; c < 6; ++c) {
        q2[(size_t)n * 6 + c] = qa[c] * rsqrt6;
        s2[(size_t)n * 6 + c] = sa[c];
    }
    float mk = 0.f, mv = 0.f;
#pragma unroll
    for (int c = 0; c < 6; ++c) {
        mk = fmaxf(mk, fabsf(ka[c]));
        mv = fmaxf(mv, fabsf(va[c]));
    }
    float sk = fmaxf(mk, 1e-8f) * (1.f / 127.f);
    float sv = fmaxf(mv, 1e-8f) * (1.f / 127.f);
    float isk = 1.f / sk, isv = 1.f / sv;
    int qk[6], qv[6];
#pragma unroll
    for (int c = 0; c < 6; ++c) {
        qk[c] = __float2int_rn(ka[c] * isk);
        qv[c] = __float2int_rn(va[c] * isv);
    }
    uint4 w;
    w.x = (qk[0] & 255) | ((qk[1] & 255) << 8) | ((qk[2] & 255) << 16) | ((qk[3] & 255) << 24);
    w.y = (qk[4] & 255) | ((qk[5] & 255) << 8) | ((qv[0] & 255) << 16) | ((qv[1] & 255) << 24);
    w.z = (qv[2] & 255) | ((qv[3] & 255) << 8) | ((qv[4] & 255) << 16) | ((qv[5] & 255) << 24);
    __half2 hs = __floats2half2_rn(sk, sv);
    w.w = *(unsigned*)&hs;
    kv2[n] = w;
}

// ---- G2: fused layer-2 gather (one dwordx4 per edge) + pooling ----
__global__ void g2_layer2(const int* __restrict__ rs, const int* __restrict__ re,
                          const int* __restrict__ csr_src,
                          const float* __restrict__ q2,
                          const uint4* __restrict__ kv2,
                          const float* __restrict__ s2,
                          const int* __restrict__ batch,
                          float* __restrict__ psum, float* __restrict__ pcnt) {
    __shared__ float bsum[N_GRAPHS * 6];
    __shared__ float bcnt[N_GRAPHS];
    for (int i = threadIdx.x; i < N_GRAPHS * 6; i += 256) bsum[i] = 0.f;
    for (int i = threadIdx.x; i < N_GRAPHS; i += 256) bcnt[i] = 0.f;
    __syncthreads();

    int node = blockIdx.x * 16 + (threadIdx.x >> 4);
    int lane16 = threadIdx.x & 15;

    float q[6];
#pragma unroll
    for (int c = 0; c < 6; ++c) q[c] = q2[(size_t)node * 6 + c];
    int row = rs[node];
    int deg = re[node] - row;

    float mA = NEG_INF, dA = 0.f;
    float aA[6] = {0.f, 0.f, 0.f, 0.f, 0.f, 0.f};
    float mB = NEG_INF, dB = 0.f;
    float aB[6] = {0.f, 0.f, 0.f, 0.f, 0.f, 0.f};
    for (int e = lane16; e < deg; e += 32) {
        int e2 = e + 16;
        bool vB = e2 < deg;
        int srcA = csr_src[row + e];
        int srcB = vB ? csr_src[row + e2] : srcA;
        uint4 wA = kv2[srcA];
        uint4 wB = kv2[srcB];

        float2 sAB = __half22float2(*(const __half2*)&wA.w);
        float lA = sAB.x * (q[0] * b2f(wA.x, 0) + q[1] * b2f(wA.x, 8)
                          + q[2] * b2f(wA.x, 16) + q[3] * b2f(wA.x, 24)
                          + q[4] * b2f(wA.y, 0) + q[5] * b2f(wA.y, 8));
        float mnA = fmaxf(mA, lA);
        float scA = __expf(mA - mnA);
        float wgtA = __expf(lA - mnA);
        float wsA = wgtA * sAB.y;
        dA = dA * scA + wgtA;
        aA[0] = aA[0] * scA + wsA * b2f(wA.y, 16);
        aA[1] = aA[1] * scA + wsA * b2f(wA.y, 24);
        aA[2] = aA[2] * scA + wsA * b2f(wA.z, 0);
        aA[3] = aA[3] * scA + wsA * b2f(wA.z, 8);
        aA[4] = aA[4] * scA + wsA * b2f(wA.z, 16);
        aA[5] = aA[5] * scA + wsA * b2f(wA.z, 24);
        mA = mnA;

        float2 sB2 = __half22float2(*(const __half2*)&wB.w);
        float lB = vB ? (sB2.x * (q[0] * b2f(wB.x, 0) + q[1] * b2f(wB.x, 8)
                                + q[2] * b2f(wB.x, 16) + q[3] * b2f(wB.x, 24)
                                + q[4] * b2f(wB.y, 0) + q[5] * b2f(wB.y, 8)))
                       : NEG_INF;
        float mnB = fmaxf(mB, lB);
        float scB = __expf(mB - mnB);
        float wgtB = vB ? __expf(lB - mnB) : 0.f;
        float wsB = wgtB * sB2.y;
        dB = dB * scB + wgtB;
        aB[0] = aB[0] * scB + wsB * b2f(wB.y, 16);
        aB[1] = aB[1] * scB + wsB * b2f(wB.y, 24);
        aB[2] = aB[2] * scB + wsB * b2f(wB.z, 0);
        aB[3] = aB[3] * scB + wsB * b2f(wB.z, 8);
        aB[4] = aB[4] * scB + wsB * b2f(wB.z, 16);
        aB[5] = aB[5] * scB + wsB * b2f(wB.z, 24);
        mB = mnB;
    }
    // merge B into A (in-lane)
    float m = fmaxf(mA, mB);
    float fA = __expf(mA - m), fB = __expf(mB - m);
    float d = dA * fA + dB * fB;
    float acc[6];
#pragma unroll
    for (int c = 0; c < 6; ++c) acc[c] = aA[c] * fA + aB[c] * fB;

    // cross-lane: global max, single rescale, butterfly sums
    float gm = m;
#pragma unroll
    for (int off = 1; off <= 8; off <<= 1) gm = fmaxf(gm, __shfl_xor(gm, off));
    float f = __expf(m - gm);
    d *= f;
#pragma unroll
    for (int c = 0; c < 6; ++c) acc[c] *= f;
#pragma unroll
    for (int off = 1; off <= 8; off <<= 1) {
        d += __shfl_xor(d, off);
#pragma unroll
        for (int c = 0; c < 6; ++c) acc[c] += __shfl_xor(acc[c], off);
    }

    if (lane16 == 0) {
        float inv = 1.f / (d + 1e-16f);
        int g = batch[node];
#pragma unroll
        for (int c = 0; c < 6; ++c) {
            float val = acc[c] * inv + s2[(size_t)node * 6 + c];
            atomicAdd(&bsum[g * 6 + c], val);
        }
        atomicAdd(&bcnt[g], 1.f);
    }
    __syncthreads();
    for (int i = threadIdx.x; i < N_GRAPHS * 6; i += 256) {
        float v = bsum[i];
        if (v != 0.f) atomAddF(psum + i, v);
    }
    for (int i = threadIdx.x; i < N_GRAPHS; i += 256) {
        float v = bcnt[i];
        if (v != 0.f) atomAddF(pcnt + i, v);
    }
}

// ---- K9: pooled mean + log_softmax ----
__global__ void k9_final(const float* __restrict__ psum, const float* __restrict__ pcnt,
                         float* __restrict__ out) {
    int g = threadIdx.x;
    if (g >= N_GRAPHS) return;
    float cnt = fmaxf(pcnt[g], 1.0f);
    float z[6];
    float mx = -1e30f;
#pragma unroll
    for (int c = 0; c < 6; ++c) {
        z[c] = psum[g * 6 + c] / cnt;
        mx = fmaxf(mx, z[c]);
    }
    float se = 0.f;
#pragma unroll
    for (int c = 0; c < 6; ++c) se += __expf(z[c] - mx);
    float lse = mx + logf(se);
#pragma unroll
    for (int c = 0; c < 6; ++c) out[g * 6 + c] = z[c] - lse;
}

extern "C" void kernel_launch(void* const* d_in, const int* in_sizes, int n_in,
                              void* d_out, int out_size, void* d_ws, size_t ws_size,
                              hipStream_t stream) {
    const float* x   = (const float*)d_in[0];
    const int*   ei  = (const int*)d_in[1];
    const int*   bat = (const int*)d_in[2];
    const float* Wq1 = (const float*)d_in[3];  const float* bq1 = (const float*)d_in[4];
    const float* Wk1 = (const float*)d_in[5];  const float* bk1 = (const float*)d_in[6];
    const float* Wv1 = (const float*)d_in[7];  const float* bv1 = (const float*)d_in[8];
    const float* Ws1 = (const float*)d_in[9];  const float* bs1 = (const float*)d_in[10];
    const float* Wq2 = (const float*)d_in[11]; const float* bq2 = (const float*)d_in[12];
    const float* Wk2 = (const float*)d_in[13]; const float* bk2 = (const float*)d_in[14];
    const float* Wv2 = (const float*)d_in[15]; const float* bv2 = (const float*)d_in[16];
    const float* Ws2 = (const float*)d_in[17]; const float* bs2 = (const float*)d_in[18];
    float* out = (float*)d_out;

    char* ws = (char*)d_ws;
    size_t off = 0;
    auto alloc = [&](size_t bytes) -> char* {
        char* p = ws + off;
        off += (bytes + 255) & ~(size_t)255;
        return p;
    };

    // ---- zero-initialized region (one small memset) ----
    float* psum = (float*)alloc((size_t)N_GRAPHS * 6 * 4);
    float* pcnt = (float*)alloc((size_t)N_GRAPHS * 4);
    int* bucket_fill = (int*)alloc((size_t)NB * 4);
    size_t zero_bytes = off;

    // ---- uninitialized scratch ----
    unsigned* pairs   = (unsigned*)alloc((size_t)NB * CAP * 4);
    int*      csr_src = (int*)     alloc((size_t)NB * CAP * 4);
    int*      rsv     = (int*)     alloc((size_t)N_NODES * 4);
    int*      rev     = (int*)     alloc((size_t)N_NODES * 4);
    float4*   xp      = (float4*)  alloc((size_t)N_NODES * 16);
    uint2*    xh      = (uint2*)   alloc((size_t)N_NODES * 8);
    float*    h1      = (float*)   alloc((size_t)N_NODES * 64 * 4);
    float*    q2      = (float*)   alloc((size_t)N_NODES * 6 * 4);
    float*    s2      = (float*)   alloc((size_t)N_NODES * 6 * 4);
    uint4*    kv2     = (uint4*)   alloc((size_t)N_NODES * 16);

    hipMemsetAsync(d_ws, 0, zero_bytes, stream);

    k0_packx<<<(N_NODES + 255) / 256, 256, 0, stream>>>(x, xp, xh);
    s1_partition<<<NBLK, 256, 0, stream>>>(ei, bucket_fill, pairs);
    b4_build<<<NB, 512, 0, stream>>>(pairs, bucket_fill, rsv, rev, csr_src);

    g1_layer1<<<N_NODES / 16, 256, 0, stream>>>(xp, xh, Wq1, bq1, Wk1, bk1, Wv1, bv1,
                                                Ws1, bs1, rsv, rev, csr_src, h1);
    k5_node2<<<(N_NODES + 255) / 256, 256, 0, stream>>>(h1, Wq2, bq2, Wk2, bk2,
                                                        Wv2, bv2, Ws2, bs2,
                                                        q2, s2, kv2);
    g2_layer2<<<N_NODES / 16, 256, 0, stream>>>(rsv, rev, csr_src, q2, kv2, s2,
                                                bat, psum, pcnt);
    k9_final<<<1, 64, 0, stream>>>(psum, pcnt, out);
}

// Round 8
// 168.520 us; speedup vs baseline: 31.0942x; 1.0340x over previous
//
#include <hip/hip_runtime.h>
#include <hip/hip_fp16.h>
#include <math.h>

#define N_NODES 100000
#define N_EDGES 3200000
#define N_GRAPHS 64
#define NEG_INF -1e30f

// bucket sort geometry: bucket = dst >> 9  (512 nodes per bucket)
#define NB 196         // ceil(100000/512)
#define CAP 18432      // per-bucket capacity; mean 16384 + 16 sigma
#define NBLK 1024      // partition blocks
#define CHUNK 3125     // 1024 * 3125 = 3.2M exactly

__device__ __forceinline__ void atomAddF(float* p, float v) {
#if defined(__HIP_PLATFORM_AMD__)
    unsafeAtomicAdd(p, v);
#else
    atomicAdd(p, v);
#endif
}

__device__ __forceinline__ float b2f(unsigned w, int sh) {
    return (float)(signed char)(w >> sh);
}

// logit from packed kv row; also extracts v-scale
__device__ __forceinline__ float kvdot(const float* q, uint4 w, float* sv_out) {
    float2 s = __half22float2(*(const __half2*)&w.w);
    *sv_out = s.y;
    return s.x * (q[0] * b2f(w.x, 0) + q[1] * b2f(w.x, 8)
                + q[2] * b2f(w.x, 16) + q[3] * b2f(w.x, 24)
                + q[4] * b2f(w.y, 0) + q[5] * b2f(w.y, 8));
}

// ---- K0: pack x into float4 (node-own, fp32) and half4 (gather, 8B) ----
__global__ void k0_packx(const float* __restrict__ x, float4* __restrict__ xp,
                         uint2* __restrict__ xh) {
    int n = blockIdx.x * 256 + threadIdx.x;
    if (n >= N_NODES) return;
    float x0 = x[3 * n], x1 = x[3 * n + 1], x2 = x[3 * n + 2];
    xp[n] = make_float4(x0, x1, x2, 0.f);
    __half2 h01 = __floats2half2_rn(x0, x1);
    __half2 h2p = __floats2half2_rn(x2, 0.f);
    xh[n] = make_uint2(*(unsigned*)&h01, *(unsigned*)&h2p);
}

// ---- S1: fused count + reserve + partition (no dst cache; L2-hot re-read) ----
__global__ void s1_partition(const int* __restrict__ ei,
                             int* __restrict__ bucket_fill,
                             unsigned* __restrict__ pairs) {
    __shared__ int cnt[NB];
    __shared__ int cur[NB];
    for (int i = threadIdx.x; i < NB; i += 256) cnt[i] = 0;
    __syncthreads();
    int base = blockIdx.x * CHUNK;
    for (int i = threadIdx.x; i < CHUNK; i += 256) {
        unsigned dst = (unsigned)ei[N_EDGES + base + i];
        atomicAdd(&cnt[dst >> 9], 1);
    }
    __syncthreads();
    for (int b = threadIdx.x; b < NB; b += 256) {
        int c = cnt[b];
        int off = c > 0 ? atomicAdd(&bucket_fill[b], c) : 0;
        cur[b] = b * CAP + off;
    }
    __syncthreads();
    for (int i = threadIdx.x; i < CHUNK; i += 256) {
        unsigned dst = (unsigned)ei[N_EDGES + base + i];
        int src = ei[base + i];
        int pos = atomicAdd(&cur[dst >> 9], 1);
        pairs[pos] = ((unsigned)src << 9) | (dst & 511u);
    }
}

// ---- B4: per-bucket exact CSR build ----
__global__ void b4_build(const unsigned* __restrict__ pairs,
                         const int* __restrict__ bucket_fill,
                         int* __restrict__ rs, int* __restrict__ re,
                         int* __restrict__ csr_src) {
    __shared__ int cnt[512];
    __shared__ int sc[512];
    __shared__ int cur[512];
    int b = blockIdx.x;
    int tid = threadIdx.x;   // blockDim = 512
    int rbase = b * CAP;
    int ne = bucket_fill[b];

    cnt[tid] = 0;
    __syncthreads();
    for (int i = tid; i < ne; i += 512)
        atomicAdd(&cnt[pairs[rbase + i] & 511u], 1);
    __syncthreads();
    sc[tid] = cnt[tid];
    __syncthreads();
    for (int off = 1; off < 512; off <<= 1) {
        int v = (tid >= off) ? sc[tid - off] : 0;
        __syncthreads();
        sc[tid] += v;
        __syncthreads();
    }
    int excl = sc[tid] - cnt[tid];
    cur[tid] = rbase + excl;
    int node = (b << 9) + tid;
    if (node < N_NODES) {
        rs[node] = rbase + excl;
        re[node] = rbase + sc[tid];
    }
    __syncthreads();
    for (int i = tid; i < ne; i += 512) {
        unsigned p = pairs[rbase + i];
        int pos = atomicAdd(&cur[p & 511u], 1);
        csr_src[pos] = (int)(p >> 9);
    }
}

// ---- G1: fused layer-1, rank-3 factorization, fp16 x-gathers, fp16 h1 out ----
__global__ void g1_layer1(const float4* __restrict__ xp,
                          const uint2* __restrict__ xh,
                          const float* __restrict__ Wq, const float* __restrict__ bq,
                          const float* __restrict__ Wk, const float* __restrict__ bk,
                          const float* __restrict__ Wv, const float* __restrict__ bv,
                          const float* __restrict__ Ws, const float* __restrict__ bs,
                          const int* __restrict__ rs, const int* __restrict__ re,
                          const int* __restrict__ csr_src,
                          uint2* __restrict__ h1) {
    __shared__ float sWq[192], sWk[192], sWv[192], sWs[192];
    __shared__ float sbq[64], sbk[64], sbv[64], sbs[64];
    for (int i = threadIdx.x; i < 192; i += 256) {
        sWq[i] = Wq[i]; sWk[i] = Wk[i]; sWv[i] = Wv[i]; sWs[i] = Ws[i];
    }
    for (int i = threadIdx.x; i < 64; i += 256) {
        sbq[i] = bq[i]; sbk[i] = bk[i]; sbv[i] = bv[i]; sbs[i] = bs[i];
    }
    __syncthreads();

    int lane = threadIdx.x & 63;
    int u = lane & 15;
    int slot = u >> 2;
    int j0 = u * 4;
    int n = blockIdx.x * 16 + (threadIdx.x >> 6) * 4 + (lane >> 4);

    float4 xc = xp[n];
    float x0 = xc.x, x1 = xc.y, x2 = xc.z;

    float q[4];
#pragma unroll
    for (int i = 0; i < 4; ++i)
        q[i] = 0.25f * (sbq[j0 + i] + x0 * sWq[j0 + i] + x1 * sWq[64 + j0 + i]
                        + x2 * sWq[128 + j0 + i]);
    float t0 = 0.f, t1 = 0.f, t2 = 0.f, tb = 0.f;
#pragma unroll
    for (int i = 0; i < 4; ++i) {
        float qi = q[i];
        t0 += qi * sWk[j0 + i];
        t1 += qi * sWk[64 + j0 + i];
        t2 += qi * sWk[128 + j0 + i];
        tb += qi * sbk[j0 + i];
    }
#pragma unroll
    for (int off = 1; off <= 2; off <<= 1) {
        t0 += __shfl_xor(t0, off);
        t1 += __shfl_xor(t1, off);
        t2 += __shfl_xor(t2, off);
        tb += __shfl_xor(tb, off);
    }
    // transpose: edge loop wants head = u&3
    int tsrc = (lane & 48) | ((lane & 3) << 2) | ((lane >> 2) & 3);
    t0 = __shfl(t0, tsrc, 64);
    t1 = __shfl(t1, tsrc, 64);
    t2 = __shfl(t2, tsrc, 64);
    tb = __shfl(tb, tsrc, 64);

    int row = rs[n];
    int deg = re[n] - row;

    float mA = NEG_INF, dA = 0.f, s0A = 0.f, s1A = 0.f, s2A = 0.f;
    float mB = NEG_INF, dB = 0.f, s0B = 0.f, s1B = 0.f, s2B = 0.f;
    for (int base = 0; base < deg; base += 8) {
        int eA = base + slot, eB = base + 4 + slot;
        bool vA = eA < deg, vB = eB < deg;
        int srcA = vA ? csr_src[row + eA] : 0;
        int srcB = vB ? csr_src[row + eB] : 0;
        uint2 wA = xh[srcA];
        uint2 wB = xh[srcB];
        float2 a01 = __half22float2(*(const __half2*)&wA.x);
        float a2 = __half22float2(*(const __half2*)&wA.y).x;
        float2 b01 = __half22float2(*(const __half2*)&wB.x);
        float b2 = __half22float2(*(const __half2*)&wB.y).x;
        float lA = vA ? (tb + a01.x * t0 + a01.y * t1 + a2 * t2) : NEG_INF;
        float lB = vB ? (tb + b01.x * t0 + b01.y * t1 + b2 * t2) : NEG_INF;
        float mnA = fmaxf(mA, lA);
        float scA = __expf(mA - mnA);
        float aA = vA ? __expf(lA - mnA) : 0.f;
        dA = dA * scA + aA;
        s0A = s0A * scA + aA * a01.x;
        s1A = s1A * scA + aA * a01.y;
        s2A = s2A * scA + aA * a2;
        mA = mnA;
        float mnB = fmaxf(mB, lB);
        float scB = __expf(mB - mnB);
        float aB = vB ? __expf(lB - mnB) : 0.f;
        dB = dB * scB + aB;
        s0B = s0B * scB + aB * b01.x;
        s1B = s1B * scB + aB * b01.y;
        s2B = s2B * scB + aB * b2;
        mB = mnB;
    }
    // merge B into A (in-lane)
    float m = fmaxf(mA, mB);
    float fA = __expf(mA - m), fB = __expf(mB - m);
    float d = dA * fA + dB * fB;
    float s0 = s0A * fA + s0B * fB;
    float s1 = s1A * fA + s1B * fB;
    float s2 = s2A * fA + s2B * fB;

    // cross-slot merge: global max, single rescale, butterfly sums
    float gm = m;
    gm = fmaxf(gm, __shfl_xor(gm, 4));
    gm = fmaxf(gm, __shfl_xor(gm, 8));
    float f = __expf(m - gm);
    d *= f; s0 *= f; s1 *= f; s2 *= f;
#pragma unroll
    for (int off = 4; off <= 8; off <<= 1) {
        d += __shfl_xor(d, off);
        s0 += __shfl_xor(s0, off);
        s1 += __shfl_xor(s1, off);
        s2 += __shfl_xor(s2, off);
    }

    // epilogue: lane u needs head u>>2's state
    int esrc = (lane & 48) | ((lane >> 2) & 3);
    float dH = __shfl(d, esrc, 64);
    float s0H = __shfl(s0, esrc, 64);
    float s1H = __shfl(s1, esrc, 64);
    float s2H = __shfl(s2, esrc, 64);
    float inv = 1.f / (dH + 1e-16f);
    float fr = dH * inv, r0 = s0H * inv, r1 = s1H * inv, r2 = s2H * inv;

    float o[4];
#pragma unroll
    for (int i = 0; i < 4; ++i) {
        int j = j0 + i;
        float val = fr * sbv[j] + r0 * sWv[j] + r1 * sWv[64 + j] + r2 * sWv[128 + j]
                  + sbs[j] + x0 * sWs[j] + x1 * sWs[64 + j] + x2 * sWs[128 + j];
        o[i] = fmaxf(val, 0.f);
    }
    __half2 p01 = __floats2half2_rn(o[0], o[1]);
    __half2 p23 = __floats2half2_rn(o[2], o[3]);
    h1[(size_t)n * 16 + u] = make_uint2(*(unsigned*)&p01, *(unsigned*)&p23);
}

// ---- K5: reads fp16 h1; q2 (pre-scaled) + s2 fp32; kv2 int8 16B rows ----
__global__ void k5_node2(const unsigned* __restrict__ h1,
                         const float* __restrict__ Wq, const float* __restrict__ bq,
                         const float* __restrict__ Wk, const float* __restrict__ bk,
                         const float* __restrict__ Wv, const float* __restrict__ bv,
                         const float* __restrict__ Ws, const float* __restrict__ bs,
                         float* __restrict__ q2, float* __restrict__ s2,
                         uint4* __restrict__ kv2) {
    __shared__ float sWq[384], sWk[384], sWv[384], sWs[384];
    __shared__ float sbq[6], sbk[6], sbv[6], sbs[6];
    for (int i = threadIdx.x; i < 384; i += blockDim.x) {
        sWq[i] = Wq[i]; sWk[i] = Wk[i]; sWv[i] = Wv[i]; sWs[i] = Ws[i];
    }
    if (threadIdx.x < 6) {
        sbq[threadIdx.x] = bq[threadIdx.x];
        sbk[threadIdx.x] = bk[threadIdx.x];
        sbv[threadIdx.x] = bv[threadIdx.x];
        sbs[threadIdx.x] = bs[threadIdx.x];
    }
    __syncthreads();
    int n = blockIdx.x * blockDim.x + threadIdx.x;
    if (n >= N_NODES) return;
    float qa[6], ka[6], va[6], sa[6];
#pragma unroll
    for (int c = 0; c < 6; ++c) { qa[c] = sbq[c]; ka[c] = sbk[c]; va[c] = sbv[c]; sa[c] = sbs[c]; }
    const uint4* hp = reinterpret_cast<const uint4*>(h1 + (size_t)n * 32);
#pragma unroll
    for (int i4 = 0; i4 < 8; ++i4) {
        uint4 hv = hp[i4];
        float2 f01 = __half22float2(*(const __half2*)&hv.x);
        float2 f23 = __half22float2(*(const __half2*)&hv.y);
        float2 f45 = __half22float2(*(const __half2*)&hv.z);
        float2 f67 = __half22float2(*(const __half2*)&hv.w);
        float hvv[8] = {f01.x, f01.y, f23.x, f23.y, f45.x, f45.y, f67.x, f67.y};
#pragma unroll
        for (int uu = 0; uu < 8; ++uu) {
            float hx = hvv[uu];
            int i = i4 * 8 + uu;
#pragma unroll
            for (int c = 0; c < 6; ++c) {
                qa[c] += hx * sWq[i * 6 + c];
                ka[c] += hx * sWk[i * 6 + c];
                va[c] += hx * sWv[i * 6 + c];
                sa[c] += hx * sWs[i * 6 + c];
            }
        }
    }
    const float rsqrt6 = 0.4082482904638631f;
#pragma unroll
    for (int c = 0; c < 6; ++c) {
        q2[(size_t)n * 6 + c] = qa[c] * rsqrt6;
        s2[(size_t)n * 6 + c] = sa[c];
    }
    float mk = 0.f, mv = 0.f;
#pragma unroll
    for (int c = 0; c < 6; ++c) {
        mk = fmaxf(mk, fabsf(ka[c]));
        mv = fmaxf(mv, fabsf(va[c]));
    }
    float sk = fmaxf(mk, 1e-8f) * (1.f / 127.f);
    float sv = fmaxf(mv, 1e-8f) * (1.f / 127.f);
    float isk = 1.f / sk, isv = 1.f / sv;
    int qk[6], qv[6];
#pragma unroll
    for (int c = 0; c < 6; ++c) {
        qk[c] = __float2int_rn(ka[c] * isk);
        qv[c] = __float2int_rn(va[c] * isv);
    }
    uint4 w;
    w.x = (qk[0] & 255) | ((qk[1] & 255) << 8) | ((qk[2] & 255) << 16) | ((qk[3] & 255) << 24);
    w.y = (qk[4] & 255) | ((qk[5] & 255) << 8) | ((qv[0] & 255) << 16) | ((qv[1] & 255) << 24);
    w.z = (qv[2] & 255) | ((qv[3] & 255) << 8) | ((qv[4] & 255) << 16) | ((qv[5] & 255) << 24);
    __half2 hs = __floats2half2_rn(sk, sv);
    w.w = *(unsigned*)&hs;
    kv2[n] = w;
}

// ---- G2: two-phase softmax, 8 lanes/node, register-resident edges ----
__global__ void g2_layer2(const int* __restrict__ rs, const int* __restrict__ re,
                          const int* __restrict__ csr_src,
                          const float* __restrict__ q2,
                          const uint4* __restrict__ kv2,
                          const float* __restrict__ s2,
                          const int* __restrict__ batch,
                          float* __restrict__ psum, float* __restrict__ pcnt) {
    __shared__ float bsum[N_GRAPHS * 6];
    __shared__ float bcnt[N_GRAPHS];
    for (int i = threadIdx.x; i < N_GRAPHS * 6; i += 256) bsum[i] = 0.f;
    for (int i = threadIdx.x; i < N_GRAPHS; i += 256) bcnt[i] = 0.f;
    __syncthreads();

    int node = blockIdx.x * 32 + (threadIdx.x >> 3);
    int lane8 = threadIdx.x & 7;

    float q[6];
#pragma unroll
    for (int c = 0; c < 6; ++c) q[c] = q2[(size_t)node * 6 + c];
    int row = rs[node];
    int deg = re[node] - row;

    // phase 1: up to 8 edges/lane in registers (covers deg <= 64)
    float lg[8], svr[8];
    unsigned py[8], pz[8];
#pragma unroll
    for (int i = 0; i < 8; ++i) { lg[i] = NEG_INF; svr[i] = 0.f; py[i] = 0u; pz[i] = 0u; }
    float lmax = NEG_INF;
#pragma unroll
    for (int i = 0; i < 4; ++i) {
        int e = lane8 + i * 8;
        bool v = e < deg;
        int src = v ? csr_src[row + e] : 0;
        uint4 w = kv2[src];
        float svx;
        float l = kvdot(q, w, &svx);
        if (v) {
            lg[i] = l; svr[i] = svx; py[i] = w.y; pz[i] = w.z;
            lmax = fmaxf(lmax, l);
        }
    }
    if (deg > 32) {
#pragma unroll
        for (int i = 4; i < 8; ++i) {
            int e = lane8 + i * 8;
            bool v = e < deg;
            int src = v ? csr_src[row + e] : 0;
            uint4 w = kv2[src];
            float svx;
            float l = kvdot(q, w, &svx);
            if (v) {
                lg[i] = l; svr[i] = svx; py[i] = w.y; pz[i] = w.z;
                lmax = fmaxf(lmax, l);
            }
        }
    }
    // overflow (deg > 64): online fold — essentially never taken, correctness net
    float mo = NEG_INF, dov = 0.f;
    float ao[6] = {0.f, 0.f, 0.f, 0.f, 0.f, 0.f};
    for (int e = lane8 + 64; e < deg; e += 8) {
        int src = csr_src[row + e];
        uint4 w = kv2[src];
        float svx;
        float l = kvdot(q, w, &svx);
        float mn = fmaxf(mo, l);
        float scp = __expf(mo - mn);
        float wx = __expf(l - mn);
        float wsx = wx * svx;
        dov = dov * scp + wx;
        ao[0] = ao[0] * scp + wsx * b2f(w.y, 16);
        ao[1] = ao[1] * scp + wsx * b2f(w.y, 24);
        ao[2] = ao[2] * scp + wsx * b2f(w.z, 0);
        ao[3] = ao[3] * scp + wsx * b2f(w.z, 8);
        ao[4] = ao[4] * scp + wsx * b2f(w.z, 16);
        ao[5] = ao[5] * scp + wsx * b2f(w.z, 24);
        mo = mn;
    }
    lmax = fmaxf(lmax, mo);
    // 3-stage cross-lane max
    lmax = fmaxf(lmax, __shfl_xor(lmax, 1));
    lmax = fmaxf(lmax, __shfl_xor(lmax, 2));
    lmax = fmaxf(lmax, __shfl_xor(lmax, 4));
    if (lmax < -5e29f) lmax = 0.f;   // deg==0 guard: all weights underflow to 0

    // phase 2: independent exps, in-lane accumulation (no rescale chain)
    float d = 0.f;
    float acc[6] = {0.f, 0.f, 0.f, 0.f, 0.f, 0.f};
#pragma unroll
    for (int i = 0; i < 8; ++i) {
        float w = __expf(lg[i] - lmax);   // exact 0 for empty slots
        float ws = w * svr[i];
        d += w;
        acc[0] += ws * b2f(py[i], 16);
        acc[1] += ws * b2f(py[i], 24);
        acc[2] += ws * b2f(pz[i], 0);
        acc[3] += ws * b2f(pz[i], 8);
        acc[4] += ws * b2f(pz[i], 16);
        acc[5] += ws * b2f(pz[i], 24);
    }
    // fold overflow state (scale by exp(mo - lmax); 0 when unused)
    float so = __expf(mo - lmax);
    d += dov * so;
#pragma unroll
    for (int c = 0; c < 6; ++c) acc[c] += ao[c] * so;

    // 3-stage butterfly sums
#pragma unroll
    for (int off = 1; off <= 4; off <<= 1) {
        d += __shfl_xor(d, off);
#pragma unroll
        for (int c = 0; c < 6; ++c) acc[c] += __shfl_xor(acc[c], off);
    }

    if (lane8 == 0) {
        float inv = 1.f / (d + 1e-16f);
        int g = batch[node];
#pragma unroll
        for (int c = 0; c < 6; ++c) {
            float val = acc[c] * inv + s2[(size_t)node * 6 + c];
            atomicAdd(&bsum[g * 6 + c], val);
        }
        atomicAdd(&bcnt[g], 1.f);
    }
    __syncthreads();
    for (int i = threadIdx.x; i < N_GRAPHS * 6; i += 256) {
        float v = bsum[i];
        if (v != 0.f) atomAddF(psum + i, v);
    }
    for (int i = threadIdx.x; i < N_GRAPHS; i += 256) {
        float v = bcnt[i];
        if (v != 0.f) atomAddF(pcnt + i, v);
    }
}

// ---- K9: pooled mean + log_softmax ----
__global__ void k9_final(const float* __restrict__ psum, const float* __restrict__ pcnt,
                         float* __restrict__ out) {
    int g = threadIdx.x;
    if (g >= N_GRAPHS) return;
    float cnt = fmaxf(pcnt[g], 1.0f);
    float z[6];
    float mx = -1e30f;
#pragma unroll
    for (int c = 0; c < 6; ++c) {
        z[c] = psum[g * 6 + c] / cnt;
        mx = fmaxf(mx, z[c]);
    }
    float se = 0.f;
#pragma unroll
    for (int c = 0; c < 6; ++c) se += __expf(z[c] - mx);
    float lse = mx + logf(se);
#pragma unroll
    for (int c = 0; c < 6; ++c) out[g * 6 + c] = z[c] - lse;
}

extern "C" void kernel_launch(void* const* d_in, const int* in_sizes, int n_in,
                              void* d_out, int out_size, void* d_ws, size_t ws_size,
                              hipStream_t stream) {
    const float* x   = (const float*)d_in[0];
    const int*   ei  = (const int*)d_in[1];
    const int*   bat = (const int*)d_in[2];
    const float* Wq1 = (const float*)d_in[3];  const float* bq1 = (const float*)d_in[4];
    const float* Wk1 = (const float*)d_in[5];  const float* bk1 = (const float*)d_in[6];
    const float* Wv1 = (const float*)d_in[7];  const float* bv1 = (const float*)d_in[8];
    const float* Ws1 = (const float*)d_in[9];  const float* bs1 = (const float*)d_in[10];
    const float* Wq2 = (const float*)d_in[11]; const float* bq2 = (const float*)d_in[12];
    const float* Wk2 = (const float*)d_in[13]; const float* bk2 = (const float*)d_in[14];
    const float* Wv2 = (const float*)d_in[15]; const float* bv2 = (const float*)d_in[16];
    const float* Ws2 = (const float*)d_in[17]; const float* bs2 = (const float*)d_in[18];
    float* out = (float*)d_out;

    char* ws = (char*)d_ws;
    size_t off = 0;
    auto alloc = [&](size_t bytes) -> char* {
        char* p = ws + off;
        off += (bytes + 255) & ~(size_t)255;
        return p;
    };

    // ---- zero-initialized region (one small memset) ----
    float* psum = (float*)alloc((size_t)N_GRAPHS * 6 * 4);
    float* pcnt = (float*)alloc((size_t)N_GRAPHS * 4);
    int* bucket_fill = (int*)alloc((size_t)NB * 4);
    size_t zero_bytes = off;

    // ---- uninitialized scratch ----
    unsigned* pairs   = (unsigned*)alloc((size_t)NB * CAP * 4);
    int*      csr_src = (int*)     alloc((size_t)NB * CAP * 4);
    int*      rsv     = (int*)     alloc((size_t)N_NODES * 4);
    int*      rev     = (int*)     alloc((size_t)N_NODES * 4);
    float4*   xp      = (float4*)  alloc((size_t)N_NODES * 16);
    uint2*    xh      = (uint2*)   alloc((size_t)N_NODES * 8);
    unsigned* h1      = (unsigned*)alloc((size_t)N_NODES * 64 * 2);  // fp16
    float*    q2      = (float*)   alloc((size_t)N_NODES * 6 * 4);
    float*    s2      = (float*)   alloc((size_t)N_NODES * 6 * 4);
    uint4*    kv2     = (uint4*)   alloc((size_t)N_NODES * 16);

    hipMemsetAsync(d_ws, 0, zero_bytes, stream);

    k0_packx<<<(N_NODES + 255) / 256, 256, 0, stream>>>(x, xp, xh);
    s1_partition<<<NBLK, 256, 0, stream>>>(ei, bucket_fill, pairs);
    b4_build<<<NB, 512, 0, stream>>>(pairs, bucket_fill, rsv, rev, csr_src);

    g1_layer1<<<N_NODES / 16, 256, 0, stream>>>(xp, xh, Wq1, bq1, Wk1, bk1, Wv1, bv1,
                                                Ws1, bs1, rsv, rev, csr_src,
                                                (uint2*)h1);
    k5_node2<<<(N_NODES + 255) / 256, 256, 0, stream>>>(h1, Wq2, bq2, Wk2, bk2,
                                                        Wv2, bv2, Ws2, bs2,
                                                        q2, s2, kv2);
    g2_layer2<<<N_NODES / 32, 256, 0, stream>>>(rsv, rev, csr_src, q2, kv2, s2,
                                                bat, psum, pcnt);
    k9_final<<<1, 64, 0, stream>>>(psum, pcnt, out);
}

// Round 9
// 163.428 us; speedup vs baseline: 32.0629x; 1.0312x over previous
//
#include <hip/hip_runtime.h>
#include <hip/hip_fp16.h>
#include <math.h>

#define N_NODES 100000
#define N_EDGES 3200000
#define N_GRAPHS 64
#define NEG_INF -1e30f

// bucket sort geometry: bucket = dst >> 9  (512 nodes per bucket)
#define NB 196         // ceil(100000/512)
#define CAP 18432      // per-bucket capacity; mean 16326 + ~16 sigma
#define NBLK 512       // partition blocks
#define CHUNK 6250     // 512 * 6250 = 3.2M exactly

__device__ __forceinline__ void atomAddF(float* p, float v) {
#if defined(__HIP_PLATFORM_AMD__)
    unsafeAtomicAdd(p, v);
#else
    atomicAdd(p, v);
#endif
}

__device__ __forceinline__ float b2f(unsigned w, int sh) {
    return (float)(signed char)(w >> sh);
}

// logit from packed kv row; also extracts v-scale
__device__ __forceinline__ float kvdot(const float* q, uint4 w, float* sv_out) {
    float2 s = __half22float2(*(const __half2*)&w.w);
    *sv_out = s.y;
    return s.x * (q[0] * b2f(w.x, 0) + q[1] * b2f(w.x, 8)
                + q[2] * b2f(w.x, 16) + q[3] * b2f(w.x, 24)
                + q[4] * b2f(w.y, 0) + q[5] * b2f(w.y, 8));
}

// ---- K0: pack x into float4 (node-own, fp32) and half4 (gather, 8B) ----
__global__ void k0_packx(const float* __restrict__ x, float4* __restrict__ xp,
                         uint2* __restrict__ xh) {
    int n = blockIdx.x * 256 + threadIdx.x;
    if (n >= N_NODES) return;
    float x0 = x[3 * n], x1 = x[3 * n + 1], x2 = x[3 * n + 2];
    xp[n] = make_float4(x0, x1, x2, 0.f);
    __half2 h01 = __floats2half2_rn(x0, x1);
    __half2 h2p = __floats2half2_rn(x2, 0.f);
    xh[n] = make_uint2(*(unsigned*)&h01, *(unsigned*)&h2p);
}

// ---- S1: in-LDS bucket sort of each block's chunk; streaming global I/O.
// Writes pairs[block*CHUNK .. +CHUNK) grouped by bucket, and the per-block
// exclusive-scan bases offs[block*NB + b]. No global atomics.
__global__ __launch_bounds__(512) void s1_partition(const int* __restrict__ ei,
                                                    int* __restrict__ offs,
                                                    unsigned* __restrict__ pairs) {
    __shared__ unsigned pairbuf[CHUNK];        // 25000 B
    __shared__ unsigned sortbuf[CHUNK];        // 25000 B
    __shared__ unsigned char buckbuf[CHUNK];   // 6250 B
    __shared__ int hist[4][200];               // per-wave-pair, padded
    __shared__ int cur[NB], tmp[NB];
    int tid = threadIdx.x;
    int wp = tid >> 7;                         // 4 wave-pairs
    for (int i = tid; i < 4 * 200; i += 512) ((int*)hist)[i] = 0;
    __syncthreads();
    int gbase = blockIdx.x * CHUNK;
    for (int i = tid; i < CHUNK; i += 512) {
        int src = ei[gbase + i];
        unsigned dst = (unsigned)ei[N_EDGES + gbase + i];
        pairbuf[i] = ((unsigned)src << 9) | (dst & 511u);
        unsigned b = dst >> 9;
        buckbuf[i] = (unsigned char)b;
        atomicAdd(&hist[wp][b], 1);
    }
    __syncthreads();
    if (tid < NB)
        tmp[tid] = hist[0][tid] + hist[1][tid] + hist[2][tid] + hist[3][tid];
    __syncthreads();
    for (int off = 1; off < NB; off <<= 1) {
        int v = 0;
        if (tid < NB && tid >= off) v = tmp[tid - off];
        __syncthreads();
        if (tid < NB) tmp[tid] += v;
        __syncthreads();
    }
    if (tid < NB) {
        int cnt_b = hist[0][tid] + hist[1][tid] + hist[2][tid] + hist[3][tid];
        int excl = tmp[tid] - cnt_b;
        cur[tid] = excl;
        offs[blockIdx.x * NB + tid] = excl;
    }
    __syncthreads();
    for (int i = tid; i < CHUNK; i += 512) {
        int pos = atomicAdd(&cur[buckbuf[i]], 1);
        sortbuf[pos] = pairbuf[i];
    }
    __syncthreads();
    for (int i = tid; i < CHUNK; i += 512)
        pairs[gbase + i] = sortbuf[i];
}

// ---- B4: per-bucket exact CSR build; reads 512 per-block segments ----
__global__ __launch_bounds__(512) void b4_build(const unsigned* __restrict__ pairs,
                                                const int* __restrict__ offs,
                                                int* __restrict__ rs,
                                                int* __restrict__ re,
                                                int* __restrict__ csr_src) {
    __shared__ int so[NBLK], seg_e[NBLK];
    __shared__ int cnt[512], sc[512], cur[512];
    int b = blockIdx.x;
    int tid = threadIdx.x;
    for (int k = tid; k < NBLK; k += 512) {
        so[k] = offs[k * NB + b];
        seg_e[k] = (b == NB - 1) ? CHUNK : offs[k * NB + b + 1];
    }
    cnt[tid] = 0;
    __syncthreads();
    int wave = tid >> 6, lane = tid & 63;
    for (int k = wave; k < NBLK; k += 8) {
        int s = so[k], e = seg_e[k], gb = k * CHUNK;
        for (int i = s + lane; i < e; i += 64)
            atomicAdd(&cnt[pairs[gb + i] & 511u], 1);
    }
    __syncthreads();
    sc[tid] = cnt[tid];
    __syncthreads();
    for (int off = 1; off < 512; off <<= 1) {
        int v = (tid >= off) ? sc[tid - off] : 0;
        __syncthreads();
        sc[tid] += v;
        __syncthreads();
    }
    int rbase = b * CAP;
    int excl = sc[tid] - cnt[tid];
    cur[tid] = rbase + excl;
    int node = (b << 9) + tid;
    if (node < N_NODES) {
        rs[node] = rbase + excl;
        re[node] = rbase + sc[tid];
    }
    __syncthreads();
    for (int k = wave; k < NBLK; k += 8) {
        int s = so[k], e = seg_e[k], gb = k * CHUNK;
        for (int i = s + lane; i < e; i += 64) {
            unsigned p = pairs[gb + i];
            int pos = atomicAdd(&cur[p & 511u], 1);
            csr_src[pos] = (int)(p >> 9);
        }
    }
}

// ---- G1: fused layer-1, rank-3 factorization, fp16 x-gathers, fp16 h1 out ----
__global__ void g1_layer1(const float4* __restrict__ xp,
                          const uint2* __restrict__ xh,
                          const float* __restrict__ Wq, const float* __restrict__ bq,
                          const float* __restrict__ Wk, const float* __restrict__ bk,
                          const float* __restrict__ Wv, const float* __restrict__ bv,
                          const float* __restrict__ Ws, const float* __restrict__ bs,
                          const int* __restrict__ rs, const int* __restrict__ re,
                          const int* __restrict__ csr_src,
                          uint2* __restrict__ h1) {
    __shared__ float sWq[192], sWk[192], sWv[192], sWs[192];
    __shared__ float sbq[64], sbk[64], sbv[64], sbs[64];
    for (int i = threadIdx.x; i < 192; i += 256) {
        sWq[i] = Wq[i]; sWk[i] = Wk[i]; sWv[i] = Wv[i]; sWs[i] = Ws[i];
    }
    for (int i = threadIdx.x; i < 64; i += 256) {
        sbq[i] = bq[i]; sbk[i] = bk[i]; sbv[i] = bv[i]; sbs[i] = bs[i];
    }
    __syncthreads();

    int lane = threadIdx.x & 63;
    int u = lane & 15;
    int slot = u >> 2;
    int j0 = u * 4;
    int n = blockIdx.x * 16 + (threadIdx.x >> 6) * 4 + (lane >> 4);

    float4 xc = xp[n];
    float x0 = xc.x, x1 = xc.y, x2 = xc.z;

    float q[4];
#pragma unroll
    for (int i = 0; i < 4; ++i)
        q[i] = 0.25f * (sbq[j0 + i] + x0 * sWq[j0 + i] + x1 * sWq[64 + j0 + i]
                        + x2 * sWq[128 + j0 + i]);
    float t0 = 0.f, t1 = 0.f, t2 = 0.f, tb = 0.f;
#pragma unroll
    for (int i = 0; i < 4; ++i) {
        float qi = q[i];
        t0 += qi * sWk[j0 + i];
        t1 += qi * sWk[64 + j0 + i];
        t2 += qi * sWk[128 + j0 + i];
        tb += qi * sbk[j0 + i];
    }
#pragma unroll
    for (int off = 1; off <= 2; off <<= 1) {
        t0 += __shfl_xor(t0, off);
        t1 += __shfl_xor(t1, off);
        t2 += __shfl_xor(t2, off);
        tb += __shfl_xor(tb, off);
    }
    // transpose: edge loop wants head = u&3
    int tsrc = (lane & 48) | ((lane & 3) << 2) | ((lane >> 2) & 3);
    t0 = __shfl(t0, tsrc, 64);
    t1 = __shfl(t1, tsrc, 64);
    t2 = __shfl(t2, tsrc, 64);
    tb = __shfl(tb, tsrc, 64);

    int row = rs[n];
    int deg = re[n] - row;

    float mA = NEG_INF, dA = 0.f, s0A = 0.f, s1A = 0.f, s2A = 0.f;
    float mB = NEG_INF, dB = 0.f, s0B = 0.f, s1B = 0.f, s2B = 0.f;
    for (int base = 0; base < deg; base += 8) {
        int eA = base + slot, eB = base + 4 + slot;
        bool vA = eA < deg, vB = eB < deg;
        int srcA = vA ? csr_src[row + eA] : 0;
        int srcB = vB ? csr_src[row + eB] : 0;
        uint2 wA = xh[srcA];
        uint2 wB = xh[srcB];
        float2 a01 = __half22float2(*(const __half2*)&wA.x);
        float a2 = __half22float2(*(const __half2*)&wA.y).x;
        float2 b01 = __half22float2(*(const __half2*)&wB.x);
        float b2 = __half22float2(*(const __half2*)&wB.y).x;
        float lA = vA ? (tb + a01.x * t0 + a01.y * t1 + a2 * t2) : NEG_INF;
        float lB = vB ? (tb + b01.x * t0 + b01.y * t1 + b2 * t2) : NEG_INF;
        float mnA = fmaxf(mA, lA);
        float scA = __expf(mA - mnA);
        float aA = vA ? __expf(lA - mnA) : 0.f;
        dA = dA * scA + aA;
        s0A = s0A * scA + aA * a01.x;
        s1A = s1A * scA + aA * a01.y;
        s2A = s2A * scA + aA * a2;
        mA = mnA;
        float mnB = fmaxf(mB, lB);
        float scB = __expf(mB - mnB);
        float aB = vB ? __expf(lB - mnB) : 0.f;
        dB = dB * scB + aB;
        s0B = s0B * scB + aB * b01.x;
        s1B = s1B * scB + aB * b01.y;
        s2B = s2B * scB + aB * b2;
        mB = mnB;
    }
    // merge B into A (in-lane)
    float m = fmaxf(mA, mB);
    float fA = __expf(mA - m), fB = __expf(mB - m);
    float d = dA * fA + dB * fB;
    float s0 = s0A * fA + s0B * fB;
    float s1 = s1A * fA + s1B * fB;
    float s2 = s2A * fA + s2B * fB;

    // cross-slot merge: global max, single rescale, butterfly sums
    float gm = m;
    gm = fmaxf(gm, __shfl_xor(gm, 4));
    gm = fmaxf(gm, __shfl_xor(gm, 8));
    float f = __expf(m - gm);
    d *= f; s0 *= f; s1 *= f; s2 *= f;
#pragma unroll
    for (int off = 4; off <= 8; off <<= 1) {
        d += __shfl_xor(d, off);
        s0 += __shfl_xor(s0, off);
        s1 += __shfl_xor(s1, off);
        s2 += __shfl_xor(s2, off);
    }

    // epilogue: lane u needs head u>>2's state
    int esrc = (lane & 48) | ((lane >> 2) & 3);
    float dH = __shfl(d, esrc, 64);
    float s0H = __shfl(s0, esrc, 64);
    float s1H = __shfl(s1, esrc, 64);
    float s2H = __shfl(s2, esrc, 64);
    float inv = 1.f / (dH + 1e-16f);
    float fr = dH * inv, r0 = s0H * inv, r1 = s1H * inv, r2 = s2H * inv;

    float o[4];
#pragma unroll
    for (int i = 0; i < 4; ++i) {
        int j = j0 + i;
        float val = fr * sbv[j] + r0 * sWv[j] + r1 * sWv[64 + j] + r2 * sWv[128 + j]
                  + sbs[j] + x0 * sWs[j] + x1 * sWs[64 + j] + x2 * sWs[128 + j];
        o[i] = fmaxf(val, 0.f);
    }
    __half2 p01 = __floats2half2_rn(o[0], o[1]);
    __half2 p23 = __floats2half2_rn(o[2], o[3]);
    h1[(size_t)n * 16 + u] = make_uint2(*(unsigned*)&p01, *(unsigned*)&p23);
}

// ---- K5: reads fp16 h1; q2 (pre-scaled) + s2 fp32; kv2 int8 16B rows ----
__global__ void k5_node2(const unsigned* __restrict__ h1,
                         const float* __restrict__ Wq, const float* __restrict__ bq,
                         const float* __restrict__ Wk, const float* __restrict__ bk,
                         const float* __restrict__ Wv, const float* __restrict__ bv,
                         const float* __restrict__ Ws, const float* __restrict__ bs,
                         float* __restrict__ q2, float* __restrict__ s2,
                         uint4* __restrict__ kv2) {
    __shared__ float sWq[384], sWk[384], sWv[384], sWs[384];
    __shared__ float sbq[6], sbk[6], sbv[6], sbs[6];
    for (int i = threadIdx.x; i < 384; i += blockDim.x) {
        sWq[i] = Wq[i]; sWk[i] = Wk[i]; sWv[i] = Wv[i]; sWs[i] = Ws[i];
    }
    if (threadIdx.x < 6) {
        sbq[threadIdx.x] = bq[threadIdx.x];
        sbk[threadIdx.x] = bk[threadIdx.x];
        sbv[threadIdx.x] = bv[threadIdx.x];
        sbs[threadIdx.x] = bs[threadIdx.x];
    }
    __syncthreads();
    int n = blockIdx.x * blockDim.x + threadIdx.x;
    if (n >= N_NODES) return;
    float qa[6], ka[6], va[6], sa[6];
#pragma unroll
    for (int c = 0; c < 6; ++c) { qa[c] = sbq[c]; ka[c] = sbk[c]; va[c] = sbv[c]; sa[c] = sbs[c]; }
    const uint4* hp = reinterpret_cast<const uint4*>(h1 + (size_t)n * 32);
#pragma unroll
    for (int i4 = 0; i4 < 8; ++i4) {
        uint4 hv = hp[i4];
        float2 f01 = __half22float2(*(const __half2*)&hv.x);
        float2 f23 = __half22float2(*(const __half2*)&hv.y);
        float2 f45 = __half22float2(*(const __half2*)&hv.z);
        float2 f67 = __half22float2(*(const __half2*)&hv.w);
        float hvv[8] = {f01.x, f01.y, f23.x, f23.y, f45.x, f45.y, f67.x, f67.y};
#pragma unroll
        for (int uu = 0; uu < 8; ++uu) {
            float hx = hvv[uu];
            int i = i4 * 8 + uu;
#pragma unroll
            for (int c = 0; c < 6; ++c) {
                qa[c] += hx * sWq[i * 6 + c];
                ka[c] += hx * sWk[i * 6 + c];
                va[c] += hx * sWv[i * 6 + c];
                sa[c] += hx * sWs[i * 6 + c];
            }
        }
    }
    const float rsqrt6 = 0.4082482904638631f;
#pragma unroll
    for (int c = 0; c < 6; ++c) {
        q2[(size_t)n * 6 + c] = qa[c] * rsqrt6;
        s2[(size_t)n * 6 + c] = sa[c];
    }
    float mk = 0.f, mv = 0.f;
#pragma unroll
    for (int c = 0; c < 6; ++c) {
        mk = fmaxf(mk, fabsf(ka[c]));
        mv = fmaxf(mv, fabsf(va[c]));
    }
    float sk = fmaxf(mk, 1e-8f) * (1.f / 127.f);
    float sv = fmaxf(mv, 1e-8f) * (1.f / 127.f);
    float isk = 1.f / sk, isv = 1.f / sv;
    int qk[6], qv[6];
#pragma unroll
    for (int c = 0; c < 6; ++c) {
        qk[c] = __float2int_rn(ka[c] * isk);
        qv[c] = __float2int_rn(va[c] * isv);
    }
    uint4 w;
    w.x = (qk[0] & 255) | ((qk[1] & 255) << 8) | ((qk[2] & 255) << 16) | ((qk[3] & 255) << 24);
    w.y = (qk[4] & 255) | ((qk[5] & 255) << 8) | ((qv[0] & 255) << 16) | ((qv[1] & 255) << 24);
    w.z = (qv[2] & 255) | ((qv[3] & 255) << 8) | ((qv[4] & 255) << 16) | ((qv[5] & 255) << 24);
    __half2 hs = __floats2half2_rn(sk, sv);
    w.w = *(unsigned*)&hs;
    kv2[n] = w;
}

// ---- G2: two-phase softmax, 8 lanes/node, register-resident edges ----
__global__ void g2_layer2(const int* __restrict__ rs, const int* __restrict__ re,
                          const int* __restrict__ csr_src,
                          const float* __restrict__ q2,
                          const uint4* __restrict__ kv2,
                          const float* __restrict__ s2,
                          const int* __restrict__ batch,
                          float* __restrict__ psum, float* __restrict__ pcnt) {
    __shared__ float bsum[N_GRAPHS * 6];
    __shared__ float bcnt[N_GRAPHS];
    for (int i = threadIdx.x; i < N_GRAPHS * 6; i += 256) bsum[i] = 0.f;
    for (int i = threadIdx.x; i < N_GRAPHS; i += 256) bcnt[i] = 0.f;
    __syncthreads();

    int node = blockIdx.x * 32 + (threadIdx.x >> 3);
    int lane8 = threadIdx.x & 7;

    float q[6];
#pragma unroll
    for (int c = 0; c < 6; ++c) q[c] = q2[(size_t)node * 6 + c];
    int row = rs[node];
    int deg = re[node] - row;

    // phase 1: up to 8 edges/lane in registers (covers deg <= 64)
    float lg[8], svr[8];
    unsigned py[8], pz[8];
#pragma unroll
    for (int i = 0; i < 8; ++i) { lg[i] = NEG_INF; svr[i] = 0.f; py[i] = 0u; pz[i] = 0u; }
    float lmax = NEG_INF;
#pragma unroll
    for (int i = 0; i < 4; ++i) {
        int e = lane8 + i * 8;
        bool v = e < deg;
        int src = v ? csr_src[row + e] : 0;
        uint4 w = kv2[src];
        float svx;
        float l = kvdot(q, w, &svx);
        if (v) {
            lg[i] = l; svr[i] = svx; py[i] = w.y; pz[i] = w.z;
            lmax = fmaxf(lmax, l);
        }
    }
    if (deg > 32) {
#pragma unroll
        for (int i = 4; i < 8; ++i) {
            int e = lane8 + i * 8;
            bool v = e < deg;
            int src = v ? csr_src[row + e] : 0;
            uint4 w = kv2[src];
            float svx;
            float l = kvdot(q, w, &svx);
            if (v) {
                lg[i] = l; svr[i] = svx; py[i] = w.y; pz[i] = w.z;
                lmax = fmaxf(lmax, l);
            }
        }
    }
    // overflow (deg > 64): online fold — essentially never taken, correctness net
    float mo = NEG_INF, dov = 0.f;
    float ao[6] = {0.f, 0.f, 0.f, 0.f, 0.f, 0.f};
    for (int e = lane8 + 64; e < deg; e += 8) {
        int src = csr_src[row + e];
        uint4 w = kv2[src];
        float svx;
        float l = kvdot(q, w, &svx);
        float mn = fmaxf(mo, l);
        float scp = __expf(mo - mn);
        float wx = __expf(l - mn);
        float wsx = wx * svx;
        dov = dov * scp + wx;
        ao[0] = ao[0] * scp + wsx * b2f(w.y, 16);
        ao[1] = ao[1] * scp + wsx * b2f(w.y, 24);
        ao[2] = ao[2] * scp + wsx * b2f(w.z, 0);
        ao[3] = ao[3] * scp + wsx * b2f(w.z, 8);
        ao[4] = ao[4] * scp + wsx * b2f(w.z, 16);
        ao[5] = ao[5] * scp + wsx * b2f(w.z, 24);
        mo = mn;
    }
    lmax = fmaxf(lmax, mo);
    // 3-stage cross-lane max
    lmax = fmaxf(lmax, __shfl_xor(lmax, 1));
    lmax = fmaxf(lmax, __shfl_xor(lmax, 2));
    lmax = fmaxf(lmax, __shfl_xor(lmax, 4));
    if (lmax < -5e29f) lmax = 0.f;   // deg==0 guard: all weights underflow to 0

    // phase 2: independent exps, in-lane accumulation (no rescale chain)
    float d = 0.f;
    float acc[6] = {0.f, 0.f, 0.f, 0.f, 0.f, 0.f};
#pragma unroll
    for (int i = 0; i < 8; ++i) {
        float w = __expf(lg[i] - lmax);   // exact 0 for empty slots
        float ws = w * svr[i];
        d += w;
        acc[0] += ws * b2f(py[i], 16);
        acc[1] += ws * b2f(py[i], 24);
        acc[2] += ws * b2f(pz[i], 0);
        acc[3] += ws * b2f(pz[i], 8);
        acc[4] += ws * b2f(pz[i], 16);
        acc[5] += ws * b2f(pz[i], 24);
    }
    // fold overflow state (scale by exp(mo - lmax); 0 when unused)
    float so = __expf(mo - lmax);
    d += dov * so;
#pragma unroll
    for (int c = 0; c < 6; ++c) acc[c] += ao[c] * so;

    // 3-stage butterfly sums
#pragma unroll
    for (int off = 1; off <= 4; off <<= 1) {
        d += __shfl_xor(d, off);
#pragma unroll
        for (int c = 0; c < 6; ++c) acc[c] += __shfl_xor(acc[c], off);
    }

    if (lane8 == 0) {
        float inv = 1.f / (d + 1e-16f);
        int g = batch[node];
#pragma unroll
        for (int c = 0; c < 6; ++c) {
            float val = acc[c] * inv + s2[(size_t)node * 6 + c];
            atomicAdd(&bsum[g * 6 + c], val);
        }
        atomicAdd(&bcnt[g], 1.f);
    }
    __syncthreads();
    for (int i = threadIdx.x; i < N_GRAPHS * 6; i += 256) {
        float v = bsum[i];
        if (v != 0.f) atomAddF(psum + i, v);
    }
    for (int i = threadIdx.x; i < N_GRAPHS; i += 256) {
        float v = bcnt[i];
        if (v != 0.f) atomAddF(pcnt + i, v);
    }
}

// ---- K9: pooled mean + log_softmax ----
__global__ void k9_final(const float* __restrict__ psum, const float* __restrict__ pcnt,
                         float* __restrict__ out) {
    int g = threadIdx.x;
    if (g >= N_GRAPHS) return;
    float cnt = fmaxf(pcnt[g], 1.0f);
    float z[6];
    float mx = -1e30f;
#pragma unroll
    for (int c = 0; c < 6; ++c) {
        z[c] = psum[g * 6 + c] / cnt;
        mx = fmaxf(mx, z[c]);
    }
    float se = 0.f;
#pragma unroll
    for (int c = 0; c < 6; ++c) se += __expf(z[c] - mx);
    float lse = mx + logf(se);
#pragma unroll
    for (int c = 0; c < 6; ++c) out[g * 6 + c] = z[c] - lse;
}

extern "C" void kernel_launch(void* const* d_in, const int* in_sizes, int n_in,
                              void* d_out, int out_size, void* d_ws, size_t ws_size,
                              hipStream_t stream) {
    const float* x   = (const float*)d_in[0];
    const int*   ei  = (const int*)d_in[1];
    const int*   bat = (const int*)d_in[2];
    const float* Wq1 = (const float*)d_in[3];  const float* bq1 = (const float*)d_in[4];
    const float* Wk1 = (const float*)d_in[5];  const float* bk1 = (const float*)d_in[6];
    const float* Wv1 = (const float*)d_in[7];  const float* bv1 = (const float*)d_in[8];
    const float* Ws1 = (const float*)d_in[9];  const float* bs1 = (const float*)d_in[10];
    const float* Wq2 = (const float*)d_in[11]; const float* bq2 = (const float*)d_in[12];
    const float* Wk2 = (const float*)d_in[13]; const float* bk2 = (const float*)d_in[14];
    const float* Wv2 = (const float*)d_in[15]; const float* bv2 = (const float*)d_in[16];
    const float* Ws2 = (const float*)d_in[17]; const float* bs2 = (const float*)d_in[18];
    float* out = (float*)d_out;

    char* ws = (char*)d_ws;
    size_t off = 0;
    auto alloc = [&](size_t bytes) -> char* {
        char* p = ws + off;
        off += (bytes + 255) & ~(size_t)255;
        return p;
    };

    // ---- zero-initialized region (one small memset) ----
    float* psum = (float*)alloc((size_t)N_GRAPHS * 6 * 4);
    float* pcnt = (float*)alloc((size_t)N_GRAPHS * 4);
    size_t zero_bytes = off;

    // ---- uninitialized scratch ----
    int*      offs    = (int*)     alloc((size_t)NBLK * NB * 4);
    unsigned* pairs   = (unsigned*)alloc((size_t)N_EDGES * 4);
    int*      csr_src = (int*)     alloc((size_t)NB * CAP * 4);
    int*      rsv     = (int*)     alloc((size_t)N_NODES * 4);
    int*      rev     = (int*)     alloc((size_t)N_NODES * 4);
    float4*   xp      = (float4*)  alloc((size_t)N_NODES * 16);
    uint2*    xh      = (uint2*)   alloc((size_t)N_NODES * 8);
    unsigned* h1      = (unsigned*)alloc((size_t)N_NODES * 64 * 2);  // fp16
    float*    q2      = (float*)   alloc((size_t)N_NODES * 6 * 4);
    float*    s2      = (float*)   alloc((size_t)N_NODES * 6 * 4);
    uint4*    kv2     = (uint4*)   alloc((size_t)N_NODES * 16);

    hipMemsetAsync(d_ws, 0, zero_bytes, stream);

    k0_packx<<<(N_NODES + 255) / 256, 256, 0, stream>>>(x, xp, xh);
    s1_partition<<<NBLK, 512, 0, stream>>>(ei, offs, pairs);
    b4_build<<<NB, 512, 0, stream>>>(pairs, offs, rsv, rev, csr_src);

    g1_layer1<<<N_NODES / 16, 256, 0, stream>>>(xp, xh, Wq1, bq1, Wk1, bk1, Wv1, bv1,
                                                Ws1, bs1, rsv, rev, csr_src,
                                                (uint2*)h1);
    k5_node2<<<(N_NODES + 255) / 256, 256, 0, stream>>>(h1, Wq2, bq2, Wk2, bk2,
                                                        Wv2, bv2, Ws2, bs2,
                                                        q2, s2, kv2);
    g2_layer2<<<N_NODES / 32, 256, 0, stream>>>(rsv, rev, csr_src, q2, kv2, s2,
                                                bat, psum, pcnt);
    k9_final<<<1, 64, 0, stream>>>(psum, pcnt, out);
}

// Round 10
// 144.380 us; speedup vs baseline: 36.2931x; 1.1319x over previous
//
#include <hip/hip_runtime.h>
#include <hip/hip_fp16.h>
#include <math.h>

#define N_NODES 100000
#define N_EDGES 3200000
#define N_GRAPHS 64
#define NEG_INF -1e30f

// bucket sort geometry: bucket = dst >> 9  (512 nodes per bucket)
#define NB 196         // ceil(100000/512)
#define CAP 18432      // per-bucket capacity; mean 16326 + ~16 sigma
#define NBLK 512       // partition blocks
#define CHUNK 6250     // 512 * 6250 = 3.2M exactly

__device__ __forceinline__ void atomAddF(float* p, float v) {
#if defined(__HIP_PLATFORM_AMD__)
    unsafeAtomicAdd(p, v);
#else
    atomicAdd(p, v);
#endif
}

__device__ __forceinline__ float b2f(unsigned w, int sh) {
    return (float)(signed char)(w >> sh);
}

// logit from packed kv row; also extracts v-scale
__device__ __forceinline__ float kvdot(const float* q, uint4 w, float* sv_out) {
    float2 s = __half22float2(*(const __half2*)&w.w);
    *sv_out = s.y;
    return s.x * (q[0] * b2f(w.x, 0) + q[1] * b2f(w.x, 8)
                + q[2] * b2f(w.x, 16) + q[3] * b2f(w.x, 24)
                + q[4] * b2f(w.y, 0) + q[5] * b2f(w.y, 8));
}

// ---- K0: pack x into float4 (node-own, fp32) and half4 (gather, 8B) ----
__global__ void k0_packx(const float* __restrict__ x, float4* __restrict__ xp,
                         uint2* __restrict__ xh) {
    int n = blockIdx.x * 256 + threadIdx.x;
    if (n >= N_NODES) return;
    float x0 = x[3 * n], x1 = x[3 * n + 1], x2 = x[3 * n + 2];
    xp[n] = make_float4(x0, x1, x2, 0.f);
    __half2 h01 = __floats2half2_rn(x0, x1);
    __half2 h2p = __floats2half2_rn(x2, 0.f);
    xh[n] = make_uint2(*(unsigned*)&h01, *(unsigned*)&h2p);
}

// ---- S1: in-LDS bucket sort of each block's chunk; streaming global I/O ----
__global__ __launch_bounds__(512) void s1_partition(const int* __restrict__ ei,
                                                    int* __restrict__ offs,
                                                    unsigned* __restrict__ pairs) {
    __shared__ unsigned pairbuf[CHUNK];        // 25000 B
    __shared__ unsigned sortbuf[CHUNK];        // 25000 B
    __shared__ unsigned char buckbuf[CHUNK];   // 6250 B
    __shared__ int hist[4][200];               // per-wave-pair, padded
    __shared__ int cur[NB], tmp[NB];
    int tid = threadIdx.x;
    int wp = tid >> 7;                         // 4 wave-pairs
    for (int i = tid; i < 4 * 200; i += 512) ((int*)hist)[i] = 0;
    __syncthreads();
    int gbase = blockIdx.x * CHUNK;
    for (int i = tid; i < CHUNK; i += 512) {
        int src = ei[gbase + i];
        unsigned dst = (unsigned)ei[N_EDGES + gbase + i];
        pairbuf[i] = ((unsigned)src << 9) | (dst & 511u);
        unsigned b = dst >> 9;
        buckbuf[i] = (unsigned char)b;
        atomicAdd(&hist[wp][b], 1);
    }
    __syncthreads();
    if (tid < NB)
        tmp[tid] = hist[0][tid] + hist[1][tid] + hist[2][tid] + hist[3][tid];
    __syncthreads();
    for (int off = 1; off < NB; off <<= 1) {
        int v = 0;
        if (tid < NB && tid >= off) v = tmp[tid - off];
        __syncthreads();
        if (tid < NB) tmp[tid] += v;
        __syncthreads();
    }
    if (tid < NB) {
        int cnt_b = hist[0][tid] + hist[1][tid] + hist[2][tid] + hist[3][tid];
        int excl = tmp[tid] - cnt_b;
        cur[tid] = excl;
        offs[blockIdx.x * NB + tid] = excl;
    }
    __syncthreads();
    for (int i = tid; i < CHUNK; i += 512) {
        int pos = atomicAdd(&cur[buckbuf[i]], 1);
        sortbuf[pos] = pairbuf[i];
    }
    __syncthreads();
    for (int i = tid; i < CHUNK; i += 512)
        pairs[gbase + i] = sortbuf[i];
}

// ---- B4: per-bucket CSR build with full-bucket LDS staging.
// One global read of pairs (coalesced segment copy into dense LDS), then
// count/scan/scatter run at LDS speed. 1024 threads, ~86KB LDS, 1 blk/CU.
#define B4T 1024
__global__ __launch_bounds__(B4T) void b4_build(const unsigned* __restrict__ pairs,
                                                const int* __restrict__ offs,
                                                int* __restrict__ rs,
                                                int* __restrict__ re,
                                                int* __restrict__ csr_src) {
    __shared__ unsigned eLDS[CAP];             // 73728 B: bucket's edges, dense
    __shared__ int so[NBLK], slen[NBLK], dbase[NBLK];
    __shared__ int cnt[512], sc[512], cur[512];
    int b = blockIdx.x;
    int tid = threadIdx.x;

    for (int k = tid; k < NBLK; k += B4T) {
        int s = offs[k * NB + b];
        int e = (b == NB - 1) ? CHUNK : offs[k * NB + b + 1];
        so[k] = s;
        slen[k] = e - s;
    }
    __syncthreads();
    // inclusive scan of slen -> dbase (then exclusive via -slen)
    if (tid < NBLK) sc[tid] = slen[tid];
    __syncthreads();
    for (int off = 1; off < NBLK; off <<= 1) {
        int v = (tid < NBLK && tid >= off) ? sc[tid - off] : 0;
        __syncthreads();
        if (tid < NBLK) sc[tid] += v;
        __syncthreads();
    }
    if (tid < NBLK) dbase[tid] = sc[tid] - slen[tid];
    __syncthreads();
    int ne = dbase[NBLK - 1] + slen[NBLK - 1];

    // coalesced copy: wave per segment
    int wave = tid >> 6, lane = tid & 63;
    for (int k = wave; k < NBLK; k += (B4T / 64)) {
        int gb = k * CHUNK + so[k];
        int db = dbase[k], ln = slen[k];
        for (int i = lane; i < ln; i += 64)
            eLDS[db + i] = pairs[gb + i];
    }
    if (tid < 512) cnt[tid] = 0;
    __syncthreads();

    // count (from LDS)
    for (int i = tid; i < ne; i += B4T)
        atomicAdd(&cnt[eLDS[i] & 511u], 1);
    __syncthreads();
    if (tid < 512) sc[tid] = cnt[tid];
    __syncthreads();
    for (int off = 1; off < 512; off <<= 1) {
        int v = (tid < 512 && tid >= off) ? sc[tid - off] : 0;
        __syncthreads();
        if (tid < 512) sc[tid] += v;
        __syncthreads();
    }
    int rbase = b * CAP;
    if (tid < 512) {
        int excl = sc[tid] - cnt[tid];
        cur[tid] = rbase + excl;
        int node = (b << 9) + tid;
        if (node < N_NODES) {
            rs[node] = rbase + excl;
            re[node] = rbase + sc[tid];
        }
    }
    __syncthreads();
    // scatter (read LDS, write bucket-local global slice)
    for (int i = tid; i < ne; i += B4T) {
        unsigned p = eLDS[i];
        int pos = atomicAdd(&cur[p & 511u], 1);
        csr_src[pos] = (int)(p >> 9);
    }
}

// ---- G1: fused layer-1, rank-3 factorization, fp16 x-gathers, fp16 h1 out ----
__global__ void g1_layer1(const float4* __restrict__ xp,
                          const uint2* __restrict__ xh,
                          const float* __restrict__ Wq, const float* __restrict__ bq,
                          const float* __restrict__ Wk, const float* __restrict__ bk,
                          const float* __restrict__ Wv, const float* __restrict__ bv,
                          const float* __restrict__ Ws, const float* __restrict__ bs,
                          const int* __restrict__ rs, const int* __restrict__ re,
                          const int* __restrict__ csr_src,
                          uint2* __restrict__ h1) {
    __shared__ float sWq[192], sWk[192], sWv[192], sWs[192];
    __shared__ float sbq[64], sbk[64], sbv[64], sbs[64];
    for (int i = threadIdx.x; i < 192; i += 256) {
        sWq[i] = Wq[i]; sWk[i] = Wk[i]; sWv[i] = Wv[i]; sWs[i] = Ws[i];
    }
    for (int i = threadIdx.x; i < 64; i += 256) {
        sbq[i] = bq[i]; sbk[i] = bk[i]; sbv[i] = bv[i]; sbs[i] = bs[i];
    }
    __syncthreads();

    int lane = threadIdx.x & 63;
    int u = lane & 15;
    int slot = u >> 2;
    int j0 = u * 4;
    int n = blockIdx.x * 16 + (threadIdx.x >> 6) * 4 + (lane >> 4);

    float4 xc = xp[n];
    float x0 = xc.x, x1 = xc.y, x2 = xc.z;

    float q[4];
#pragma unroll
    for (int i = 0; i < 4; ++i)
        q[i] = 0.25f * (sbq[j0 + i] + x0 * sWq[j0 + i] + x1 * sWq[64 + j0 + i]
                        + x2 * sWq[128 + j0 + i]);
    float t0 = 0.f, t1 = 0.f, t2 = 0.f, tb = 0.f;
#pragma unroll
    for (int i = 0; i < 4; ++i) {
        float qi = q[i];
        t0 += qi * sWk[j0 + i];
        t1 += qi * sWk[64 + j0 + i];
        t2 += qi * sWk[128 + j0 + i];
        tb += qi * sbk[j0 + i];
    }
#pragma unroll
    for (int off = 1; off <= 2; off <<= 1) {
        t0 += __shfl_xor(t0, off);
        t1 += __shfl_xor(t1, off);
        t2 += __shfl_xor(t2, off);
        tb += __shfl_xor(tb, off);
    }
    // transpose: edge loop wants head = u&3
    int tsrc = (lane & 48) | ((lane & 3) << 2) | ((lane >> 2) & 3);
    t0 = __shfl(t0, tsrc, 64);
    t1 = __shfl(t1, tsrc, 64);
    t2 = __shfl(t2, tsrc, 64);
    tb = __shfl(tb, tsrc, 64);

    int row = rs[n];
    int deg = re[n] - row;

    float mA = NEG_INF, dA = 0.f, s0A = 0.f, s1A = 0.f, s2A = 0.f;
    float mB = NEG_INF, dB = 0.f, s0B = 0.f, s1B = 0.f, s2B = 0.f;
    for (int base = 0; base < deg; base += 8) {
        int eA = base + slot, eB = base + 4 + slot;
        bool vA = eA < deg, vB = eB < deg;
        int srcA = vA ? csr_src[row + eA] : 0;
        int srcB = vB ? csr_src[row + eB] : 0;
        uint2 wA = xh[srcA];
        uint2 wB = xh[srcB];
        float2 a01 = __half22float2(*(const __half2*)&wA.x);
        float a2 = __half22float2(*(const __half2*)&wA.y).x;
        float2 b01 = __half22float2(*(const __half2*)&wB.x);
        float b2 = __half22float2(*(const __half2*)&wB.y).x;
        float lA = vA ? (tb + a01.x * t0 + a01.y * t1 + a2 * t2) : NEG_INF;
        float lB = vB ? (tb + b01.x * t0 + b01.y * t1 + b2 * t2) : NEG_INF;
        float mnA = fmaxf(mA, lA);
        float scA = __expf(mA - mnA);
        float aA = vA ? __expf(lA - mnA) : 0.f;
        dA = dA * scA + aA;
        s0A = s0A * scA + aA * a01.x;
        s1A = s1A * scA + aA * a01.y;
        s2A = s2A * scA + aA * a2;
        mA = mnA;
        float mnB = fmaxf(mB, lB);
        float scB = __expf(mB - mnB);
        float aB = vB ? __expf(lB - mnB) : 0.f;
        dB = dB * scB + aB;
        s0B = s0B * scB + aB * b01.x;
        s1B = s1B * scB + aB * b01.y;
        s2B = s2B * scB + aB * b2;
        mB = mnB;
    }
    // merge B into A (in-lane)
    float m = fmaxf(mA, mB);
    float fA = __expf(mA - m), fB = __expf(mB - m);
    float d = dA * fA + dB * fB;
    float s0 = s0A * fA + s0B * fB;
    float s1 = s1A * fA + s1B * fB;
    float s2 = s2A * fA + s2B * fB;

    // cross-slot merge: global max, single rescale, butterfly sums
    float gm = m;
    gm = fmaxf(gm, __shfl_xor(gm, 4));
    gm = fmaxf(gm, __shfl_xor(gm, 8));
    float f = __expf(m - gm);
    d *= f; s0 *= f; s1 *= f; s2 *= f;
#pragma unroll
    for (int off = 4; off <= 8; off <<= 1) {
        d += __shfl_xor(d, off);
        s0 += __shfl_xor(s0, off);
        s1 += __shfl_xor(s1, off);
        s2 += __shfl_xor(s2, off);
    }

    // epilogue: lane u needs head u>>2's state
    int esrc = (lane & 48) | ((lane >> 2) & 3);
    float dH = __shfl(d, esrc, 64);
    float s0H = __shfl(s0, esrc, 64);
    float s1H = __shfl(s1, esrc, 64);
    float s2H = __shfl(s2, esrc, 64);
    float inv = 1.f / (dH + 1e-16f);
    float fr = dH * inv, r0 = s0H * inv, r1 = s1H * inv, r2 = s2H * inv;

    float o[4];
#pragma unroll
    for (int i = 0; i < 4; ++i) {
        int j = j0 + i;
        float val = fr * sbv[j] + r0 * sWv[j] + r1 * sWv[64 + j] + r2 * sWv[128 + j]
                  + sbs[j] + x0 * sWs[j] + x1 * sWs[64 + j] + x2 * sWs[128 + j];
        o[i] = fmaxf(val, 0.f);
    }
    __half2 p01 = __floats2half2_rn(o[0], o[1]);
    __half2 p23 = __floats2half2_rn(o[2], o[3]);
    h1[(size_t)n * 16 + u] = make_uint2(*(unsigned*)&p01, *(unsigned*)&p23);
}

// ---- K5: reads fp16 h1; q2 (pre-scaled) + s2 fp32; kv2 int8 16B rows ----
__global__ void k5_node2(const unsigned* __restrict__ h1,
                         const float* __restrict__ Wq, const float* __restrict__ bq,
                         const float* __restrict__ Wk, const float* __restrict__ bk,
                         const float* __restrict__ Wv, const float* __restrict__ bv,
                         const float* __restrict__ Ws, const float* __restrict__ bs,
                         float* __restrict__ q2, float* __restrict__ s2,
                         uint4* __restrict__ kv2) {
    __shared__ float sWq[384], sWk[384], sWv[384], sWs[384];
    __shared__ float sbq[6], sbk[6], sbv[6], sbs[6];
    for (int i = threadIdx.x; i < 384; i += blockDim.x) {
        sWq[i] = Wq[i]; sWk[i] = Wk[i]; sWv[i] = Wv[i]; sWs[i] = Ws[i];
    }
    if (threadIdx.x < 6) {
        sbq[threadIdx.x] = bq[threadIdx.x];
        sbk[threadIdx.x] = bk[threadIdx.x];
        sbv[threadIdx.x] = bv[threadIdx.x];
        sbs[threadIdx.x] = bs[threadIdx.x];
    }
    __syncthreads();
    int n = blockIdx.x * blockDim.x + threadIdx.x;
    if (n >= N_NODES) return;
    float qa[6], ka[6], va[6], sa[6];
#pragma unroll
    for (int c = 0; c < 6; ++c) { qa[c] = sbq[c]; ka[c] = sbk[c]; va[c] = sbv[c]; sa[c] = sbs[c]; }
    const uint4* hp = reinterpret_cast<const uint4*>(h1 + (size_t)n * 32);
#pragma unroll
    for (int i4 = 0; i4 < 8; ++i4) {
        uint4 hv = hp[i4];
        float2 f01 = __half22float2(*(const __half2*)&hv.x);
        float2 f23 = __half22float2(*(const __half2*)&hv.y);
        float2 f45 = __half22float2(*(const __half2*)&hv.z);
        float2 f67 = __half22float2(*(const __half2*)&hv.w);
        float hvv[8] = {f01.x, f01.y, f23.x, f23.y, f45.x, f45.y, f67.x, f67.y};
#pragma unroll
        for (int uu = 0; uu < 8; ++uu) {
            float hx = hvv[uu];
            int i = i4 * 8 + uu;
#pragma unroll
            for (int c = 0; c < 6; ++c) {
                qa[c] += hx * sWq[i * 6 + c];
                ka[c] += hx * sWk[i * 6 + c];
                va[c] += hx * sWv[i * 6 + c];
                sa[c] += hx * sWs[i * 6 + c];
            }
        }
    }
    const float rsqrt6 = 0.4082482904638631f;
#pragma unroll
    for (int c = 0; c < 6; ++c) {
        q2[(size_t)n * 6 + c] = qa[c] * rsqrt6;
        s2[(size_t)n * 6 + c] = sa[c];
    }
    float mk = 0.f, mv = 0.f;
#pragma unroll
    for (int c = 0; c < 6; ++c) {
        mk = fmaxf(mk, fabsf(ka[c]));
        mv = fmaxf(mv, fabsf(va[c]));
    }
    float sk = fmaxf(mk, 1e-8f) * (1.f / 127.f);
    float sv = fmaxf(mv, 1e-8f) * (1.f / 127.f);
    float isk = 1.f / sk, isv = 1.f / sv;
    int qk[6], qv[6];
#pragma unroll
    for (int c = 0; c < 6; ++c) {
        qk[c] = __float2int_rn(ka[c] * isk);
        qv[c] = __float2int_rn(va[c] * isv);
    }
    uint4 w;
    w.x = (qk[0] & 255) | ((qk[1] & 255) << 8) | ((qk[2] & 255) << 16) | ((qk[3] & 255) << 24);
    w.y = (qk[4] & 255) | ((qk[5] & 255) << 8) | ((qv[0] & 255) << 16) | ((qv[1] & 255) << 24);
    w.z = (qv[2] & 255) | ((qv[3] & 255) << 8) | ((qv[4] & 255) << 16) | ((qv[5] & 255) << 24);
    __half2 hs = __floats2half2_rn(sk, sv);
    w.w = *(unsigned*)&hs;
    kv2[n] = w;
}

// ---- G2: two-phase softmax, 8 lanes/node, register-resident edges ----
__global__ void g2_layer2(const int* __restrict__ rs, const int* __restrict__ re,
                          const int* __restrict__ csr_src,
                          const float* __restrict__ q2,
                          const uint4* __restrict__ kv2,
                          const float* __restrict__ s2,
                          const int* __restrict__ batch,
                          float* __restrict__ psum, float* __restrict__ pcnt) {
    __shared__ float bsum[N_GRAPHS * 6];
    __shared__ float bcnt[N_GRAPHS];
    for (int i = threadIdx.x; i < N_GRAPHS * 6; i += 256) bsum[i] = 0.f;
    for (int i = threadIdx.x; i < N_GRAPHS; i += 256) bcnt[i] = 0.f;
    __syncthreads();

    int node = blockIdx.x * 32 + (threadIdx.x >> 3);
    int lane8 = threadIdx.x & 7;

    float q[6];
#pragma unroll
    for (int c = 0; c < 6; ++c) q[c] = q2[(size_t)node * 6 + c];
    int row = rs[node];
    int deg = re[node] - row;

    // phase 1: up to 8 edges/lane in registers (covers deg <= 64)
    float lg[8], svr[8];
    unsigned py[8], pz[8];
#pragma unroll
    for (int i = 0; i < 8; ++i) { lg[i] = NEG_INF; svr[i] = 0.f; py[i] = 0u; pz[i] = 0u; }
    float lmax = NEG_INF;
#pragma unroll
    for (int i = 0; i < 4; ++i) {
        int e = lane8 + i * 8;
        bool v = e < deg;
        int src = v ? csr_src[row + e] : 0;
        uint4 w = kv2[src];
        float svx;
        float l = kvdot(q, w, &svx);
        if (v) {
            lg[i] = l; svr[i] = svx; py[i] = w.y; pz[i] = w.z;
            lmax = fmaxf(lmax, l);
        }
    }
    if (deg > 32) {
#pragma unroll
        for (int i = 4; i < 8; ++i) {
            int e = lane8 + i * 8;
            bool v = e < deg;
            int src = v ? csr_src[row + e] : 0;
            uint4 w = kv2[src];
            float svx;
            float l = kvdot(q, w, &svx);
            if (v) {
                lg[i] = l; svr[i] = svx; py[i] = w.y; pz[i] = w.z;
                lmax = fmaxf(lmax, l);
            }
        }
    }
    // overflow (deg > 64): online fold — essentially never taken, correctness net
    float mo = NEG_INF, dov = 0.f;
    float ao[6] = {0.f, 0.f, 0.f, 0.f, 0.f, 0.f};
    for (int e = lane8 + 64; e < deg; e += 8) {
        int src = csr_src[row + e];
        uint4 w = kv2[src];
        float svx;
        float l = kvdot(q, w, &svx);
        float mn = fmaxf(mo, l);
        float scp = __expf(mo - mn);
        float wx = __expf(l - mn);
        float wsx = wx * svx;
        dov = dov * scp + wx;
        ao[0] = ao[0] * scp + wsx * b2f(w.y, 16);
        ao[1] = ao[1] * scp + wsx * b2f(w.y, 24);
        ao[2] = ao[2] * scp + wsx * b2f(w.z, 0);
        ao[3] = ao[3] * scp + wsx * b2f(w.z, 8);
        ao[4] = ao[4] * scp + wsx * b2f(w.z, 16);
        ao[5] = ao[5] * scp + wsx * b2f(w.z, 24);
        mo = mn;
    }
    lmax = fmaxf(lmax, mo);
    // 3-stage cross-lane max
    lmax = fmaxf(lmax, __shfl_xor(lmax, 1));
    lmax = fmaxf(lmax, __shfl_xor(lmax, 2));
    lmax = fmaxf(lmax, __shfl_xor(lmax, 4));
    if (lmax < -5e29f) lmax = 0.f;   // deg==0 guard: all weights underflow to 0

    // phase 2: independent exps, in-lane accumulation (no rescale chain)
    float d = 0.f;
    float acc[6] = {0.f, 0.f, 0.f, 0.f, 0.f, 0.f};
#pragma unroll
    for (int i = 0; i < 8; ++i) {
        float w = __expf(lg[i] - lmax);   // exact 0 for empty slots
        float ws = w * svr[i];
        d += w;
        acc[0] += ws * b2f(py[i], 16);
        acc[1] += ws * b2f(py[i], 24);
        acc[2] += ws * b2f(pz[i], 0);
        acc[3] += ws * b2f(pz[i], 8);
        acc[4] += ws * b2f(pz[i], 16);
        acc[5] += ws * b2f(pz[i], 24);
    }
    // fold overflow state (scale by exp(mo - lmax); 0 when unused)
    float so = __expf(mo - lmax);
    d += dov * so;
#pragma unroll
    for (int c = 0; c < 6; ++c) acc[c] += ao[c] * so;

    // 3-stage butterfly sums
#pragma unroll
    for (int off = 1; off <= 4; off <<= 1) {
        d += __shfl_xor(d, off);
#pragma unroll
        for (int c = 0; c < 6; ++c) acc[c] += __shfl_xor(acc[c], off);
    }

    if (lane8 == 0) {
        float inv = 1.f / (d + 1e-16f);
        int g = batch[node];
#pragma unroll
        for (int c = 0; c < 6; ++c) {
            float val = acc[c] * inv + s2[(size_t)node * 6 + c];
            atomicAdd(&bsum[g * 6 + c], val);
        }
        atomicAdd(&bcnt[g], 1.f);
    }
    __syncthreads();
    for (int i = threadIdx.x; i < N_GRAPHS * 6; i += 256) {
        float v = bsum[i];
        if (v != 0.f) atomAddF(psum + i, v);
    }
    for (int i = threadIdx.x; i < N_GRAPHS; i += 256) {
        float v = bcnt[i];
        if (v != 0.f) atomAddF(pcnt + i, v);
    }
}

// ---- K9: pooled mean + log_softmax ----
__global__ void k9_final(const float* __restrict__ psum, const float* __restrict__ pcnt,
                         float* __restrict__ out) {
    int g = threadIdx.x;
    if (g >= N_GRAPHS) return;
    float cnt = fmaxf(pcnt[g], 1.0f);
    float z[6];
    float mx = -1e30f;
#pragma unroll
    for (int c = 0; c < 6; ++c) {
        z[c] = psum[g * 6 + c] / cnt;
        mx = fmaxf(mx, z[c]);
    }
    float se = 0.f;
#pragma unroll
    for (int c = 0; c < 6; ++c) se += __expf(z[c] - mx);
    float lse = mx + logf(se);
#pragma unroll
    for (int c = 0; c < 6; ++c) out[g * 6 + c] = z[c] - lse;
}

extern "C" void kernel_launch(void* const* d_in, const int* in_sizes, int n_in,
                              void* d_out, int out_size, void* d_ws, size_t ws_size,
                              hipStream_t stream) {
    const float* x   = (const float*)d_in[0];
    const int*   ei  = (const int*)d_in[1];
    const int*   bat = (const int*)d_in[2];
    const float* Wq1 = (const float*)d_in[3];  const float* bq1 = (const float*)d_in[4];
    const float* Wk1 = (const float*)d_in[5];  const float* bk1 = (const float*)d_in[6];
    const float* Wv1 = (const float*)d_in[7];  const float* bv1 = (const float*)d_in[8];
    const float* Ws1 = (const float*)d_in[9];  const float* bs1 = (const float*)d_in[10];
    const float* Wq2 = (const float*)d_in[11]; const float* bq2 = (const float*)d_in[12];
    const float* Wk2 = (const float*)d_in[13]; const float* bk2 = (const float*)d_in[14];
    const float* Wv2 = (const float*)d_in[15]; const float* bv2 = (const float*)d_in[16];
    const float* Ws2 = (const float*)d_in[17]; const float* bs2 = (const float*)d_in[18];
    float* out = (float*)d_out;

    char* ws = (char*)d_ws;
    size_t off = 0;
    auto alloc = [&](size_t bytes) -> char* {
        char* p = ws + off;
        off += (bytes + 255) & ~(size_t)255;
        return p;
    };

    // ---- zero-initialized region (one small memset) ----
    float* psum = (float*)alloc((size_t)N_GRAPHS * 6 * 4);
    float* pcnt = (float*)alloc((size_t)N_GRAPHS * 4);
    size_t zero_bytes = off;

    // ---- uninitialized scratch ----
    int*      offs    = (int*)     alloc((size_t)NBLK * NB * 4);
    unsigned* pairs   = (unsigned*)alloc((size_t)N_EDGES * 4);
    int*      csr_src = (int*)     alloc((size_t)NB * CAP * 4);
    int*      rsv     = (int*)     alloc((size_t)N_NODES * 4);
    int*      rev     = (int*)     alloc((size_t)N_NODES * 4);
    float4*   xp      = (float4*)  alloc((size_t)N_NODES * 16);
    uint2*    xh      = (uint2*)   alloc((size_t)N_NODES * 8);
    unsigned* h1      = (unsigned*)alloc((size_t)N_NODES * 64 * 2);  // fp16
    float*    q2      = (float*)   alloc((size_t)N_NODES * 6 * 4);
    float*    s2      = (float*)   alloc((size_t)N_NODES * 6 * 4);
    uint4*    kv2     = (uint4*)   alloc((size_t)N_NODES * 16);

    hipMemsetAsync(d_ws, 0, zero_bytes, stream);

    k0_packx<<<(N_NODES + 255) / 256, 256, 0, stream>>>(x, xp, xh);
    s1_partition<<<NBLK, 512, 0, stream>>>(ei, offs, pairs);
    b4_build<<<NB, B4T, 0, stream>>>(pairs, offs, rsv, rev, csr_src);

    g1_layer1<<<N_NODES / 16, 256, 0, stream>>>(xp, xh, Wq1, bq1, Wk1, bk1, Wv1, bv1,
                                                Ws1, bs1, rsv, rev, csr_src,
                                                (uint2*)h1);
    k5_node2<<<(N_NODES + 255) / 256, 256, 0, stream>>>(h1, Wq2, bq2, Wk2, bk2,
                                                        Wv2, bv2, Ws2, bs2,
                                                        q2, s2, kv2);
    g2_layer2<<<N_NODES / 32, 256, 0, stream>>>(rsv, rev, csr_src, q2, kv2, s2,
                                                bat, psum, pcnt);
    k9_final<<<1, 64, 0, stream>>>(psum, pcnt, out);
}